// Round 1
// baseline (7438.876 us; speedup 1.0000x reference)
//
#include <hip/hip_runtime.h>
#include <math.h>

#define B_ 256
#define N_ 127
#define S_ 128
#define NDIM_ 3
#define D_ 256
#define H_ 8
#define DH_ 32
#define M_ 256
#define HID_ 256
#define L_ 4
#define ROWS 16

// ---------- block reductions (256 threads = 4 waves) ----------
__device__ __forceinline__ float blk_sum(float v, float* sred) {
#pragma unroll
    for (int o = 32; o > 0; o >>= 1) v += __shfl_xor(v, o, 64);
    if ((threadIdx.x & 63) == 0) sred[threadIdx.x >> 6] = v;
    __syncthreads();
    v = sred[0] + sred[1] + sred[2] + sred[3];
    __syncthreads();
    return v;
}

__device__ __forceinline__ float blk_max(float v, float* sred) {
#pragma unroll
    for (int o = 32; o > 0; o >>= 1) v = fmaxf(v, __shfl_xor(v, o, 64));
    if ((threadIdx.x & 63) == 0) sred[threadIdx.x >> 6] = v;
    __syncthreads();
    v = fmaxf(fmaxf(sred[0], sred[1]), fmaxf(sred[2], sred[3]));
    __syncthreads();
    return v;
}

// ---------- embedding: h[b,0,:]=0 ; h[b,n,:] = x[b,n-1,:] @ emb_w^T + emb_b ----------
__global__ void k_embed(const float* __restrict__ x, const float* __restrict__ ew,
                        const float* __restrict__ eb, float* __restrict__ h) {
    const int idx = blockIdx.x * 256 + threadIdx.x;   // over B*S*D exactly
    const int d = idx & (D_ - 1);
    const int n = (idx >> 8) & (S_ - 1);
    const int b = idx >> 15;
    float val = 0.f;
    if (n > 0) {
        const float* xr = x + ((size_t)b * N_ + (n - 1)) * NDIM_;
        val = eb[d] + xr[0] * ew[d * 3 + 0] + xr[1] * ew[d * 3 + 1] + xr[2] * ew[d * 3 + 2];
    }
    h[idx] = val;
}

// ---------- QKV projection, 16 rows per block; v gets keep-mask ----------
__global__ void __launch_bounds__(256) k_qkv(
    const float* __restrict__ h, const int* __restrict__ mask,
    const float* __restrict__ Wq, const float* __restrict__ bq,
    const float* __restrict__ Wk, const float* __restrict__ bk,
    const float* __restrict__ Wv, const float* __restrict__ bv,
    float* __restrict__ q, float* __restrict__ k, float* __restrict__ v)
{
    __shared__ float rows[ROWS * D_];
    const int t = threadIdx.x;
    const int row0 = blockIdx.x * ROWS;
    for (int i = t * 4; i < ROWS * D_; i += 1024)
        *(float4*)&rows[i] = *(const float4*)&h[(size_t)row0 * D_ + i];
    __syncthreads();
    float aq[ROWS], ak[ROWS], av[ROWS];
#pragma unroll
    for (int r = 0; r < ROWS; r++) { aq[r] = 0.f; ak[r] = 0.f; av[r] = 0.f; }
    const float* wq = Wq + (size_t)t * D_;
    const float* wk = Wk + (size_t)t * D_;
    const float* wv = Wv + (size_t)t * D_;
    for (int d = 0; d < D_; d += 4) {
        const float4 q4 = *(const float4*)&wq[d];
        const float4 k4 = *(const float4*)&wk[d];
        const float4 v4 = *(const float4*)&wv[d];
#pragma unroll
        for (int r = 0; r < ROWS; r++) {
            const float4 x4 = *(const float4*)&rows[r * D_ + d];   // uniform-addr LDS broadcast
            aq[r] += x4.x * q4.x + x4.y * q4.y + x4.z * q4.z + x4.w * q4.w;
            ak[r] += x4.x * k4.x + x4.y * k4.y + x4.z * k4.z + x4.w * k4.w;
            av[r] += x4.x * v4.x + x4.y * v4.y + x4.z * v4.z + x4.w * v4.w;
        }
    }
    const int b = row0 >> 7;            // row0 / S
    const int n0 = row0 & (S_ - 1);
    const int hh = t >> 5, dh = t & 31;
    const float bqv = bq[t], bkv = bk[t], bvv = bv[t];
#pragma unroll
    for (int r = 0; r < ROWS; r++) {
        const int n = n0 + r;
        const float keep = (n == 0) ? 1.f : (mask[b * N_ + n - 1] ? 0.f : 1.f);
        const size_t o = (((size_t)b * H_ + hh) * S_ + n) * DH_ + dh;
        q[o] = aq[r] + bqv;
        k[o] = ak[r] + bkv;
        v[o] = (av[r] + bvv) * keep;
    }
}

// ---------- ordered-int float max helpers ----------
__global__ void k_reset(int* slot) {
    const int i = __float_as_int(-INFINITY);
    *slot = (i >= 0) ? i : (i ^ 0x7fffffff);
}

// global max over dd_k = nrm * (k . proj_m)   (whole tensor, per layer)
__global__ void __launch_bounds__(256) k_kmax(
    const float* __restrict__ kg, const float* __restrict__ proj, int* __restrict__ slot)
{
    __shared__ float sk[S_ * DH_];
    __shared__ float sred[4];
    const int t = threadIdx.x;
    const float* kb = kg + (size_t)blockIdx.x * S_ * DH_;
    for (int i = t * 4; i < S_ * DH_; i += 1024)
        *(float4*)&sk[i] = *(const float4*)&kb[i];
    float pr[DH_];
#pragma unroll
    for (int d = 0; d < DH_; d += 4) {
        const float4 p = *(const float4*)&proj[t * DH_ + d];
        pr[d] = p.x; pr[d + 1] = p.y; pr[d + 2] = p.z; pr[d + 3] = p.w;
    }
    __syncthreads();
    const float nrm = 0.42044820762685725f;   // 32^-0.25
    float mx = -INFINITY;
    for (int n = 0; n < S_; n++) {
        float acc = 0.f;
#pragma unroll
        for (int d = 0; d < DH_; d++) acc += sk[n * DH_ + d] * pr[d];
        mx = fmaxf(mx, acc * nrm);
    }
    mx = blk_max(mx, sred);
    if (t == 0) {
        const int i = __float_as_int(mx);
        atomicMax(slot, (i >= 0) ? i : (i ^ 0x7fffffff));
    }
}

// ---------- fused performer attention, one block per (b,h) ----------
__global__ void __launch_bounds__(256) k_attn(
    const float* __restrict__ qg, const float* __restrict__ kg, const float* __restrict__ vg,
    const float* __restrict__ proj, const int* __restrict__ slot, float* __restrict__ outp)
{
    __shared__ float sk[S_ * (DH_ + 1)];       // padded for diag pass
    __shared__ float sctx[M_ * (DH_ + 1)];     // padded for phase-3 reads
    __shared__ float sdk[S_], sdq[S_];
    __shared__ float srow[M_];
    __shared__ float spart[8 * DH_];
    __shared__ float sred[4];
    const int bh = blockIdx.x;
    const int b = bh >> 3, hh = bh & 7;
    const int t = threadIdx.x;
    const float* kb = kg + (size_t)bh * S_ * DH_;
    const float* qb = qg + (size_t)bh * S_ * DH_;
    const float* vb = vg + (size_t)bh * S_ * DH_;
    for (int i = t; i < S_ * DH_; i += 256)
        sk[(i >> 5) * (DH_ + 1) + (i & 31)] = kb[i];
    float pr[DH_];                              // this thread's proj row (m = t)
#pragma unroll
    for (int d = 0; d < DH_; d += 4) {
        const float4 p = *(const float4*)&proj[t * DH_ + d];
        pr[d] = p.x; pr[d + 1] = p.y; pr[d + 2] = p.z; pr[d + 3] = p.w;
    }
    __syncthreads();
    const float nrm = 0.42044820762685725f;
    const float diagc = 0.5f * nrm * nrm;
    if (t < S_) {
        float s = 0.f;
#pragma unroll
        for (int d = 0; d < DH_; d++) { const float xv = sk[t * (DH_ + 1) + d]; s += xv * xv; }
        sdk[t] = s * diagc;
        float s2 = 0.f;
#pragma unroll
        for (int d = 0; d < DH_; d++) { const float xv = qb[t * DH_ + d]; s2 += xv * xv; }
        sdq[t] = s2 * diagc;
    }
    __syncthreads();
    float kmaxv;
    { const int iv = *slot; kmaxv = __int_as_float((iv >= 0) ? iv : (iv ^ 0x7fffffff)); }
    const float ratio = 0.0625f;                // 256^-0.5
    float ctx[DH_];
#pragma unroll
    for (int d = 0; d < DH_; d++) ctx[d] = 0.f;
    float ksum = 0.f;
    // phase 2: kp rows -> ksum (per-thread, m = t) and ctx[m][d] in registers
    for (int n = 0; n < S_; n++) {
        float acc = 0.f;
#pragma unroll
        for (int d = 0; d < DH_; d++) acc += sk[n * (DH_ + 1) + d] * pr[d];
        const float kp = ratio * (expf(acc * nrm - sdk[n] - kmaxv) + 1e-4f);
        ksum += kp;
        const float4* v4 = (const float4*)(vb + n * DH_);   // uniform-addr global (L1-hot)
#pragma unroll
        for (int d4 = 0; d4 < DH_ / 4; d4++) {
            const float4 vv = v4[d4];
            ctx[d4 * 4 + 0] += kp * vv.x; ctx[d4 * 4 + 1] += kp * vv.y;
            ctx[d4 * 4 + 2] += kp * vv.z; ctx[d4 * 4 + 3] += kp * vv.w;
        }
    }
#pragma unroll
    for (int d = 0; d < DH_; d++) sctx[t * (DH_ + 1) + d] = ctx[d];
    __syncthreads();
    // phase 3: qp rows -> o[n][d]
    const int dlane = t & 31, g = t >> 5;
    for (int n = 0; n < S_; n++) {
        float acc = 0.f;
        const float4* q4 = (const float4*)(qb + n * DH_);
#pragma unroll
        for (int d4 = 0; d4 < DH_ / 4; d4++) {
            const float4 qq = q4[d4];
            acc += qq.x * pr[d4 * 4 + 0] + qq.y * pr[d4 * 4 + 1]
                 + qq.z * pr[d4 * 4 + 2] + qq.w * pr[d4 * 4 + 3];
        }
        const float dd = acc * nrm;
        const float mx = blk_max(dd, sred);                  // row max over m
        const float qp = ratio * (expf(dd - sdq[n] - mx) + 1e-4f);
        const float den = blk_sum(qp * ksum, sred);          // qp . ksum
        srow[t] = qp;
        __syncthreads();
        float part = 0.f;
#pragma unroll 8
        for (int j = 0; j < 32; j++) {
            const int m = g * 32 + j;
            part += srow[m] * sctx[m * (DH_ + 1) + dlane];
        }
        spart[g * DH_ + dlane] = part;
        __syncthreads();
        if (t < DH_) {
            float o = 0.f;
#pragma unroll
            for (int gg = 0; gg < 8; gg++) o += spart[gg * DH_ + t];
            outp[((size_t)b * S_ + n) * D_ + hh * DH_ + t] = o / den;
        }
        __syncthreads();
    }
}

// ---------- output projection + LayerNorm, 16 rows per block ----------
__global__ void __launch_bounds__(256) k_oproj_ln(
    const float* __restrict__ in, const float* __restrict__ W, const float* __restrict__ bias,
    const float* __restrict__ gw, const float* __restrict__ gb, float* __restrict__ outp)
{
    __shared__ float rows[ROWS * D_];
    __shared__ float sout[ROWS * D_];
    __shared__ float smu[ROWS], srs[ROWS];
    const int t = threadIdx.x;
    const size_t row0 = (size_t)blockIdx.x * ROWS;
    for (int i = t * 4; i < ROWS * D_; i += 1024)
        *(float4*)&rows[i] = *(const float4*)&in[row0 * D_ + i];
    __syncthreads();
    float acc[ROWS];
#pragma unroll
    for (int r = 0; r < ROWS; r++) acc[r] = 0.f;
    const float* w = W + (size_t)t * D_;
    for (int d = 0; d < D_; d += 4) {
        const float4 w4 = *(const float4*)&w[d];
#pragma unroll
        for (int r = 0; r < ROWS; r++) {
            const float4 x4 = *(const float4*)&rows[r * D_ + d];
            acc[r] += x4.x * w4.x + x4.y * w4.y + x4.z * w4.z + x4.w * w4.w;
        }
    }
    const float bv = bias[t];
#pragma unroll
    for (int r = 0; r < ROWS; r++) sout[r * D_ + t] = acc[r] + bv;
    __syncthreads();
    {
        const int r = t >> 4, c = t & 15;      // 16 lanes per row
        float s = 0.f, s2 = 0.f;
        for (int j = 0; j < D_; j += 16) {
            const float xv = sout[r * D_ + j + c];
            s += xv; s2 += xv * xv;
        }
#pragma unroll
        for (int o = 8; o > 0; o >>= 1) { s += __shfl_xor(s, o, 64); s2 += __shfl_xor(s2, o, 64); }
        if (c == 0) {
            const float mu = s * (1.f / D_);
            smu[r] = mu;
            srs[r] = rsqrtf(s2 * (1.f / D_) - mu * mu + 1e-5f);
        }
    }
    __syncthreads();
    const float g = gw[t], bb = gb[t];
#pragma unroll
    for (int r = 0; r < ROWS; r++)
        outp[(row0 + r) * D_ + t] = (sout[r * D_ + t] - smu[r]) * srs[r] * g + bb;
}

// ---------- FFN (leaky) + LayerNorm, 16 rows per block ----------
__global__ void __launch_bounds__(256) k_ffn_ln(
    const float* __restrict__ in, const float* __restrict__ W1, const float* __restrict__ b1,
    const float* __restrict__ W2, const float* __restrict__ b2,
    const float* __restrict__ gw, const float* __restrict__ gb, float* __restrict__ outp)
{
    __shared__ float rows[ROWS * D_];
    __shared__ float shid[ROWS * HID_];
    __shared__ float smu[ROWS], srs[ROWS];
    const int t = threadIdx.x;
    const size_t row0 = (size_t)blockIdx.x * ROWS;
    for (int i = t * 4; i < ROWS * D_; i += 1024)
        *(float4*)&rows[i] = *(const float4*)&in[row0 * D_ + i];
    __syncthreads();
    float acc[ROWS];
#pragma unroll
    for (int r = 0; r < ROWS; r++) acc[r] = 0.f;
    const float* w1 = W1 + (size_t)t * D_;
    for (int d = 0; d < D_; d += 4) {
        const float4 w4 = *(const float4*)&w1[d];
#pragma unroll
        for (int r = 0; r < ROWS; r++) {
            const float4 x4 = *(const float4*)&rows[r * D_ + d];
            acc[r] += x4.x * w4.x + x4.y * w4.y + x4.z * w4.z + x4.w * w4.w;
        }
    }
    const float b1v = b1[t];
#pragma unroll
    for (int r = 0; r < ROWS; r++) {
        const float u = acc[r] + b1v;
        shid[r * HID_ + t] = (u >= 0.f) ? u : 0.2f * u;
        acc[r] = 0.f;
    }
    __syncthreads();   // shid ready; all 'rows' reads of GEMM1 also complete
    const float* w2 = W2 + (size_t)t * HID_;
    for (int d = 0; d < HID_; d += 4) {
        const float4 w4 = *(const float4*)&w2[d];
#pragma unroll
        for (int r = 0; r < ROWS; r++) {
            const float4 x4 = *(const float4*)&shid[r * HID_ + d];
            acc[r] += x4.x * w4.x + x4.y * w4.y + x4.z * w4.z + x4.w * w4.w;
        }
    }
    const float b2v = b2[t];
#pragma unroll
    for (int r = 0; r < ROWS; r++) rows[r * D_ + t] = acc[r] + b2v;   // reuse rows as sout
    __syncthreads();
    {
        const int r = t >> 4, c = t & 15;
        float s = 0.f, s2 = 0.f;
        for (int j = 0; j < D_; j += 16) {
            const float xv = rows[r * D_ + j + c];
            s += xv; s2 += xv * xv;
        }
#pragma unroll
        for (int o = 8; o > 0; o >>= 1) { s += __shfl_xor(s, o, 64); s2 += __shfl_xor(s2, o, 64); }
        if (c == 0) {
            const float mu = s * (1.f / D_);
            smu[r] = mu;
            srs[r] = rsqrtf(s2 * (1.f / D_) - mu * mu + 1e-5f);
        }
    }
    __syncthreads();
    const float g = gw[t], bb = gb[t];
#pragma unroll
    for (int r = 0; r < ROWS; r++)
        outp[(row0 + r) * D_ + t] = (rows[r * D_ + t] - smu[r]) * srs[r] * g + bb;
}

// ---------- classification head: c = h[:,0]; 2x leaky MLP; scalar out ----------
__global__ void __launch_bounds__(256) k_head(
    const float* __restrict__ hfin, const float* __restrict__ h1w, const float* __restrict__ h1b,
    const float* __restrict__ h2w, const float* __restrict__ h2b,
    const float* __restrict__ ow, const float* __restrict__ ob, float* __restrict__ outp)
{
    __shared__ float c0[D_];
    __shared__ float c1[2 * HID_];
    __shared__ float sred[4];
    const int t = threadIdx.x;
    const int b = blockIdx.x;
    c0[t] = hfin[(size_t)b * S_ * D_ + t];     // row n = 0
    __syncthreads();
#pragma unroll
    for (int half = 0; half < 2; half++) {
        const int j = half * 256 + t;
        float a = h1b[j];
        const float* w = h1w + (size_t)j * D_;
        for (int d = 0; d < D_; d += 4) {
            const float4 w4 = *(const float4*)&w[d];
            const float4 x4 = *(const float4*)&c0[d];
            a += x4.x * w4.x + x4.y * w4.y + x4.z * w4.z + x4.w * w4.w;
        }
        c1[j] = (a >= 0.f) ? a : 0.2f * a;
    }
    __syncthreads();
    float a2 = h2b[t];
    const float* w2 = h2w + (size_t)t * (2 * HID_);
    for (int j = 0; j < 2 * HID_; j += 4) {
        const float4 w4 = *(const float4*)&w2[j];
        const float4 x4 = *(const float4*)&c1[j];
        a2 += x4.x * w4.x + x4.y * w4.y + x4.z * w4.z + x4.w * w4.w;
    }
    const float c2 = (a2 >= 0.f) ? a2 : 0.2f * a2;
    const float s = blk_sum(c2 * ow[t], sred);
    if (t == 0) outp[b] = s + ob[0];
}

extern "C" void kernel_launch(void* const* d_in, const int* in_sizes, int n_in,
                              void* d_out, int out_size, void* d_ws, size_t ws_size,
                              hipStream_t stream)
{
    const float* x     = (const float*)d_in[0];
    const int*   mask  = (const int*)d_in[1];
    const float* emb_w = (const float*)d_in[2];
    const float* emb_b = (const float*)d_in[3];
    const float* Wq    = (const float*)d_in[4];
    const float* bq    = (const float*)d_in[5];
    const float* Wk    = (const float*)d_in[6];
    const float* bk    = (const float*)d_in[7];
    const float* Wv    = (const float*)d_in[8];
    const float* bv    = (const float*)d_in[9];
    const float* Wo    = (const float*)d_in[10];
    const float* bo    = (const float*)d_in[11];
    const float* proj  = (const float*)d_in[12];
    const float* n1w   = (const float*)d_in[13];
    const float* n1b   = (const float*)d_in[14];
    const float* n2w   = (const float*)d_in[15];
    const float* n2b   = (const float*)d_in[16];
    const float* f1w   = (const float*)d_in[17];
    const float* f1b   = (const float*)d_in[18];
    const float* f2w   = (const float*)d_in[19];
    const float* f2b   = (const float*)d_in[20];
    const float* h1w   = (const float*)d_in[21];
    const float* h1b   = (const float*)d_in[22];
    const float* h2w   = (const float*)d_in[23];
    const float* h2b   = (const float*)d_in[24];
    const float* ow    = (const float*)d_in[25];
    const float* ob    = (const float*)d_in[26];

    const size_t BSD = (size_t)B_ * S_ * D_;
    float* A = (float*)d_ws;           // h (ping), also attn output
    float* Q = A + BSD;
    float* K = Q + BSD;
    float* V = K + BSD;
    float* T = V + BSD;                // post-LN1 buffer
    int* slot = (int*)(T + BSD);       // global k-max (ordered-int)

    k_embed<<<B_ * S_ * D_ / 256, 256, 0, stream>>>(x, emb_w, emb_b, A);
    for (int l = 0; l < L_; l++) {
        k_qkv<<<B_ * S_ / ROWS, 256, 0, stream>>>(A, mask,
            Wq + (size_t)l * D_ * D_, bq + l * D_,
            Wk + (size_t)l * D_ * D_, bk + l * D_,
            Wv + (size_t)l * D_ * D_, bv + l * D_, Q, K, V);
        k_reset<<<1, 1, 0, stream>>>(slot);
        k_kmax<<<B_ * H_, 256, 0, stream>>>(K, proj + (size_t)l * M_ * DH_, slot);
        k_attn<<<B_ * H_, 256, 0, stream>>>(Q, K, V, proj + (size_t)l * M_ * DH_, slot, A);
        k_oproj_ln<<<B_ * S_ / ROWS, 256, 0, stream>>>(A,
            Wo + (size_t)l * D_ * D_, bo + l * D_, n1w + l * D_, n1b + l * D_, T);
        k_ffn_ln<<<B_ * S_ / ROWS, 256, 0, stream>>>(T,
            f1w + (size_t)l * HID_ * D_, f1b + l * HID_,
            f2w + (size_t)l * D_ * HID_, f2b + l * D_,
            n2w + l * D_, n2b + l * D_, A);
    }
    k_head<<<B_, 256, 0, stream>>>(A, h1w, h1b, h2w, h2b, ow, ob, (float*)d_out);
}

// Round 2
// 5372.750 us; speedup vs baseline: 1.3846x; 1.3846x over previous
//
#include <hip/hip_runtime.h>
#include <math.h>

#define B_ 256
#define N_ 127
#define S_ 128
#define NDIM_ 3
#define D_ 256
#define H_ 8
#define DH_ 32
#define M_ 256
#define HID_ 256
#define L_ 4
#define ROWS 16
#define LOG2E 1.44269504088896340736f

// ---------- block reductions (256 threads = 4 waves) ----------
__device__ __forceinline__ float blk_sum(float v, float* sred) {
#pragma unroll
    for (int o = 32; o > 0; o >>= 1) v += __shfl_xor(v, o, 64);
    if ((threadIdx.x & 63) == 0) sred[threadIdx.x >> 6] = v;
    __syncthreads();
    v = sred[0] + sred[1] + sred[2] + sred[3];
    __syncthreads();
    return v;
}

__device__ __forceinline__ float blk_max(float v, float* sred) {
#pragma unroll
    for (int o = 32; o > 0; o >>= 1) v = fmaxf(v, __shfl_xor(v, o, 64));
    if ((threadIdx.x & 63) == 0) sred[threadIdx.x >> 6] = v;
    __syncthreads();
    v = fmaxf(fmaxf(sred[0], sred[1]), fmaxf(sred[2], sred[3]));
    __syncthreads();
    return v;
}

// ---------- embedding: h[b,0,:]=0 ; h[b,n,:] = x[b,n-1,:] @ emb_w^T + emb_b ----------
__global__ void k_embed(const float* __restrict__ x, const float* __restrict__ ew,
                        const float* __restrict__ eb, float* __restrict__ h) {
    const int idx = blockIdx.x * 256 + threadIdx.x;   // over B*S*D exactly
    const int d = idx & (D_ - 1);
    const int n = (idx >> 8) & (S_ - 1);
    const int b = idx >> 15;
    float val = 0.f;
    if (n > 0) {
        const float* xr = x + ((size_t)b * N_ + (n - 1)) * NDIM_;
        val = eb[d] + xr[0] * ew[d * 3 + 0] + xr[1] * ew[d * 3 + 1] + xr[2] * ew[d * 3 + 2];
    }
    h[idx] = val;
}

// ---------- QKV projection, 16 rows per block; v gets keep-mask ----------
__global__ void __launch_bounds__(256) k_qkv(
    const float* __restrict__ h, const int* __restrict__ mask,
    const float* __restrict__ Wq, const float* __restrict__ bq,
    const float* __restrict__ Wk, const float* __restrict__ bk,
    const float* __restrict__ Wv, const float* __restrict__ bv,
    float* __restrict__ q, float* __restrict__ k, float* __restrict__ v)
{
    __shared__ float rows[ROWS * D_];
    const int t = threadIdx.x;
    const int row0 = blockIdx.x * ROWS;
    for (int i = t * 4; i < ROWS * D_; i += 1024)
        *(float4*)&rows[i] = *(const float4*)&h[(size_t)row0 * D_ + i];
    __syncthreads();
    float aq[ROWS], ak[ROWS], av[ROWS];
#pragma unroll
    for (int r = 0; r < ROWS; r++) { aq[r] = 0.f; ak[r] = 0.f; av[r] = 0.f; }
    const float* wq = Wq + (size_t)t * D_;
    const float* wk = Wk + (size_t)t * D_;
    const float* wv = Wv + (size_t)t * D_;
    for (int d = 0; d < D_; d += 4) {
        const float4 q4 = *(const float4*)&wq[d];
        const float4 k4 = *(const float4*)&wk[d];
        const float4 v4 = *(const float4*)&wv[d];
#pragma unroll
        for (int r = 0; r < ROWS; r++) {
            const float4 x4 = *(const float4*)&rows[r * D_ + d];   // uniform-addr LDS broadcast
            aq[r] += x4.x * q4.x + x4.y * q4.y + x4.z * q4.z + x4.w * q4.w;
            ak[r] += x4.x * k4.x + x4.y * k4.y + x4.z * k4.z + x4.w * k4.w;
            av[r] += x4.x * v4.x + x4.y * v4.y + x4.z * v4.z + x4.w * v4.w;
        }
    }
    const int b = row0 >> 7;            // row0 / S
    const int n0 = row0 & (S_ - 1);
    const int hh = t >> 5, dh = t & 31;
    const float bqv = bq[t], bkv = bk[t], bvv = bv[t];
#pragma unroll
    for (int r = 0; r < ROWS; r++) {
        const int n = n0 + r;
        const float keep = (n == 0) ? 1.f : (mask[b * N_ + n - 1] ? 0.f : 1.f);
        const size_t o = (((size_t)b * H_ + hh) * S_ + n) * DH_ + dh;
        q[o] = aq[r] + bqv;
        k[o] = ak[r] + bkv;
        v[o] = (av[r] + bvv) * keep;
    }
}

// ---------- ordered-int float max helpers ----------
__global__ void k_reset(int* slot) {
    const int i = __float_as_int(-INFINITY);
    *slot = (i >= 0) ? i : (i ^ 0x7fffffff);
}

// global max over dd_k = nrm * (k . proj_m)   (whole tensor, per layer)
__global__ void __launch_bounds__(256) k_kmax(
    const float* __restrict__ kg, const float* __restrict__ proj, int* __restrict__ slot)
{
    __shared__ float sk[S_ * DH_];
    __shared__ float sred[4];
    const int t = threadIdx.x;
    const float* kb = kg + (size_t)blockIdx.x * S_ * DH_;
    for (int i = t * 4; i < S_ * DH_; i += 1024)
        *(float4*)&sk[i] = *(const float4*)&kb[i];
    float pr[DH_];
#pragma unroll
    for (int d = 0; d < DH_; d += 4) {
        const float4 p = *(const float4*)&proj[t * DH_ + d];
        pr[d] = p.x; pr[d + 1] = p.y; pr[d + 2] = p.z; pr[d + 3] = p.w;
    }
    __syncthreads();
    const float nrm = 0.42044820762685725f;   // 32^-0.25
    float mx = -INFINITY;
    for (int n = 0; n < S_; n++) {
        float acc = 0.f;
#pragma unroll
        for (int d = 0; d < DH_; d++) acc += sk[n * DH_ + d] * pr[d];
        mx = fmaxf(mx, acc * nrm);
    }
    mx = blk_max(mx, sred);
    if (t == 0) {
        const int i = __float_as_int(mx);
        atomicMax(slot, (i >= 0) ? i : (i ^ 0x7fffffff));
    }
}

// ---------- fused performer attention, one block per (b,h) ----------
// Phase 1: stage k tile + proj row (m = t); diag terms.
// Phase 2: per-thread m: kp over n -> ksum[m], ctx[m][:32] -> sctx (stride 34).
// Phase 3: 8 tiles of 16 q-rows:
//   dd in regs + LDS (stride 257), transpose reductions for rowmax/den
//   (16-lane strided reads + 4 shuffle rounds), then o = qp @ ctx as a
//   register-tiled mini-GEMM: 2x2 outputs/thread, 2-way m-split, float2 reads.
__global__ void __launch_bounds__(256) k_attn(
    const float* __restrict__ qg, const float* __restrict__ kg, const float* __restrict__ vg,
    const float* __restrict__ proj, const int* __restrict__ slot, float* __restrict__ outp)
{
    __shared__ float skq[16 * 257];      // phase1-2: k rows [128][32]; phase3: dd/qp [16][257]; then partials[512]
    __shared__ float sctx[M_ * 34];      // ctx[m][d], stride 34 (float2-aligned, conflict-free)
    __shared__ float sdk[S_], sdq[S_];
    __shared__ float sksum[M_];
    __shared__ float smax[16], sinv[16];
    const int bh = blockIdx.x;
    const int b = bh >> 3, hh = bh & 7;
    const int t = threadIdx.x;
    const float* kb = kg + (size_t)bh * S_ * DH_;
    const float* qb = qg + (size_t)bh * S_ * DH_;
    const float* vb = vg + (size_t)bh * S_ * DH_;
    // ---- phase 1: k tile + proj row
    for (int i = t * 4; i < S_ * DH_; i += 1024)
        *(float4*)&skq[i] = *(const float4*)&kb[i];
    float pr[DH_];
#pragma unroll
    for (int d = 0; d < DH_; d += 4) {
        const float4 p = *(const float4*)&proj[t * DH_ + d];
        pr[d] = p.x; pr[d + 1] = p.y; pr[d + 2] = p.z; pr[d + 3] = p.w;
    }
    __syncthreads();
    const float nrm = 0.42044820762685725f;   // 32^-0.25
    const float diagc = 0.5f * nrm * nrm;
    if (t < S_) {
        float s = 0.f, s2 = 0.f;
#pragma unroll
        for (int d4 = 0; d4 < DH_ / 4; d4++) {
            const float4 kk = *(const float4*)&skq[t * DH_ + d4 * 4];   // one-time conflict, ok
            s += kk.x * kk.x + kk.y * kk.y + kk.z * kk.z + kk.w * kk.w;
            const float4 qq = *(const float4*)&qb[t * DH_ + d4 * 4];
            s2 += qq.x * qq.x + qq.y * qq.y + qq.z * qq.z + qq.w * qq.w;
        }
        sdk[t] = s * diagc;
        sdq[t] = s2 * diagc;
    }
    __syncthreads();
    float kmaxv;
    { const int iv = *slot; kmaxv = __int_as_float((iv >= 0) ? iv : (iv ^ 0x7fffffff)); }
    const float ratio = 0.0625f;              // 256^-0.5
    // ---- phase 2: kp -> ksum, ctx (m = t)
    {
        float ctx[DH_];
#pragma unroll
        for (int d = 0; d < DH_; d++) ctx[d] = 0.f;
        float ksum = 0.f;
        for (int n = 0; n < S_; n++) {
            float acc = 0.f;
#pragma unroll
            for (int d4 = 0; d4 < DH_ / 4; d4++) {
                const float4 kk = *(const float4*)&skq[n * DH_ + d4 * 4];   // uniform broadcast
                acc += kk.x * pr[d4 * 4 + 0] + kk.y * pr[d4 * 4 + 1]
                     + kk.z * pr[d4 * 4 + 2] + kk.w * pr[d4 * 4 + 3];
            }
            const float kp = ratio * (exp2f((acc * nrm - sdk[n] - kmaxv) * LOG2E) + 1e-4f);
            ksum += kp;
            const float4* v4 = (const float4*)(vb + n * DH_);   // uniform global (L1-hot)
#pragma unroll
            for (int d4 = 0; d4 < DH_ / 4; d4++) {
                const float4 vv = v4[d4];
                ctx[d4 * 4 + 0] += kp * vv.x; ctx[d4 * 4 + 1] += kp * vv.y;
                ctx[d4 * 4 + 2] += kp * vv.z; ctx[d4 * 4 + 3] += kp * vv.w;
            }
        }
        sksum[t] = ksum;
#pragma unroll
        for (int d2 = 0; d2 < DH_ / 2; d2++)
            *(float2*)&sctx[t * 34 + d2 * 2] = make_float2(ctx[d2 * 2], ctx[d2 * 2 + 1]);
    }
    __syncthreads();   // sctx/sksum ready; skq (k tile) now dead -> reuse as dd/qp
    // ---- phase 3: 8 tiles of 16 rows
    const int rr = t >> 4, cc = t & 15;                 // reduction mapping (16 rows x 16 lanes)
    const int mc = t >> 7;                              // m-chunk (0: m<128, 1: m>=128)
    const int rg = (t >> 4) & 7, cg = t & 15;           // step-D mapping: rows 2rg,2rg+1; cols 2cg,2cg+1
    for (int tile = 0; tile < 8; tile++) {
        const int n0 = tile * 16;
        float ddr[16];
#pragma unroll
        for (int r = 0; r < 16; r++) {
            const float4* q4 = (const float4*)(qb + (n0 + r) * DH_);   // uniform global
            float acc = 0.f;
#pragma unroll
            for (int d4 = 0; d4 < DH_ / 4; d4++) {
                const float4 qq = q4[d4];
                acc += qq.x * pr[d4 * 4 + 0] + qq.y * pr[d4 * 4 + 1]
                     + qq.z * pr[d4 * 4 + 2] + qq.w * pr[d4 * 4 + 3];
            }
            ddr[r] = acc * nrm;
            skq[r * 257 + t] = ddr[r];
        }
        __syncthreads();
        {   // row max over m (transpose reduce)
            float mx = -INFINITY;
#pragma unroll
            for (int j = 0; j < 16; j++) mx = fmaxf(mx, skq[rr * 257 + cc + j * 16]);
#pragma unroll
            for (int o = 8; o > 0; o >>= 1) mx = fmaxf(mx, __shfl_xor(mx, o, 64));
            if (cc == 0) smax[rr] = mx;
        }
        __syncthreads();
#pragma unroll
        for (int r = 0; r < 16; r++) {   // qp (overwrite dd in LDS)
            const float qp = ratio * (exp2f((ddr[r] - sdq[n0 + r] - smax[r]) * LOG2E) + 1e-4f);
            skq[r * 257 + t] = qp;
        }
        __syncthreads();
        {   // den = qp . ksum (transpose reduce), sinv = 1/den
            float s = 0.f;
#pragma unroll
            for (int j = 0; j < 16; j++) {
                const int m = cc + j * 16;
                s += skq[rr * 257 + m] * sksum[m];
            }
#pragma unroll
            for (int o = 8; o > 0; o >>= 1) s += __shfl_xor(s, o, 64);
            if (cc == 0) sinv[rr] = 1.0f / s;
        }
        __syncthreads();
        // step D: o[r][d] = sum_m qp[r][m]*ctx[m][d]; 2x2 per thread, 2-way m-split
        float a00 = 0.f, a01 = 0.f, a10 = 0.f, a11 = 0.f;
        const int r0 = 2 * rg, r1 = 2 * rg + 1, c0 = 2 * cg;
        const int mbase = mc * 128;
        for (int j = 0; j < 128; j++) {
            const int m = mbase + j;
            const float q0 = skq[r0 * 257 + m];
            const float q1 = skq[r1 * 257 + m];
            const float2 cv = *(const float2*)&sctx[m * 34 + c0];
            a00 += q0 * cv.x; a01 += q0 * cv.y;
            a10 += q1 * cv.x; a11 += q1 * cv.y;
        }
        __syncthreads();   // qp region dead; reuse skq[0..511] for chunk-0 partials
        if (mc == 0) {
            *(float2*)&skq[r0 * 32 + c0] = make_float2(a00, a01);
            *(float2*)&skq[r1 * 32 + c0] = make_float2(a10, a11);
        }
        __syncthreads();
        if (mc == 1) {
            const float2 p0 = *(const float2*)&skq[r0 * 32 + c0];
            const float2 p1 = *(const float2*)&skq[r1 * 32 + c0];
            const float i0 = sinv[r0], i1 = sinv[r1];
            float* orow0 = outp + ((size_t)b * S_ + n0 + r0) * D_ + hh * DH_ + c0;
            float* orow1 = outp + ((size_t)b * S_ + n0 + r1) * D_ + hh * DH_ + c0;
            *(float2*)orow0 = make_float2((a00 + p0.x) * i0, (a01 + p0.y) * i0);
            *(float2*)orow1 = make_float2((a10 + p1.x) * i1, (a11 + p1.y) * i1);
        }
        __syncthreads();   // protect skq before next tile's dd writes
    }
}

// ---------- output projection + LayerNorm, 16 rows per block ----------
__global__ void __launch_bounds__(256) k_oproj_ln(
    const float* __restrict__ in, const float* __restrict__ W, const float* __restrict__ bias,
    const float* __restrict__ gw, const float* __restrict__ gb, float* __restrict__ outp)
{
    __shared__ float rows[ROWS * D_];
    __shared__ float sout[ROWS * D_];
    __shared__ float smu[ROWS], srs[ROWS];
    const int t = threadIdx.x;
    const size_t row0 = (size_t)blockIdx.x * ROWS;
    for (int i = t * 4; i < ROWS * D_; i += 1024)
        *(float4*)&rows[i] = *(const float4*)&in[row0 * D_ + i];
    __syncthreads();
    float acc[ROWS];
#pragma unroll
    for (int r = 0; r < ROWS; r++) acc[r] = 0.f;
    const float* w = W + (size_t)t * D_;
    for (int d = 0; d < D_; d += 4) {
        const float4 w4 = *(const float4*)&w[d];
#pragma unroll
        for (int r = 0; r < ROWS; r++) {
            const float4 x4 = *(const float4*)&rows[r * D_ + d];
            acc[r] += x4.x * w4.x + x4.y * w4.y + x4.z * w4.z + x4.w * w4.w;
        }
    }
    const float bv = bias[t];
#pragma unroll
    for (int r = 0; r < ROWS; r++) sout[r * D_ + t] = acc[r] + bv;
    __syncthreads();
    {
        const int r = t >> 4, c = t & 15;      // 16 lanes per row
        float s = 0.f, s2 = 0.f;
        for (int j = 0; j < D_; j += 16) {
            const float xv = sout[r * D_ + j + c];
            s += xv; s2 += xv * xv;
        }
#pragma unroll
        for (int o = 8; o > 0; o >>= 1) { s += __shfl_xor(s, o, 64); s2 += __shfl_xor(s2, o, 64); }
        if (c == 0) {
            const float mu = s * (1.f / D_);
            smu[r] = mu;
            srs[r] = rsqrtf(s2 * (1.f / D_) - mu * mu + 1e-5f);
        }
    }
    __syncthreads();
    const float g = gw[t], bb = gb[t];
#pragma unroll
    for (int r = 0; r < ROWS; r++)
        outp[(row0 + r) * D_ + t] = (sout[r * D_ + t] - smu[r]) * srs[r] * g + bb;
}

// ---------- FFN (leaky) + LayerNorm, 16 rows per block ----------
__global__ void __launch_bounds__(256) k_ffn_ln(
    const float* __restrict__ in, const float* __restrict__ W1, const float* __restrict__ b1,
    const float* __restrict__ W2, const float* __restrict__ b2,
    const float* __restrict__ gw, const float* __restrict__ gb, float* __restrict__ outp)
{
    __shared__ float rows[ROWS * D_];
    __shared__ float shid[ROWS * HID_];
    __shared__ float smu[ROWS], srs[ROWS];
    const int t = threadIdx.x;
    const size_t row0 = (size_t)blockIdx.x * ROWS;
    for (int i = t * 4; i < ROWS * D_; i += 1024)
        *(float4*)&rows[i] = *(const float4*)&in[row0 * D_ + i];
    __syncthreads();
    float acc[ROWS];
#pragma unroll
    for (int r = 0; r < ROWS; r++) acc[r] = 0.f;
    const float* w1 = W1 + (size_t)t * D_;
    for (int d = 0; d < D_; d += 4) {
        const float4 w4 = *(const float4*)&w1[d];
#pragma unroll
        for (int r = 0; r < ROWS; r++) {
            const float4 x4 = *(const float4*)&rows[r * D_ + d];
            acc[r] += x4.x * w4.x + x4.y * w4.y + x4.z * w4.z + x4.w * w4.w;
        }
    }
    const float b1v = b1[t];
#pragma unroll
    for (int r = 0; r < ROWS; r++) {
        const float u = acc[r] + b1v;
        shid[r * HID_ + t] = (u >= 0.f) ? u : 0.2f * u;
        acc[r] = 0.f;
    }
    __syncthreads();   // shid ready; all 'rows' reads of GEMM1 also complete
    const float* w2 = W2 + (size_t)t * HID_;
    for (int d = 0; d < HID_; d += 4) {
        const float4 w4 = *(const float4*)&w2[d];
#pragma unroll
        for (int r = 0; r < ROWS; r++) {
            const float4 x4 = *(const float4*)&shid[r * HID_ + d];
            acc[r] += x4.x * w4.x + x4.y * w4.y + x4.z * w4.z + x4.w * w4.w;
        }
    }
    const float b2v = b2[t];
#pragma unroll
    for (int r = 0; r < ROWS; r++) rows[r * D_ + t] = acc[r] + b2v;   // reuse rows as sout
    __syncthreads();
    {
        const int r = t >> 4, c = t & 15;
        float s = 0.f, s2 = 0.f;
        for (int j = 0; j < D_; j += 16) {
            const float xv = rows[r * D_ + j + c];
            s += xv; s2 += xv * xv;
        }
#pragma unroll
        for (int o = 8; o > 0; o >>= 1) { s += __shfl_xor(s, o, 64); s2 += __shfl_xor(s2, o, 64); }
        if (c == 0) {
            const float mu = s * (1.f / D_);
            smu[r] = mu;
            srs[r] = rsqrtf(s2 * (1.f / D_) - mu * mu + 1e-5f);
        }
    }
    __syncthreads();
    const float g = gw[t], bb = gb[t];
#pragma unroll
    for (int r = 0; r < ROWS; r++)
        outp[(row0 + r) * D_ + t] = (rows[r * D_ + t] - smu[r]) * srs[r] * g + bb;
}

// ---------- classification head: c = h[:,0]; 2x leaky MLP; scalar out ----------
__global__ void __launch_bounds__(256) k_head(
    const float* __restrict__ hfin, const float* __restrict__ h1w, const float* __restrict__ h1b,
    const float* __restrict__ h2w, const float* __restrict__ h2b,
    const float* __restrict__ ow, const float* __restrict__ ob, float* __restrict__ outp)
{
    __shared__ float c0[D_];
    __shared__ float c1[2 * HID_];
    __shared__ float sred[4];
    const int t = threadIdx.x;
    const int b = blockIdx.x;
    c0[t] = hfin[(size_t)b * S_ * D_ + t];     // row n = 0
    __syncthreads();
#pragma unroll
    for (int half = 0; half < 2; half++) {
        const int j = half * 256 + t;
        float a = h1b[j];
        const float* w = h1w + (size_t)j * D_;
        for (int d = 0; d < D_; d += 4) {
            const float4 w4 = *(const float4*)&w[d];
            const float4 x4 = *(const float4*)&c0[d];
            a += x4.x * w4.x + x4.y * w4.y + x4.z * w4.z + x4.w * w4.w;
        }
        c1[j] = (a >= 0.f) ? a : 0.2f * a;
    }
    __syncthreads();
    float a2 = h2b[t];
    const float* w2 = h2w + (size_t)t * (2 * HID_);
    for (int j = 0; j < 2 * HID_; j += 4) {
        const float4 w4 = *(const float4*)&w2[j];
        const float4 x4 = *(const float4*)&c1[j];
        a2 += x4.x * w4.x + x4.y * w4.y + x4.z * w4.z + x4.w * w4.w;
    }
    const float c2 = (a2 >= 0.f) ? a2 : 0.2f * a2;
    const float s = blk_sum(c2 * ow[t], sred);
    if (t == 0) outp[b] = s + ob[0];
}

extern "C" void kernel_launch(void* const* d_in, const int* in_sizes, int n_in,
                              void* d_out, int out_size, void* d_ws, size_t ws_size,
                              hipStream_t stream)
{
    const float* x     = (const float*)d_in[0];
    const int*   mask  = (const int*)d_in[1];
    const float* emb_w = (const float*)d_in[2];
    const float* emb_b = (const float*)d_in[3];
    const float* Wq    = (const float*)d_in[4];
    const float* bq    = (const float*)d_in[5];
    const float* Wk    = (const float*)d_in[6];
    const float* bk    = (const float*)d_in[7];
    const float* Wv    = (const float*)d_in[8];
    const float* bv    = (const float*)d_in[9];
    const float* Wo    = (const float*)d_in[10];
    const float* bo    = (const float*)d_in[11];
    const float* proj  = (const float*)d_in[12];
    const float* n1w   = (const float*)d_in[13];
    const float* n1b   = (const float*)d_in[14];
    const float* n2w   = (const float*)d_in[15];
    const float* n2b   = (const float*)d_in[16];
    const float* f1w   = (const float*)d_in[17];
    const float* f1b   = (const float*)d_in[18];
    const float* f2w   = (const float*)d_in[19];
    const float* f2b   = (const float*)d_in[20];
    const float* h1w   = (const float*)d_in[21];
    const float* h1b   = (const float*)d_in[22];
    const float* h2w   = (const float*)d_in[23];
    const float* h2b   = (const float*)d_in[24];
    const float* ow    = (const float*)d_in[25];
    const float* ob    = (const float*)d_in[26];

    const size_t BSD = (size_t)B_ * S_ * D_;
    float* A = (float*)d_ws;           // h (ping), also attn output
    float* Q = A + BSD;
    float* K = Q + BSD;
    float* V = K + BSD;
    float* T = V + BSD;                // post-LN1 buffer
    int* slot = (int*)(T + BSD);       // global k-max (ordered-int)

    k_embed<<<B_ * S_ * D_ / 256, 256, 0, stream>>>(x, emb_w, emb_b, A);
    for (int l = 0; l < L_; l++) {
        k_qkv<<<B_ * S_ / ROWS, 256, 0, stream>>>(A, mask,
            Wq + (size_t)l * D_ * D_, bq + l * D_,
            Wk + (size_t)l * D_ * D_, bk + l * D_,
            Wv + (size_t)l * D_ * D_, bv + l * D_, Q, K, V);
        k_reset<<<1, 1, 0, stream>>>(slot);
        k_kmax<<<B_ * H_, 256, 0, stream>>>(K, proj + (size_t)l * M_ * DH_, slot);
        k_attn<<<B_ * H_, 256, 0, stream>>>(Q, K, V, proj + (size_t)l * M_ * DH_, slot, A);
        k_oproj_ln<<<B_ * S_ / ROWS, 256, 0, stream>>>(A,
            Wo + (size_t)l * D_ * D_, bo + l * D_, n1w + l * D_, n1b + l * D_, T);
        k_ffn_ln<<<B_ * S_ / ROWS, 256, 0, stream>>>(T,
            f1w + (size_t)l * HID_ * D_, f1b + l * HID_,
            f2w + (size_t)l * D_ * HID_, f2b + l * D_,
            n2w + l * D_, n2b + l * D_, A);
    }
    k_head<<<B_, 256, 0, stream>>>(A, h1w, h1b, h2w, h2b, ow, ob, (float*)d_out);
}

// Round 3
// 4245.057 us; speedup vs baseline: 1.7524x; 1.2656x over previous
//
#include <hip/hip_runtime.h>
#include <math.h>

#define B_ 256
#define N_ 127
#define S_ 128
#define NDIM_ 3
#define D_ 256
#define H_ 8
#define DH_ 32
#define M_ 256
#define HID_ 256
#define L_ 4
#define LOG2E 1.44269504088896340736f

// ---------- block reductions (256 threads = 4 waves) ----------
__device__ __forceinline__ float blk_sum(float v, float* sred) {
#pragma unroll
    for (int o = 32; o > 0; o >>= 1) v += __shfl_xor(v, o, 64);
    if ((threadIdx.x & 63) == 0) sred[threadIdx.x >> 6] = v;
    __syncthreads();
    v = sred[0] + sred[1] + sred[2] + sred[3];
    __syncthreads();
    return v;
}

__device__ __forceinline__ float blk_max(float v, float* sred) {
#pragma unroll
    for (int o = 32; o > 0; o >>= 1) v = fmaxf(v, __shfl_xor(v, o, 64));
    if ((threadIdx.x & 63) == 0) sred[threadIdx.x >> 6] = v;
    __syncthreads();
    v = fmaxf(fmaxf(sred[0], sred[1]), fmaxf(sred[2], sred[3]));
    __syncthreads();
    return v;
}

// ---------- embedding ----------
__global__ void k_embed(const float* __restrict__ x, const float* __restrict__ ew,
                        const float* __restrict__ eb, float* __restrict__ h) {
    const int idx = blockIdx.x * 256 + threadIdx.x;
    const int d = idx & (D_ - 1);
    const int n = (idx >> 8) & (S_ - 1);
    const int b = idx >> 15;
    float val = 0.f;
    if (n > 0) {
        const float* xr = x + ((size_t)b * N_ + (n - 1)) * NDIM_;
        val = eb[d] + xr[0] * ew[d * 3 + 0] + xr[1] * ew[d * 3 + 1] + xr[2] * ew[d * 3 + 2];
    }
    h[idx] = val;
}

// ---------- generic register-tiled fp32 GEMM: C[64 x 256] per block ----------
// C = A[64xK=256] @ W[N=256][K=256]^T + bias, with fused epilogue.
// EPI: 0 = write q/k layout [b,h,n,dh]; 1 = same + keep-mask (v);
//      2 = LayerNorm -> plain [row][col]; 3 = leaky -> plain.
// Thread map: rg = t>>5 owns rows rg*8..rg*8+7; cg = t&31 owns cols cg+32i.
// LDS: As[k][row] stride 68 (2-way max), Ws[k][col] stride 257 (conflict-free).
template<int EPI>
__global__ void __launch_bounds__(256) k_gemm(
    const float* __restrict__ A, const float* __restrict__ W,
    const float* __restrict__ bias, const float* __restrict__ g1,
    const float* __restrict__ g2, const int* __restrict__ mask,
    float* __restrict__ out)
{
    __shared__ float As[16][68];
    __shared__ float Ws[16][257];
    const int t = threadIdx.x;
    const int rg = t >> 5, cg = t & 31;
    const int row0 = blockIdx.x * 64;
    float acc[8][8];
#pragma unroll
    for (int j = 0; j < 8; j++)
#pragma unroll
        for (int i = 0; i < 8; i++) acc[j][i] = 0.f;

    for (int k0 = 0; k0 < 256; k0 += 16) {
        {   // stage A tile (transposed): 64 rows x 16 k
            const int rl = t >> 2, kq = (t & 3) * 4;
            const float4 a4 = *(const float4*)&A[(size_t)(row0 + rl) * D_ + k0 + kq];
            As[kq + 0][rl] = a4.x; As[kq + 1][rl] = a4.y;
            As[kq + 2][rl] = a4.z; As[kq + 3][rl] = a4.w;
        }
#pragma unroll
        for (int i = 0; i < 4; i++) {   // stage W tile: col = t, k-chunk = 4i
            const int kq = i * 4;
            const float4 w4 = *(const float4*)&W[(size_t)t * D_ + k0 + kq];
            Ws[kq + 0][t] = w4.x; Ws[kq + 1][t] = w4.y;
            Ws[kq + 2][t] = w4.z; Ws[kq + 3][t] = w4.w;
        }
        __syncthreads();
#pragma unroll
        for (int k = 0; k < 16; k++) {
            float a[8], b[8];
            *(float4*)&a[0] = *(const float4*)&As[k][rg * 8];       // broadcast
            *(float4*)&a[4] = *(const float4*)&As[k][rg * 8 + 4];
#pragma unroll
            for (int i = 0; i < 8; i++) b[i] = Ws[k][cg + 32 * i];  // 32 banks, 2-way
#pragma unroll
            for (int j = 0; j < 8; j++)
#pragma unroll
                for (int i = 0; i < 8; i++) acc[j][i] = fmaf(a[j], b[i], acc[j][i]);
        }
        __syncthreads();
    }

    float bv[8];
#pragma unroll
    for (int i = 0; i < 8; i++) bv[i] = bias[cg + 32 * i];

    if (EPI <= 1) {            // q/k/v split layout [b,h,n,dh]
        const int b = row0 >> 7;
#pragma unroll
        for (int j = 0; j < 8; j++) {
            const int row = row0 + rg * 8 + j;
            const int n = row & (S_ - 1);
            float keep = 1.f;
            if (EPI == 1) keep = (n == 0) ? 1.f : (mask[b * N_ + n - 1] ? 0.f : 1.f);
#pragma unroll
            for (int i = 0; i < 8; i++) {
                float c = acc[j][i] + bv[i];
                if (EPI == 1) c *= keep;
                out[(((size_t)b * H_ + i) * S_ + n) * DH_ + cg] = c;
            }
        }
    } else if (EPI == 2) {     // LayerNorm
        float gv[8], bbv[8];
#pragma unroll
        for (int i = 0; i < 8; i++) { gv[i] = g1[cg + 32 * i]; bbv[i] = g2[cg + 32 * i]; }
#pragma unroll
        for (int j = 0; j < 8; j++) {
            float s = 0.f, s2 = 0.f;
#pragma unroll
            for (int i = 0; i < 8; i++) {
                const float c = acc[j][i] + bv[i];
                s += c; s2 += c * c;
            }
#pragma unroll
            for (int o = 16; o > 0; o >>= 1) {
                s += __shfl_xor(s, o, 64); s2 += __shfl_xor(s2, o, 64);
            }
            const float mu = s * (1.f / D_);
            const float rs = rsqrtf(s2 * (1.f / D_) - mu * mu + 1e-5f);
            const size_t row = row0 + rg * 8 + j;
#pragma unroll
            for (int i = 0; i < 8; i++) {
                const float c = acc[j][i] + bv[i];
                out[row * D_ + cg + 32 * i] = (c - mu) * rs * gv[i] + bbv[i];
            }
        }
    } else {                   // leaky
#pragma unroll
        for (int j = 0; j < 8; j++) {
            const size_t row = row0 + rg * 8 + j;
#pragma unroll
            for (int i = 0; i < 8; i++) {
                const float c = acc[j][i] + bv[i];
                out[row * D_ + cg + 32 * i] = (c >= 0.f) ? c : 0.2f * c;
            }
        }
    }
}

// ---------- ordered-int float max helpers ----------
__global__ void k_reset(int* slot) {
    const int i = __float_as_int(-INFINITY);
    *slot = (i >= 0) ? i : (i ^ 0x7fffffff);
}

__global__ void __launch_bounds__(256) k_kmax(
    const float* __restrict__ kg, const float* __restrict__ proj, int* __restrict__ slot)
{
    __shared__ float sk[S_ * DH_];
    __shared__ float sred[4];
    const int t = threadIdx.x;
    const float* kb = kg + (size_t)blockIdx.x * S_ * DH_;
    for (int i = t * 4; i < S_ * DH_; i += 1024)
        *(float4*)&sk[i] = *(const float4*)&kb[i];
    float pr[DH_];
#pragma unroll
    for (int d = 0; d < DH_; d += 4) {
        const float4 p = *(const float4*)&proj[t * DH_ + d];
        pr[d] = p.x; pr[d + 1] = p.y; pr[d + 2] = p.z; pr[d + 3] = p.w;
    }
    __syncthreads();
    const float nrm = 0.42044820762685725f;   // 32^-0.25
    float mx = -INFINITY;
    for (int n = 0; n < S_; n++) {
        float acc = 0.f;
#pragma unroll
        for (int d = 0; d < DH_; d++) acc += sk[n * DH_ + d] * pr[d];
        mx = fmaxf(mx, acc * nrm);
    }
    mx = blk_max(mx, sred);
    if (t == 0) {
        const int i = __float_as_int(mx);
        atomicMax(slot, (i >= 0) ? i : (i ^ 0x7fffffff));
    }
}

// ---------- fused performer attention, one block per (b,h) ----------
__global__ void __launch_bounds__(256) k_attn(
    const float* __restrict__ qg, const float* __restrict__ kg, const float* __restrict__ vg,
    const float* __restrict__ proj, const int* __restrict__ slot, float* __restrict__ outp)
{
    __shared__ float skq[16 * 257];
    __shared__ float sctx[M_ * 34];
    __shared__ float sdk[S_], sdq[S_];
    __shared__ float sksum[M_];
    __shared__ float smax[16], sinv[16];
    const int bh = blockIdx.x;
    const int b = bh >> 3, hh = bh & 7;
    const int t = threadIdx.x;
    const float* kb = kg + (size_t)bh * S_ * DH_;
    const float* qb = qg + (size_t)bh * S_ * DH_;
    const float* vb = vg + (size_t)bh * S_ * DH_;
    for (int i = t * 4; i < S_ * DH_; i += 1024)
        *(float4*)&skq[i] = *(const float4*)&kb[i];
    float pr[DH_];
#pragma unroll
    for (int d = 0; d < DH_; d += 4) {
        const float4 p = *(const float4*)&proj[t * DH_ + d];
        pr[d] = p.x; pr[d + 1] = p.y; pr[d + 2] = p.z; pr[d + 3] = p.w;
    }
    __syncthreads();
    const float nrm = 0.42044820762685725f;
    const float diagc = 0.5f * nrm * nrm;
    if (t < S_) {
        float s = 0.f, s2 = 0.f;
#pragma unroll
        for (int d4 = 0; d4 < DH_ / 4; d4++) {
            const float4 kk = *(const float4*)&skq[t * DH_ + d4 * 4];
            s += kk.x * kk.x + kk.y * kk.y + kk.z * kk.z + kk.w * kk.w;
            const float4 qq = *(const float4*)&qb[t * DH_ + d4 * 4];
            s2 += qq.x * qq.x + qq.y * qq.y + qq.z * qq.z + qq.w * qq.w;
        }
        sdk[t] = s * diagc;
        sdq[t] = s2 * diagc;
    }
    __syncthreads();
    float kmaxv;
    { const int iv = *slot; kmaxv = __int_as_float((iv >= 0) ? iv : (iv ^ 0x7fffffff)); }
    const float ratio = 0.0625f;
    {
        float ctx[DH_];
#pragma unroll
        for (int d = 0; d < DH_; d++) ctx[d] = 0.f;
        float ksum = 0.f;
        for (int n = 0; n < S_; n++) {
            float acc = 0.f;
#pragma unroll
            for (int d4 = 0; d4 < DH_ / 4; d4++) {
                const float4 kk = *(const float4*)&skq[n * DH_ + d4 * 4];
                acc += kk.x * pr[d4 * 4 + 0] + kk.y * pr[d4 * 4 + 1]
                     + kk.z * pr[d4 * 4 + 2] + kk.w * pr[d4 * 4 + 3];
            }
            const float kp = ratio * (exp2f((acc * nrm - sdk[n] - kmaxv) * LOG2E) + 1e-4f);
            ksum += kp;
            const float4* v4 = (const float4*)(vb + n * DH_);
#pragma unroll
            for (int d4 = 0; d4 < DH_ / 4; d4++) {
                const float4 vv = v4[d4];
                ctx[d4 * 4 + 0] += kp * vv.x; ctx[d4 * 4 + 1] += kp * vv.y;
                ctx[d4 * 4 + 2] += kp * vv.z; ctx[d4 * 4 + 3] += kp * vv.w;
            }
        }
        sksum[t] = ksum;
#pragma unroll
        for (int d2 = 0; d2 < DH_ / 2; d2++)
            *(float2*)&sctx[t * 34 + d2 * 2] = make_float2(ctx[d2 * 2], ctx[d2 * 2 + 1]);
    }
    __syncthreads();
    const int rr = t >> 4, cc = t & 15;
    const int mc = t >> 7;
    const int rg = (t >> 4) & 7, cg = t & 15;
    for (int tile = 0; tile < 8; tile++) {
        const int n0 = tile * 16;
        float ddr[16];
#pragma unroll
        for (int r = 0; r < 16; r++) {
            const float4* q4 = (const float4*)(qb + (n0 + r) * DH_);
            float acc = 0.f;
#pragma unroll
            for (int d4 = 0; d4 < DH_ / 4; d4++) {
                const float4 qq = q4[d4];
                acc += qq.x * pr[d4 * 4 + 0] + qq.y * pr[d4 * 4 + 1]
                     + qq.z * pr[d4 * 4 + 2] + qq.w * pr[d4 * 4 + 3];
            }
            ddr[r] = acc * nrm;
            skq[r * 257 + t] = ddr[r];
        }
        __syncthreads();
        {
            float mx = -INFINITY;
#pragma unroll
            for (int j = 0; j < 16; j++) mx = fmaxf(mx, skq[rr * 257 + cc + j * 16]);
#pragma unroll
            for (int o = 8; o > 0; o >>= 1) mx = fmaxf(mx, __shfl_xor(mx, o, 64));
            if (cc == 0) smax[rr] = mx;
        }
        __syncthreads();
#pragma unroll
        for (int r = 0; r < 16; r++) {
            const float qp = ratio * (exp2f((ddr[r] - sdq[n0 + r] - smax[r]) * LOG2E) + 1e-4f);
            skq[r * 257 + t] = qp;
        }
        __syncthreads();
        {
            float s = 0.f;
#pragma unroll
            for (int j = 0; j < 16; j++) {
                const int m = cc + j * 16;
                s += skq[rr * 257 + m] * sksum[m];
            }
#pragma unroll
            for (int o = 8; o > 0; o >>= 1) s += __shfl_xor(s, o, 64);
            if (cc == 0) sinv[rr] = 1.0f / s;
        }
        __syncthreads();
        float a00 = 0.f, a01 = 0.f, a10 = 0.f, a11 = 0.f;
        const int r0 = 2 * rg, r1 = 2 * rg + 1, c0 = 2 * cg;
        const int mbase = mc * 128;
        for (int j = 0; j < 128; j++) {
            const int m = mbase + j;
            const float q0 = skq[r0 * 257 + m];
            const float q1 = skq[r1 * 257 + m];
            const float2 cv = *(const float2*)&sctx[m * 34 + c0];
            a00 += q0 * cv.x; a01 += q0 * cv.y;
            a10 += q1 * cv.x; a11 += q1 * cv.y;
        }
        __syncthreads();
        if (mc == 0) {
            *(float2*)&skq[r0 * 32 + c0] = make_float2(a00, a01);
            *(float2*)&skq[r1 * 32 + c0] = make_float2(a10, a11);
        }
        __syncthreads();
        if (mc == 1) {
            const float2 p0 = *(const float2*)&skq[r0 * 32 + c0];
            const float2 p1 = *(const float2*)&skq[r1 * 32 + c0];
            const float i0 = sinv[r0], i1 = sinv[r1];
            float* orow0 = outp + ((size_t)b * S_ + n0 + r0) * D_ + hh * DH_ + c0;
            float* orow1 = outp + ((size_t)b * S_ + n0 + r1) * D_ + hh * DH_ + c0;
            *(float2*)orow0 = make_float2((a00 + p0.x) * i0, (a01 + p0.y) * i0);
            *(float2*)orow1 = make_float2((a10 + p1.x) * i1, (a11 + p1.y) * i1);
        }
        __syncthreads();
    }
}

// ---------- classification head ----------
__global__ void __launch_bounds__(256) k_head(
    const float* __restrict__ hfin, const float* __restrict__ h1w, const float* __restrict__ h1b,
    const float* __restrict__ h2w, const float* __restrict__ h2b,
    const float* __restrict__ ow, const float* __restrict__ ob, float* __restrict__ outp)
{
    __shared__ float c0[D_];
    __shared__ float c1[2 * HID_];
    __shared__ float sred[4];
    const int t = threadIdx.x;
    const int b = blockIdx.x;
    c0[t] = hfin[(size_t)b * S_ * D_ + t];
    __syncthreads();
#pragma unroll
    for (int half = 0; half < 2; half++) {
        const int j = half * 256 + t;
        float a = h1b[j];
        const float* w = h1w + (size_t)j * D_;
        for (int d = 0; d < D_; d += 4) {
            const float4 w4 = *(const float4*)&w[d];
            const float4 x4 = *(const float4*)&c0[d];
            a += x4.x * w4.x + x4.y * w4.y + x4.z * w4.z + x4.w * w4.w;
        }
        c1[j] = (a >= 0.f) ? a : 0.2f * a;
    }
    __syncthreads();
    float a2 = h2b[t];
    const float* w2 = h2w + (size_t)t * (2 * HID_);
    for (int j = 0; j < 2 * HID_; j += 4) {
        const float4 w4 = *(const float4*)&w2[j];
        const float4 x4 = *(const float4*)&c1[j];
        a2 += x4.x * w4.x + x4.y * w4.y + x4.z * w4.z + x4.w * w4.w;
    }
    const float c2 = (a2 >= 0.f) ? a2 : 0.2f * a2;
    const float s = blk_sum(c2 * ow[t], sred);
    if (t == 0) outp[b] = s + ob[0];
}

extern "C" void kernel_launch(void* const* d_in, const int* in_sizes, int n_in,
                              void* d_out, int out_size, void* d_ws, size_t ws_size,
                              hipStream_t stream)
{
    const float* x     = (const float*)d_in[0];
    const int*   mask  = (const int*)d_in[1];
    const float* emb_w = (const float*)d_in[2];
    const float* emb_b = (const float*)d_in[3];
    const float* Wq    = (const float*)d_in[4];
    const float* bq    = (const float*)d_in[5];
    const float* Wk    = (const float*)d_in[6];
    const float* bk    = (const float*)d_in[7];
    const float* Wv    = (const float*)d_in[8];
    const float* bv    = (const float*)d_in[9];
    const float* Wo    = (const float*)d_in[10];
    const float* bo    = (const float*)d_in[11];
    const float* proj  = (const float*)d_in[12];
    const float* n1w   = (const float*)d_in[13];
    const float* n1b   = (const float*)d_in[14];
    const float* n2w   = (const float*)d_in[15];
    const float* n2b   = (const float*)d_in[16];
    const float* f1w   = (const float*)d_in[17];
    const float* f1b   = (const float*)d_in[18];
    const float* f2w   = (const float*)d_in[19];
    const float* f2b   = (const float*)d_in[20];
    const float* h1w   = (const float*)d_in[21];
    const float* h1b   = (const float*)d_in[22];
    const float* h2w   = (const float*)d_in[23];
    const float* h2b   = (const float*)d_in[24];
    const float* ow    = (const float*)d_in[25];
    const float* ob    = (const float*)d_in[26];

    const size_t BSD = (size_t)B_ * S_ * D_;
    float* A = (float*)d_ws;           // h / attn output ping
    float* Q = A + BSD;                // q proj, later ffn hidden
    float* K = Q + BSD;
    float* V = K + BSD;
    float* T = V + BSD;                // post-LN1
    int* slot = (int*)(T + BSD);

    const int GB = B_ * S_ / 64;       // 512 blocks per GEMM

    k_embed<<<B_ * S_ * D_ / 256, 256, 0, stream>>>(x, emb_w, emb_b, A);
    for (int l = 0; l < L_; l++) {
        const size_t lDD = (size_t)l * D_ * D_;
        k_gemm<0><<<GB, 256, 0, stream>>>(A, Wq + lDD, bq + l * D_, nullptr, nullptr, nullptr, Q);
        k_gemm<0><<<GB, 256, 0, stream>>>(A, Wk + lDD, bk + l * D_, nullptr, nullptr, nullptr, K);
        k_gemm<1><<<GB, 256, 0, stream>>>(A, Wv + lDD, bv + l * D_, nullptr, nullptr, mask, V);
        k_reset<<<1, 1, 0, stream>>>(slot);
        k_kmax<<<B_ * H_, 256, 0, stream>>>(K, proj + (size_t)l * M_ * DH_, slot);
        k_attn<<<B_ * H_, 256, 0, stream>>>(Q, K, V, proj + (size_t)l * M_ * DH_, slot, A);
        k_gemm<2><<<GB, 256, 0, stream>>>(A, Wo + lDD, bo + l * D_, n1w + l * D_, n1b + l * D_, nullptr, T);
        k_gemm<3><<<GB, 256, 0, stream>>>(T, f1w + (size_t)l * HID_ * D_, f1b + l * HID_, nullptr, nullptr, nullptr, Q);
        k_gemm<2><<<GB, 256, 0, stream>>>(Q, f2w + (size_t)l * D_ * HID_, f2b + l * D_, n2w + l * D_, n2b + l * D_, nullptr, A);
    }
    k_head<<<B_, 256, 0, stream>>>(A, h1w, h1b, h2w, h2b, ow, ob, (float*)d_out);
}

// Round 5
// 3354.095 us; speedup vs baseline: 2.2178x; 1.2656x over previous
//
#include <hip/hip_runtime.h>
#include <math.h>

#define B_ 256
#define N_ 127
#define S_ 128
#define NDIM_ 3
#define D_ 256
#define H_ 8
#define DH_ 32
#define M_ 256
#define HID_ 256
#define L_ 4
#define LOG2E 1.44269504088896340736f

typedef __attribute__((ext_vector_type(8))) short short8;
typedef __attribute__((ext_vector_type(4))) float floatx4;

// ---------- bf16 split helpers ----------
__device__ __forceinline__ ushort bf16_rn(float x) {
    unsigned u = __float_as_uint(x);
    u = (u + 0x7fffu + ((u >> 16) & 1u)) >> 16;
    return (ushort)u;
}
// x -> hi,lo bf16; hh = ushorts [h,h], ll = [l,l]
__device__ __forceinline__ void split2(float x, unsigned& hh, unsigned& ll) {
    const ushort h = bf16_rn(x);
    const float r = x - __uint_as_float(((unsigned)h) << 16);
    const ushort l = bf16_rn(r);
    hh = (unsigned)h * 0x10001u;
    ll = (unsigned)l * 0x10001u;
}

// ---------- block reductions ----------
__device__ __forceinline__ float blk_sum(float v, float* sred) {
#pragma unroll
    for (int o = 32; o > 0; o >>= 1) v += __shfl_xor(v, o, 64);
    if ((threadIdx.x & 63) == 0) sred[threadIdx.x >> 6] = v;
    __syncthreads();
    v = sred[0] + sred[1] + sred[2] + sred[3];
    __syncthreads();
    return v;
}
__device__ __forceinline__ float blk_max(float v, float* sred) {
#pragma unroll
    for (int o = 32; o > 0; o >>= 1) v = fmaxf(v, __shfl_xor(v, o, 64));
    if ((threadIdx.x & 63) == 0) sred[threadIdx.x >> 6] = v;
    __syncthreads();
    v = fmaxf(fmaxf(sred[0], sred[1]), fmaxf(sred[2], sred[3]));
    __syncthreads();
    return v;
}

// ---------- embedding ----------
__global__ void k_embed(const float* __restrict__ x, const float* __restrict__ ew,
                        const float* __restrict__ eb, float* __restrict__ h) {
    const int idx = blockIdx.x * 256 + threadIdx.x;
    const int d = idx & (D_ - 1);
    const int n = (idx >> 8) & (S_ - 1);
    const int b = idx >> 15;
    float val = 0.f;
    if (n > 0) {
        const float* xr = x + ((size_t)b * N_ + (n - 1)) * NDIM_;
        val = eb[d] + xr[0] * ew[d * 3 + 0] + xr[1] * ew[d * 3 + 1] + xr[2] * ew[d * 3 + 2];
    }
    h[idx] = val;
}

// ---------- weight pre-split (compact): fp32 -> uint [h|l<<16], same index ----------
__global__ void __launch_bounds__(256) k_wconv(const float* __restrict__ src, unsigned* __restrict__ dst) {
    const int idx = (blockIdx.x * 256 + threadIdx.x) * 4;  // over L*D*D = 262144 f32
    const float4 w4 = *(const float4*)&src[idx];
    const float v[4] = {w4.x, w4.y, w4.z, w4.w};
    unsigned u[4];
#pragma unroll
    for (int i = 0; i < 4; i++) {
        const ushort h = bf16_rn(v[i]);
        const float r = v[i] - __uint_as_float(((unsigned)h) << 16);
        const ushort l = bf16_rn(r);
        u[i] = (unsigned)h | ((unsigned)l << 16);   // ushorts [h, l]
    }
    *(uint4*)&dst[idx] = make_uint4(u[0], u[1], u[2], u[3]);
}

// ---------- MFMA bf16x2-split GEMM: C[64 x 256] per block, K2 = 1024 ----------
// Per original k: A-pattern {h,h,l,l}, W-pattern {h,l,h,l} -> 4 bf16 products = exact-ish fp32.
// LDS layout: chunked [k2-chunk c][row][8 ushorts] so all b128 LDS ops are lane-stride-16B.
// EPI: 0 = q/k layout [b,h,n,dh]; 1 = + keep-mask (v); 2 = LayerNorm; 3 = leaky.
template<int EPI>
__global__ void __launch_bounds__(256) k_gemm(
    const float* __restrict__ A, const unsigned* __restrict__ W2,
    const float* __restrict__ bias, const float* __restrict__ g1,
    const float* __restrict__ g2, const int* __restrict__ mask,
    float* __restrict__ out)
{
    __shared__ ushort A2s[4 * 64 * 8];     // [c][row][8]
    __shared__ ushort W2s[4 * 256 * 8];    // [c][col][8]
    __shared__ float sredA[64][2], sredB[64][2];
    const int t = threadIdx.x;
    const int w = t >> 6, lane = t & 63;
    const int quad = lane >> 4, l16 = lane & 15;
    const int rowbase = 32 * (w >> 1), colbase = 128 * (w & 1);
    const int row0 = blockIdx.x * 64;

    floatx4 acc[2][8];
#pragma unroll
    for (int rt = 0; rt < 2; rt++)
#pragma unroll
        for (int ct = 0; ct < 8; ct++) acc[rt][ct] = (floatx4){0.f, 0.f, 0.f, 0.f};

    const int srow = t >> 2, skq = t & 3;
    const float* Arow = A + (size_t)(row0 + srow) * D_ + skq * 2;
    const unsigned* Wrow = W2 + (size_t)t * 256;

    for (int s = 0; s < 32; s++) {
        __syncthreads();
        {   // A stage: originals k = 8s + skq*2, +1 -> chunk skq
            const float2 a2 = *(const float2*)(Arow + s * 8);
            unsigned hh0, ll0, hh1, ll1;
            split2(a2.x, hh0, ll0); split2(a2.y, hh1, ll1);
            *(uint4*)&A2s[skq * 512 + srow * 8] = make_uint4(hh0, ll0, hh1, ll1);
        }
        {   // W stage: col = t; 8 originals -> 4 chunks, each uint duplicated = {h,l,h,l}
            const uint4* wp = (const uint4*)(Wrow + s * 8);
            const uint4 w0 = wp[0], w1 = wp[1];
            *(uint4*)&W2s[0 * 2048 + t * 8] = make_uint4(w0.x, w0.x, w0.y, w0.y);
            *(uint4*)&W2s[1 * 2048 + t * 8] = make_uint4(w0.z, w0.z, w0.w, w0.w);
            *(uint4*)&W2s[2 * 2048 + t * 8] = make_uint4(w1.x, w1.x, w1.y, w1.y);
            *(uint4*)&W2s[3 * 2048 + t * 8] = make_uint4(w1.z, w1.z, w1.w, w1.w);
        }
        __syncthreads();
        short8 af[2], bf[8];
#pragma unroll
        for (int rt = 0; rt < 2; rt++)
            af[rt] = *(const short8*)&A2s[quad * 512 + (rowbase + 16 * rt + l16) * 8];
#pragma unroll
        for (int ct = 0; ct < 8; ct++)
            bf[ct] = *(const short8*)&W2s[quad * 2048 + (colbase + 16 * ct + l16) * 8];
#pragma unroll
        for (int rt = 0; rt < 2; rt++)
#pragma unroll
            for (int ct = 0; ct < 8; ct++)
                acc[rt][ct] = __builtin_amdgcn_mfma_f32_16x16x32_bf16(af[rt], bf[ct], acc[rt][ct], 0, 0, 0);
    }

    int colv[8]; float bv[8];
#pragma unroll
    for (int ct = 0; ct < 8; ct++) { colv[ct] = colbase + 16 * ct + l16; bv[ct] = bias[colv[ct]]; }

    if (EPI <= 1) {
        const int b = row0 >> 7;
#pragma unroll
        for (int rt = 0; rt < 2; rt++)
#pragma unroll
        for (int i = 0; i < 4; i++) {
            const int rl = rowbase + 16 * rt + quad * 4 + i;
            const int n = (row0 + rl) & (S_ - 1);
            float keep = 1.f;
            if (EPI == 1) keep = (n == 0) ? 1.f : (mask[b * N_ + n - 1] ? 0.f : 1.f);
#pragma unroll
            for (int ct = 0; ct < 8; ct++) {
                float c = acc[rt][ct][i] + bv[ct];
                if (EPI == 1) c *= keep;
                const int col = colv[ct];
                out[(((size_t)b * H_ + (col >> 5)) * S_ + n) * DH_ + (col & 31)] = c;
            }
        }
    } else if (EPI == 2) {
        float gv[8], bbv[8];
#pragma unroll
        for (int ct = 0; ct < 8; ct++) { gv[ct] = g1[colv[ct]]; bbv[ct] = g2[colv[ct]]; }
#pragma unroll
        for (int rt = 0; rt < 2; rt++)
#pragma unroll
        for (int i = 0; i < 4; i++) {
            const int rl = rowbase + 16 * rt + quad * 4 + i;
            float s = 0.f, s2 = 0.f;
#pragma unroll
            for (int ct = 0; ct < 8; ct++) {
                const float c = acc[rt][ct][i] + bv[ct];
                s += c; s2 += c * c;
            }
#pragma unroll
            for (int o = 8; o > 0; o >>= 1) { s += __shfl_xor(s, o, 64); s2 += __shfl_xor(s2, o, 64); }
            if (l16 == 0) { sredA[rl][w & 1] = s; sredB[rl][w & 1] = s2; }
        }
        __syncthreads();
#pragma unroll
        for (int rt = 0; rt < 2; rt++)
#pragma unroll
        for (int i = 0; i < 4; i++) {
            const int rl = rowbase + 16 * rt + quad * 4 + i;
            const float s = sredA[rl][0] + sredA[rl][1];
            const float s2 = sredB[rl][0] + sredB[rl][1];
            const float mu = s * (1.f / D_);
            const float rs = rsqrtf(s2 * (1.f / D_) - mu * mu + 1e-5f);
#pragma unroll
            for (int ct = 0; ct < 8; ct++) {
                const float c = acc[rt][ct][i] + bv[ct];
                out[(size_t)(row0 + rl) * D_ + colv[ct]] = (c - mu) * rs * gv[ct] + bbv[ct];
            }
        }
    } else {
#pragma unroll
        for (int rt = 0; rt < 2; rt++)
#pragma unroll
        for (int i = 0; i < 4; i++) {
            const int rl = rowbase + 16 * rt + quad * 4 + i;
#pragma unroll
            for (int ct = 0; ct < 8; ct++) {
                const float c = acc[rt][ct][i] + bv[ct];
                out[(size_t)(row0 + rl) * D_ + colv[ct]] = (c >= 0.f) ? c : 0.2f * c;
            }
        }
    }
}

// ---------- ordered-int float max helpers ----------
__global__ void k_reset(int* slot) {
    const int i = __float_as_int(-INFINITY);
    *slot = (i >= 0) ? i : (i ^ 0x7fffffff);
}

__global__ void __launch_bounds__(256) k_kmax(
    const float* __restrict__ kg, const float* __restrict__ proj, int* __restrict__ slot)
{
    __shared__ float sk[S_ * DH_];
    __shared__ float sred[4];
    const int t = threadIdx.x;
    const float* kb = kg + (size_t)blockIdx.x * S_ * DH_;
    for (int i = t * 4; i < S_ * DH_; i += 1024)
        *(float4*)&sk[i] = *(const float4*)&kb[i];
    float pr[DH_];
#pragma unroll
    for (int d = 0; d < DH_; d += 4) {
        const float4 p = *(const float4*)&proj[t * DH_ + d];
        pr[d] = p.x; pr[d + 1] = p.y; pr[d + 2] = p.z; pr[d + 3] = p.w;
    }
    __syncthreads();
    const float nrm = 0.42044820762685725f;
    float mx = -INFINITY;
    for (int n = 0; n < S_; n++) {
        float acc = 0.f;
#pragma unroll
        for (int d = 0; d < DH_; d++) acc += sk[n * DH_ + d] * pr[d];
        mx = fmaxf(mx, acc * nrm);
    }
    mx = blk_max(mx, sred);
    if (t == 0) {
        const int i = __float_as_int(mx);
        atomicMax(slot, (i >= 0) ? i : (i ^ 0x7fffffff));
    }
}

// ---------- fused performer attention, one block per (b,h) ----------
__global__ void __launch_bounds__(256) k_attn(
    const float* __restrict__ qg, const float* __restrict__ kg, const float* __restrict__ vg,
    const float* __restrict__ proj, const int* __restrict__ slot, float* __restrict__ outp)
{
    __shared__ float skq[16 * 257];
    __shared__ float sctx[M_ * 34];
    __shared__ float sdk[S_], sdq[S_];
    __shared__ float sksum[M_];
    __shared__ float smax[16], sinv[16];
    const int bh = blockIdx.x;
    const int b = bh >> 3, hh = bh & 7;
    const int t = threadIdx.x;
    const float* kb = kg + (size_t)bh * S_ * DH_;
    const float* qb = qg + (size_t)bh * S_ * DH_;
    const float* vb = vg + (size_t)bh * S_ * DH_;
    for (int i = t * 4; i < S_ * DH_; i += 1024)
        *(float4*)&skq[i] = *(const float4*)&kb[i];
    float pr[DH_];
#pragma unroll
    for (int d = 0; d < DH_; d += 4) {
        const float4 p = *(const float4*)&proj[t * DH_ + d];
        pr[d] = p.x; pr[d + 1] = p.y; pr[d + 2] = p.z; pr[d + 3] = p.w;
    }
    __syncthreads();
    const float nrm = 0.42044820762685725f;
    const float diagc = 0.5f * nrm * nrm;
    if (t < S_) {
        float s = 0.f, s2 = 0.f;
#pragma unroll
        for (int d4 = 0; d4 < DH_ / 4; d4++) {
            const float4 kk = *(const float4*)&skq[t * DH_ + d4 * 4];
            s += kk.x * kk.x + kk.y * kk.y + kk.z * kk.z + kk.w * kk.w;
            const float4 qq = *(const float4*)&qb[t * DH_ + d4 * 4];
            s2 += qq.x * qq.x + qq.y * qq.y + qq.z * qq.z + qq.w * qq.w;
        }
        sdk[t] = s * diagc;
        sdq[t] = s2 * diagc;
    }
    __syncthreads();
    float kmaxv;
    { const int iv = *slot; kmaxv = __int_as_float((iv >= 0) ? iv : (iv ^ 0x7fffffff)); }
    const float ratio = 0.0625f;
    {
        float ctx[DH_];
#pragma unroll
        for (int d = 0; d < DH_; d++) ctx[d] = 0.f;
        float ksum = 0.f;
        for (int n = 0; n < S_; n++) {
            float acc = 0.f;
#pragma unroll
            for (int d4 = 0; d4 < DH_ / 4; d4++) {
                const float4 kk = *(const float4*)&skq[n * DH_ + d4 * 4];
                acc += kk.x * pr[d4 * 4 + 0] + kk.y * pr[d4 * 4 + 1]
                     + kk.z * pr[d4 * 4 + 2] + kk.w * pr[d4 * 4 + 3];
            }
            const float kp = ratio * (exp2f((acc * nrm - sdk[n] - kmaxv) * LOG2E) + 1e-4f);
            ksum += kp;
            const float4* v4 = (const float4*)(vb + n * DH_);
#pragma unroll
            for (int d4 = 0; d4 < DH_ / 4; d4++) {
                const float4 vv = v4[d4];
                ctx[d4 * 4 + 0] += kp * vv.x; ctx[d4 * 4 + 1] += kp * vv.y;
                ctx[d4 * 4 + 2] += kp * vv.z; ctx[d4 * 4 + 3] += kp * vv.w;
            }
        }
        sksum[t] = ksum;
#pragma unroll
        for (int d2 = 0; d2 < DH_ / 2; d2++)
            *(float2*)&sctx[t * 34 + d2 * 2] = make_float2(ctx[d2 * 2], ctx[d2 * 2 + 1]);
    }
    __syncthreads();
    const int rr = t >> 4, cc = t & 15;
    const int mc = t >> 7;
    const int rg = (t >> 4) & 7, cg = t & 15;
    for (int tile = 0; tile < 8; tile++) {
        const int n0 = tile * 16;
        float ddr[16];
#pragma unroll
        for (int r = 0; r < 16; r++) {
            const float4* q4 = (const float4*)(qb + (n0 + r) * DH_);
            float acc = 0.f;
#pragma unroll
            for (int d4 = 0; d4 < DH_ / 4; d4++) {
                const float4 qq = q4[d4];
                acc += qq.x * pr[d4 * 4 + 0] + qq.y * pr[d4 * 4 + 1]
                     + qq.z * pr[d4 * 4 + 2] + qq.w * pr[d4 * 4 + 3];
            }
            ddr[r] = acc * nrm;
            skq[r * 257 + t] = ddr[r];
        }
        __syncthreads();
        {
            float mx = -INFINITY;
#pragma unroll
            for (int j = 0; j < 16; j++) mx = fmaxf(mx, skq[rr * 257 + cc + j * 16]);
#pragma unroll
            for (int o = 8; o > 0; o >>= 1) mx = fmaxf(mx, __shfl_xor(mx, o, 64));
            if (cc == 0) smax[rr] = mx;
        }
        __syncthreads();
#pragma unroll
        for (int r = 0; r < 16; r++) {
            const float qp = ratio * (exp2f((ddr[r] - sdq[n0 + r] - smax[r]) * LOG2E) + 1e-4f);
            skq[r * 257 + t] = qp;
        }
        __syncthreads();
        {
            float s = 0.f;
#pragma unroll
            for (int j = 0; j < 16; j++) {
                const int m = cc + j * 16;
                s += skq[rr * 257 + m] * sksum[m];
            }
#pragma unroll
            for (int o = 8; o > 0; o >>= 1) s += __shfl_xor(s, o, 64);
            if (cc == 0) sinv[rr] = 1.0f / s;
        }
        __syncthreads();
        float a00 = 0.f, a01 = 0.f, a10 = 0.f, a11 = 0.f;
        const int r0 = 2 * rg, r1 = 2 * rg + 1, c0 = 2 * cg;
        const int mbase = mc * 128;
        for (int j = 0; j < 128; j++) {
            const int m = mbase + j;
            const float q0 = skq[r0 * 257 + m];
            const float q1 = skq[r1 * 257 + m];
            const float2 cv = *(const float2*)&sctx[m * 34 + c0];
            a00 += q0 * cv.x; a01 += q0 * cv.y;
            a10 += q1 * cv.x; a11 += q1 * cv.y;
        }
        __syncthreads();
        if (mc == 0) {
            *(float2*)&skq[r0 * 32 + c0] = make_float2(a00, a01);
            *(float2*)&skq[r1 * 32 + c0] = make_float2(a10, a11);
        }
        __syncthreads();
        if (mc == 1) {
            const float2 p0 = *(const float2*)&skq[r0 * 32 + c0];
            const float2 p1 = *(const float2*)&skq[r1 * 32 + c0];
            const float i0 = sinv[r0], i1 = sinv[r1];
            float* orow0 = outp + ((size_t)b * S_ + n0 + r0) * D_ + hh * DH_ + c0;
            float* orow1 = outp + ((size_t)b * S_ + n0 + r1) * D_ + hh * DH_ + c0;
            *(float2*)orow0 = make_float2((a00 + p0.x) * i0, (a01 + p0.y) * i0);
            *(float2*)orow1 = make_float2((a10 + p1.x) * i1, (a11 + p1.y) * i1);
        }
        __syncthreads();
    }
}

// ---------- classification head ----------
__global__ void __launch_bounds__(256) k_head(
    const float* __restrict__ hfin, const float* __restrict__ h1w, const float* __restrict__ h1b,
    const float* __restrict__ h2w, const float* __restrict__ h2b,
    const float* __restrict__ ow, const float* __restrict__ ob, float* __restrict__ outp)
{
    __shared__ float c0[D_];
    __shared__ float c1[2 * HID_];
    __shared__ float sred[4];
    const int t = threadIdx.x;
    const int b = blockIdx.x;
    c0[t] = hfin[(size_t)b * S_ * D_ + t];
    __syncthreads();
#pragma unroll
    for (int half = 0; half < 2; half++) {
        const int j = half * 256 + t;
        float a = h1b[j];
        const float* w = h1w + (size_t)j * D_;
        for (int d = 0; d < D_; d += 4) {
            const float4 w4 = *(const float4*)&w[d];
            const float4 x4 = *(const float4*)&c0[d];
            a += x4.x * w4.x + x4.y * w4.y + x4.z * w4.z + x4.w * w4.w;
        }
        c1[j] = (a >= 0.f) ? a : 0.2f * a;
    }
    __syncthreads();
    float a2 = h2b[t];
    const float* w2 = h2w + (size_t)t * (2 * HID_);
    for (int j = 0; j < 2 * HID_; j += 4) {
        const float4 w4 = *(const float4*)&w2[j];
        const float4 x4 = *(const float4*)&c1[j];
        a2 += x4.x * w4.x + x4.y * w4.y + x4.z * w4.z + x4.w * w4.w;
    }
    const float c2 = (a2 >= 0.f) ? a2 : 0.2f * a2;
    const float s = blk_sum(c2 * ow[t], sred);
    if (t == 0) outp[b] = s + ob[0];
}

extern "C" void kernel_launch(void* const* d_in, const int* in_sizes, int n_in,
                              void* d_out, int out_size, void* d_ws, size_t ws_size,
                              hipStream_t stream)
{
    const float* x     = (const float*)d_in[0];
    const int*   mask  = (const int*)d_in[1];
    const float* emb_w = (const float*)d_in[2];
    const float* emb_b = (const float*)d_in[3];
    const float* Wq    = (const float*)d_in[4];
    const float* bq    = (const float*)d_in[5];
    const float* Wk    = (const float*)d_in[6];
    const float* bk    = (const float*)d_in[7];
    const float* Wv    = (const float*)d_in[8];
    const float* bv    = (const float*)d_in[9];
    const float* Wo    = (const float*)d_in[10];
    const float* bo    = (const float*)d_in[11];
    const float* proj  = (const float*)d_in[12];
    const float* n1w   = (const float*)d_in[13];
    const float* n1b   = (const float*)d_in[14];
    const float* n2w   = (const float*)d_in[15];
    const float* n2b   = (const float*)d_in[16];
    const float* f1w   = (const float*)d_in[17];
    const float* f1b   = (const float*)d_in[18];
    const float* f2w   = (const float*)d_in[19];
    const float* f2b   = (const float*)d_in[20];
    const float* h1w   = (const float*)d_in[21];
    const float* h1b   = (const float*)d_in[22];
    const float* h2w   = (const float*)d_in[23];
    const float* h2b   = (const float*)d_in[24];
    const float* ow    = (const float*)d_in[25];
    const float* ob    = (const float*)d_in[26];

    const size_t BSD = (size_t)B_ * S_ * D_;
    float* A = (float*)d_ws;           // h / attn output ping
    float* Q = A + BSD;                // q proj, later ffn hidden
    float* K = Q + BSD;                // k proj; T aliases K (K dead after k_attn)
    float* V = K + BSD;
    float* T = K;                      // post-LN1 (alias)
    unsigned* W2 = (unsigned*)(V + BSD);   // compact split weights: 6 x L x 256 x 256 uints
    const size_t WT = (size_t)L_ * 256 * 256;   // uints per tensor
    const size_t WM = (size_t)256 * 256;        // uints per matrix
    int* slot = (int*)(W2 + 6 * WT);

    k_wconv<<<256, 256, 0, stream>>>(Wq,  W2 + 0 * WT);
    k_wconv<<<256, 256, 0, stream>>>(Wk,  W2 + 1 * WT);
    k_wconv<<<256, 256, 0, stream>>>(Wv,  W2 + 2 * WT);
    k_wconv<<<256, 256, 0, stream>>>(Wo,  W2 + 3 * WT);
    k_wconv<<<256, 256, 0, stream>>>(f1w, W2 + 4 * WT);
    k_wconv<<<256, 256, 0, stream>>>(f2w, W2 + 5 * WT);

    const int GB = B_ * S_ / 64;       // 512 blocks per GEMM

    k_embed<<<B_ * S_ * D_ / 256, 256, 0, stream>>>(x, emb_w, emb_b, A);
    for (int l = 0; l < L_; l++) {
        k_gemm<0><<<GB, 256, 0, stream>>>(A, W2 + 0 * WT + l * WM, bq + l * D_, nullptr, nullptr, nullptr, Q);
        k_gemm<0><<<GB, 256, 0, stream>>>(A, W2 + 1 * WT + l * WM, bk + l * D_, nullptr, nullptr, nullptr, K);
        k_gemm<1><<<GB, 256, 0, stream>>>(A, W2 + 2 * WT + l * WM, bv + l * D_, nullptr, nullptr, mask, V);
        k_reset<<<1, 1, 0, stream>>>(slot);
        k_kmax<<<B_ * H_, 256, 0, stream>>>(K, proj + (size_t)l * M_ * DH_, slot);
        k_attn<<<B_ * H_, 256, 0, stream>>>(Q, K, V, proj + (size_t)l * M_ * DH_, slot, A);
        k_gemm<2><<<GB, 256, 0, stream>>>(A, W2 + 3 * WT + l * WM, bo + l * D_, n1w + l * D_, n1b + l * D_, nullptr, T);
        k_gemm<3><<<GB, 256, 0, stream>>>(T, W2 + 4 * WT + l * WM, f1b + l * HID_, nullptr, nullptr, nullptr, Q);
        k_gemm<2><<<GB, 256, 0, stream>>>(Q, W2 + 5 * WT + l * WM, f2b + l * D_, n2w + l * D_, n2b + l * D_, nullptr, A);
    }
    k_head<<<B_, 256, 0, stream>>>(A, h1w, h1b, h2w, h2b, ow, ob, (float*)d_out);
}

// Round 6
// 3317.580 us; speedup vs baseline: 2.2423x; 1.0110x over previous
//
#include <hip/hip_runtime.h>
#include <math.h>

#define B_ 256
#define N_ 127
#define S_ 128
#define NDIM_ 3
#define D_ 256
#define H_ 8
#define DH_ 32
#define M_ 256
#define HID_ 256
#define L_ 4
#define LOG2E 1.44269504088896340736f

typedef __attribute__((ext_vector_type(8))) short short8;
typedef __attribute__((ext_vector_type(4))) float floatx4;

// ---------- bf16 split helpers ----------
__device__ __forceinline__ ushort bf16_rn(float x) {
    unsigned u = __float_as_uint(x);
    u = (u + 0x7fffu + ((u >> 16) & 1u)) >> 16;
    return (ushort)u;
}
__device__ __forceinline__ void split2(float x, unsigned& hh, unsigned& ll) {
    const ushort h = bf16_rn(x);
    const float r = x - __uint_as_float(((unsigned)h) << 16);
    const ushort l = bf16_rn(r);
    hh = (unsigned)h * 0x10001u;   // ushorts [h, h]
    ll = (unsigned)l * 0x10001u;   // ushorts [l, l]
}

// ---------- block reductions ----------
__device__ __forceinline__ float blk_sum(float v, float* sred) {
#pragma unroll
    for (int o = 32; o > 0; o >>= 1) v += __shfl_xor(v, o, 64);
    if ((threadIdx.x & 63) == 0) sred[threadIdx.x >> 6] = v;
    __syncthreads();
    v = sred[0] + sred[1] + sred[2] + sred[3];
    __syncthreads();
    return v;
}

// ---------- embedding ----------
__global__ void k_embed(const float* __restrict__ x, const float* __restrict__ ew,
                        const float* __restrict__ eb, float* __restrict__ h) {
    const int idx = blockIdx.x * 256 + threadIdx.x;
    const int d = idx & (D_ - 1);
    const int n = (idx >> 8) & (S_ - 1);
    const int b = idx >> 15;
    float val = 0.f;
    if (n > 0) {
        const float* xr = x + ((size_t)b * N_ + (n - 1)) * NDIM_;
        val = eb[d] + xr[0] * ew[d * 3 + 0] + xr[1] * ew[d * 3 + 1] + xr[2] * ew[d * 3 + 2];
    }
    h[idx] = val;
}

// ---------- weight pre-split (compact): fp32 -> uint [h|l<<16], same index ----------
__global__ void __launch_bounds__(256) k_wconv(const float* __restrict__ src, unsigned* __restrict__ dst) {
    const int idx = (blockIdx.x * 256 + threadIdx.x) * 4;
    const float4 w4 = *(const float4*)&src[idx];
    const float v[4] = {w4.x, w4.y, w4.z, w4.w};
    unsigned u[4];
#pragma unroll
    for (int i = 0; i < 4; i++) {
        const ushort h = bf16_rn(v[i]);
        const float r = v[i] - __uint_as_float(((unsigned)h) << 16);
        const ushort l = bf16_rn(r);
        u[i] = (unsigned)h | ((unsigned)l << 16);
    }
    *(uint4*)&dst[idx] = make_uint4(u[0], u[1], u[2], u[3]);
}

// ---------- MFMA bf16x2-split GEMM: C[64 x 256] per block, K2 = 1024 ----------
template<int EPI>
__global__ void __launch_bounds__(256) k_gemm(
    const float* __restrict__ A, const unsigned* __restrict__ W2,
    const float* __restrict__ bias, const float* __restrict__ g1,
    const float* __restrict__ g2, const int* __restrict__ mask,
    float* __restrict__ out)
{
    __shared__ ushort A2s[4 * 64 * 8];     // [c][row][8]
    __shared__ ushort W2s[4 * 256 * 8];    // [c][col][8]
    __shared__ float sredA[64][2], sredB[64][2];
    const int t = threadIdx.x;
    const int w = t >> 6, lane = t & 63;
    const int quad = lane >> 4, l16 = lane & 15;
    const int rowbase = 32 * (w >> 1), colbase = 128 * (w & 1);
    const int row0 = blockIdx.x * 64;

    floatx4 acc[2][8];
#pragma unroll
    for (int rt = 0; rt < 2; rt++)
#pragma unroll
        for (int ct = 0; ct < 8; ct++) acc[rt][ct] = (floatx4){0.f, 0.f, 0.f, 0.f};

    const int srow = t >> 2, skq = t & 3;
    const float* Arow = A + (size_t)(row0 + srow) * D_ + skq * 2;
    const unsigned* Wrow = W2 + (size_t)t * 256;

    for (int s = 0; s < 32; s++) {
        __syncthreads();
        {
            const float2 a2 = *(const float2*)(Arow + s * 8);
            unsigned hh0, ll0, hh1, ll1;
            split2(a2.x, hh0, ll0); split2(a2.y, hh1, ll1);
            *(uint4*)&A2s[skq * 512 + srow * 8] = make_uint4(hh0, ll0, hh1, ll1);
        }
        {
            const uint4* wp = (const uint4*)(Wrow + s * 8);
            const uint4 w0 = wp[0], w1 = wp[1];
            *(uint4*)&W2s[0 * 2048 + t * 8] = make_uint4(w0.x, w0.x, w0.y, w0.y);
            *(uint4*)&W2s[1 * 2048 + t * 8] = make_uint4(w0.z, w0.z, w0.w, w0.w);
            *(uint4*)&W2s[2 * 2048 + t * 8] = make_uint4(w1.x, w1.x, w1.y, w1.y);
            *(uint4*)&W2s[3 * 2048 + t * 8] = make_uint4(w1.z, w1.z, w1.w, w1.w);
        }
        __syncthreads();
        short8 af[2], bf[8];
#pragma unroll
        for (int rt = 0; rt < 2; rt++)
            af[rt] = *(const short8*)&A2s[quad * 512 + (rowbase + 16 * rt + l16) * 8];
#pragma unroll
        for (int ct = 0; ct < 8; ct++)
            bf[ct] = *(const short8*)&W2s[quad * 2048 + (colbase + 16 * ct + l16) * 8];
#pragma unroll
        for (int rt = 0; rt < 2; rt++)
#pragma unroll
            for (int ct = 0; ct < 8; ct++)
                acc[rt][ct] = __builtin_amdgcn_mfma_f32_16x16x32_bf16(af[rt], bf[ct], acc[rt][ct], 0, 0, 0);
    }

    int colv[8]; float bv[8];
#pragma unroll
    for (int ct = 0; ct < 8; ct++) { colv[ct] = colbase + 16 * ct + l16; bv[ct] = bias[colv[ct]]; }

    if (EPI <= 1) {
        const int b = row0 >> 7;
#pragma unroll
        for (int rt = 0; rt < 2; rt++)
#pragma unroll
        for (int i = 0; i < 4; i++) {
            const int rl = rowbase + 16 * rt + quad * 4 + i;
            const int n = (row0 + rl) & (S_ - 1);
            float keep = 1.f;
            if (EPI == 1) keep = (n == 0) ? 1.f : (mask[b * N_ + n - 1] ? 0.f : 1.f);
#pragma unroll
            for (int ct = 0; ct < 8; ct++) {
                float c = acc[rt][ct][i] + bv[ct];
                if (EPI == 1) c *= keep;
                const int col = colv[ct];
                out[(((size_t)b * H_ + (col >> 5)) * S_ + n) * DH_ + (col & 31)] = c;
            }
        }
    } else if (EPI == 2) {
        float gv[8], bbv[8];
#pragma unroll
        for (int ct = 0; ct < 8; ct++) { gv[ct] = g1[colv[ct]]; bbv[ct] = g2[colv[ct]]; }
#pragma unroll
        for (int rt = 0; rt < 2; rt++)
#pragma unroll
        for (int i = 0; i < 4; i++) {
            const int rl = rowbase + 16 * rt + quad * 4 + i;
            float s = 0.f, s2 = 0.f;
#pragma unroll
            for (int ct = 0; ct < 8; ct++) {
                const float c = acc[rt][ct][i] + bv[ct];
                s += c; s2 += c * c;
            }
#pragma unroll
            for (int o = 8; o > 0; o >>= 1) { s += __shfl_xor(s, o, 64); s2 += __shfl_xor(s2, o, 64); }
            if (l16 == 0) { sredA[rl][w & 1] = s; sredB[rl][w & 1] = s2; }
        }
        __syncthreads();
#pragma unroll
        for (int rt = 0; rt < 2; rt++)
#pragma unroll
        for (int i = 0; i < 4; i++) {
            const int rl = rowbase + 16 * rt + quad * 4 + i;
            const float s = sredA[rl][0] + sredA[rl][1];
            const float s2 = sredB[rl][0] + sredB[rl][1];
            const float mu = s * (1.f / D_);
            const float rs = rsqrtf(s2 * (1.f / D_) - mu * mu + 1e-5f);
#pragma unroll
            for (int ct = 0; ct < 8; ct++) {
                const float c = acc[rt][ct][i] + bv[ct];
                out[(size_t)(row0 + rl) * D_ + colv[ct]] = (c - mu) * rs * gv[ct] + bbv[ct];
            }
        }
    } else {
#pragma unroll
        for (int rt = 0; rt < 2; rt++)
#pragma unroll
        for (int i = 0; i < 4; i++) {
            const int rl = rowbase + 16 * rt + quad * 4 + i;
#pragma unroll
            for (int ct = 0; ct < 8; ct++) {
                const float c = acc[rt][ct][i] + bv[ct];
                out[(size_t)(row0 + rl) * D_ + colv[ct]] = (c >= 0.f) ? c : 0.2f * c;
            }
        }
    }
}

// ---------- reset 4 kmax slots ----------
__global__ void k_reset(int* slots) {
    if (threadIdx.x < 4) {
        const int i = __float_as_int(-INFINITY);
        slots[threadIdx.x] = (i >= 0) ? i : (i ^ 0x7fffffff);
    }
}

// ---------- MFMA global k-max: dd_k = nrm * (k . proj_m), atomicMax over all ----------
// Block: 64 rows (bh,n) x 128 cols (m-half). Whole K=32 (K2=128) staged once.
// LDS rows stride 136 ushort (17 x 16B) -> b128 addr16 mod 8 = row+chunk: BW-floor even.
__global__ void __launch_bounds__(256) k_dmax(
    const float* __restrict__ kg, const unsigned* __restrict__ P2, int* __restrict__ slot)
{
    __shared__ __align__(16) ushort A2s[64 * 136];
    __shared__ __align__(16) ushort Ps[128 * 136];
    __shared__ float sred[4];
    const int t = threadIdx.x;
    const size_t row0 = (size_t)(blockIdx.x >> 1) * 64;
    const int m0 = (blockIdx.x & 1) * 128;
    {   // A stage: row = t>>2, 8 orig k at kq -> chunks (t&3)*4 .. +3, pattern {h,h,l,l}
        const int row = t >> 2, kq = (t & 3) * 8;
        const float* src = kg + (row0 + row) * DH_ + kq;
        const float4 f0 = *(const float4*)src;
        const float4 f1 = *(const float4*)(src + 4);
        const float vv[8] = {f0.x, f0.y, f0.z, f0.w, f1.x, f1.y, f1.z, f1.w};
#pragma unroll
        for (int i = 0; i < 4; i++) {
            unsigned hh0, ll0, hh1, ll1;
            split2(vv[2 * i], hh0, ll0); split2(vv[2 * i + 1], hh1, ll1);
            *(uint4*)&A2s[row * 136 + ((t & 3) * 4 + i) * 8] = make_uint4(hh0, ll0, hh1, ll1);
        }
    }
    {   // P stage: 2 threads/col, pattern {h,l,h,l} (uint duplicated)
        const int col = t >> 1;
        const unsigned* src = P2 + (m0 + col) * DH_ + (t & 1) * 16;
#pragma unroll
        for (int i = 0; i < 8; i++) {
            const unsigned u0 = src[2 * i], u1 = src[2 * i + 1];
            *(uint4*)&Ps[col * 136 + ((t & 1) * 8 + i) * 8] = make_uint4(u0, u0, u1, u1);
        }
    }
    __syncthreads();
    const int w = t >> 6, lane = t & 63, quad = lane >> 4, l16 = lane & 15;
    floatx4 acc[4][2];
#pragma unroll
    for (int rt = 0; rt < 4; rt++)
#pragma unroll
        for (int ct = 0; ct < 2; ct++) acc[rt][ct] = (floatx4){0.f, 0.f, 0.f, 0.f};
#pragma unroll
    for (int kk = 0; kk < 4; kk++) {
        short8 af[4], bf[2];
#pragma unroll
        for (int rt = 0; rt < 4; rt++)
            af[rt] = *(const short8*)&A2s[(rt * 16 + l16) * 136 + (kk * 4 + quad) * 8];
#pragma unroll
        for (int ct = 0; ct < 2; ct++)
            bf[ct] = *(const short8*)&Ps[((w * 2 + ct) * 16 + l16) * 136 + (kk * 4 + quad) * 8];
#pragma unroll
        for (int rt = 0; rt < 4; rt++)
#pragma unroll
            for (int ct = 0; ct < 2; ct++)
                acc[rt][ct] = __builtin_amdgcn_mfma_f32_16x16x32_bf16(af[rt], bf[ct], acc[rt][ct], 0, 0, 0);
    }
    float mx = -INFINITY;
#pragma unroll
    for (int rt = 0; rt < 4; rt++)
#pragma unroll
        for (int ct = 0; ct < 2; ct++)
#pragma unroll
            for (int i = 0; i < 4; i++) mx = fmaxf(mx, acc[rt][ct][i]);
#pragma unroll
    for (int o = 32; o > 0; o >>= 1) mx = fmaxf(mx, __shfl_xor(mx, o, 64));
    if (lane == 0) sred[w] = mx;
    __syncthreads();
    if (t == 0) {
        const float m4 = fmaxf(fmaxf(sred[0], sred[1]), fmaxf(sred[2], sred[3]))
                       * 0.42044820762685725f;
        const int i = __float_as_int(m4);
        atomicMax(slot, (i >= 0) ? i : (i ^ 0x7fffffff));
    }
}

// ---------- fused performer attention, one block per (b,h) ----------
__global__ void __launch_bounds__(256) k_attn(
    const float* __restrict__ qg, const float* __restrict__ kg, const float* __restrict__ vg,
    const float* __restrict__ proj, const int* __restrict__ slot, float* __restrict__ outp)
{
    __shared__ float skq[16 * 257];
    __shared__ float sctx[M_ * 34];
    __shared__ float sdk[S_], sdq[S_];
    __shared__ float sksum[M_];
    __shared__ float smax[16], sinv[16];
    const int bh = blockIdx.x;
    const int b = bh >> 3, hh = bh & 7;
    const int t = threadIdx.x;
    const float* kb = kg + (size_t)bh * S_ * DH_;
    const float* qb = qg + (size_t)bh * S_ * DH_;
    const float* vb = vg + (size_t)bh * S_ * DH_;
    for (int i = t * 4; i < S_ * DH_; i += 1024)
        *(float4*)&skq[i] = *(const float4*)&kb[i];
    float pr[DH_];
#pragma unroll
    for (int d = 0; d < DH_; d += 4) {
        const float4 p = *(const float4*)&proj[t * DH_ + d];
        pr[d] = p.x; pr[d + 1] = p.y; pr[d + 2] = p.z; pr[d + 3] = p.w;
    }
    const float nrm = 0.42044820762685725f;
    const float diagc = 0.5f * nrm * nrm;
    if (t < S_) {   // diag from global (L1-hot): avoids bunched LDS strided reads
        float s = 0.f, s2 = 0.f;
#pragma unroll
        for (int d4 = 0; d4 < DH_ / 4; d4++) {
            const float4 kk = *(const float4*)&kb[t * DH_ + d4 * 4];
            s += kk.x * kk.x + kk.y * kk.y + kk.z * kk.z + kk.w * kk.w;
            const float4 qq = *(const float4*)&qb[t * DH_ + d4 * 4];
            s2 += qq.x * qq.x + qq.y * qq.y + qq.z * qq.z + qq.w * qq.w;
        }
        sdk[t] = s * diagc;
        sdq[t] = s2 * diagc;
    }
    __syncthreads();
    float kmaxv;
    { const int iv = *slot; kmaxv = __int_as_float((iv >= 0) ? iv : (iv ^ 0x7fffffff)); }
    const float ratio = 0.0625f;
    {   // phase 2: kp -> ksum, ctx (m = t)
        float ctx[DH_];
#pragma unroll
        for (int d = 0; d < DH_; d++) ctx[d] = 0.f;
        float ksum = 0.f;
        for (int n = 0; n < S_; n++) {
            float acc = 0.f;
#pragma unroll
            for (int d4 = 0; d4 < DH_ / 4; d4++) {
                const float4 kk = *(const float4*)&skq[n * DH_ + d4 * 4];
                acc += kk.x * pr[d4 * 4 + 0] + kk.y * pr[d4 * 4 + 1]
                     + kk.z * pr[d4 * 4 + 2] + kk.w * pr[d4 * 4 + 3];
            }
            const float kp = ratio * (exp2f((acc * nrm - sdk[n] - kmaxv) * LOG2E) + 1e-4f);
            ksum += kp;
            const float4* v4 = (const float4*)(vb + n * DH_);
#pragma unroll
            for (int d4 = 0; d4 < DH_ / 4; d4++) {
                const float4 vv = v4[d4];
                ctx[d4 * 4 + 0] += kp * vv.x; ctx[d4 * 4 + 1] += kp * vv.y;
                ctx[d4 * 4 + 2] += kp * vv.z; ctx[d4 * 4 + 3] += kp * vv.w;
            }
        }
        sksum[t] = ksum;
#pragma unroll
        for (int d2 = 0; d2 < DH_ / 2; d2++)
            *(float2*)&sctx[t * 34 + d2 * 2] = make_float2(ctx[d2 * 2], ctx[d2 * 2 + 1]);
    }
    __syncthreads();
    const int rr = t >> 4, cc = t & 15;
    const int mc4 = t >> 6;                    // step-D: wave = m-chunk of 64
    const int tt = t & 63;
    const int r0 = (tt >> 3) * 2, r1 = r0 + 1; // step-D rows
    const int cq = (tt & 7) * 4;               // step-D cols
    for (int tile = 0; tile < 8; tile++) {
        const int n0 = tile * 16;
        float ddr[16];
#pragma unroll
        for (int r = 0; r < 16; r++) {
            const float4* q4 = (const float4*)(qb + (n0 + r) * DH_);
            float acc = 0.f;
#pragma unroll
            for (int d4 = 0; d4 < DH_ / 4; d4++) {
                const float4 qq = q4[d4];
                acc += qq.x * pr[d4 * 4 + 0] + qq.y * pr[d4 * 4 + 1]
                     + qq.z * pr[d4 * 4 + 2] + qq.w * pr[d4 * 4 + 3];
            }
            ddr[r] = acc * nrm;
            skq[r * 257 + t] = ddr[r];
        }
        __syncthreads();
        {   // row max over m (transpose reduce)
            float mx = -INFINITY;
#pragma unroll
            for (int j = 0; j < 16; j++) mx = fmaxf(mx, skq[rr * 257 + cc + j * 16]);
#pragma unroll
            for (int o = 8; o > 0; o >>= 1) mx = fmaxf(mx, __shfl_xor(mx, o, 64));
            if (cc == 0) smax[rr] = mx;
        }
        __syncthreads();
#pragma unroll
        for (int r = 0; r < 16; r++) {
            const float qp = ratio * (exp2f((ddr[r] - sdq[n0 + r] - smax[r]) * LOG2E) + 1e-4f);
            skq[r * 257 + t] = qp;
        }
        __syncthreads();
        {   // den = qp . ksum (transpose reduce)
            float s = 0.f;
#pragma unroll
            for (int j = 0; j < 16; j++) {
                const int m = cc + j * 16;
                s += skq[rr * 257 + m] * sksum[m];
            }
#pragma unroll
            for (int o = 8; o > 0; o >>= 1) s += __shfl_xor(s, o, 64);
            if (cc == 0) sinv[rr] = 1.0f / s;
        }
        __syncthreads();
        // step D: o[r][c] = sum_m qp[r][m]*ctx[m][c]; 4-way m-split, 2 rows x 4 cols/thread
        float a00 = 0.f, a01 = 0.f, a02 = 0.f, a03 = 0.f;
        float a10 = 0.f, a11 = 0.f, a12 = 0.f, a13 = 0.f;
        for (int j = 0; j < 64; j++) {
            const int m = mc4 * 64 + j;
            const float q0 = skq[r0 * 257 + m];
            const float q1 = skq[r1 * 257 + m];
            const float2 ca = *(const float2*)&sctx[m * 34 + cq];
            const float2 cb = *(const float2*)&sctx[m * 34 + cq + 2];
            a00 += q0 * ca.x; a01 += q0 * ca.y; a02 += q0 * cb.x; a03 += q0 * cb.y;
            a10 += q1 * ca.x; a11 += q1 * ca.y; a12 += q1 * cb.x; a13 += q1 * cb.y;
        }
        __syncthreads();   // all qp reads done; reuse skq[0..2303] for partials [mc][r][36]
        *(float4*)&skq[mc4 * 576 + r0 * 36 + cq] = make_float4(a00, a01, a02, a03);
        *(float4*)&skq[mc4 * 576 + r1 * 36 + cq] = make_float4(a10, a11, a12, a13);
        __syncthreads();
        {   // combine 4 partials; thread t -> outputs (r, c) and (r+8, c)
            const int r = t >> 5, c = t & 31;
            const int o1 = r * 36 + c;
            const float s0 = skq[o1] + skq[576 + o1] + skq[1152 + o1] + skq[1728 + o1];
            outp[((size_t)b * S_ + n0 + r) * D_ + hh * DH_ + c] = s0 * sinv[r];
            const int r2 = r + 8;
            const int o2 = r2 * 36 + c;
            const float s1 = skq[o2] + skq[576 + o2] + skq[1152 + o2] + skq[1728 + o2];
            outp[((size_t)b * S_ + n0 + r2) * D_ + hh * DH_ + c] = s1 * sinv[r2];
        }
        __syncthreads();
    }
}

// ---------- classification head ----------
__global__ void __launch_bounds__(256) k_head(
    const float* __restrict__ hfin, const float* __restrict__ h1w, const float* __restrict__ h1b,
    const float* __restrict__ h2w, const float* __restrict__ h2b,
    const float* __restrict__ ow, const float* __restrict__ ob, float* __restrict__ outp)
{
    __shared__ float c0[D_];
    __shared__ float c1[2 * HID_];
    __shared__ float sred[4];
    const int t = threadIdx.x;
    const int b = blockIdx.x;
    c0[t] = hfin[(size_t)b * S_ * D_ + t];
    __syncthreads();
#pragma unroll
    for (int half = 0; half < 2; half++) {
        const int j = half * 256 + t;
        float a = h1b[j];
        const float* w = h1w + (size_t)j * D_;
        for (int d = 0; d < D_; d += 4) {
            const float4 w4 = *(const float4*)&w[d];
            const float4 x4 = *(const float4*)&c0[d];
            a += x4.x * w4.x + x4.y * w4.y + x4.z * w4.z + x4.w * w4.w;
        }
        c1[j] = (a >= 0.f) ? a : 0.2f * a;
    }
    __syncthreads();
    float a2 = h2b[t];
    const float* w2 = h2w + (size_t)t * (2 * HID_);
    for (int j = 0; j < 2 * HID_; j += 4) {
        const float4 w4 = *(const float4*)&w2[j];
        const float4 x4 = *(const float4*)&c1[j];
        a2 += x4.x * w4.x + x4.y * w4.y + x4.z * w4.z + x4.w * w4.w;
    }
    const float c2 = (a2 >= 0.f) ? a2 : 0.2f * a2;
    const float s = blk_sum(c2 * ow[t], sred);
    if (t == 0) outp[b] = s + ob[0];
}

extern "C" void kernel_launch(void* const* d_in, const int* in_sizes, int n_in,
                              void* d_out, int out_size, void* d_ws, size_t ws_size,
                              hipStream_t stream)
{
    const float* x     = (const float*)d_in[0];
    const int*   mask  = (const int*)d_in[1];
    const float* emb_w = (const float*)d_in[2];
    const float* emb_b = (const float*)d_in[3];
    const float* Wq    = (const float*)d_in[4];
    const float* bq    = (const float*)d_in[5];
    const float* Wk    = (const float*)d_in[6];
    const float* bk    = (const float*)d_in[7];
    const float* Wv    = (const float*)d_in[8];
    const float* bv    = (const float*)d_in[9];
    const float* Wo    = (const float*)d_in[10];
    const float* bo    = (const float*)d_in[11];
    const float* proj  = (const float*)d_in[12];
    const float* n1w   = (const float*)d_in[13];
    const float* n1b   = (const float*)d_in[14];
    const float* n2w   = (const float*)d_in[15];
    const float* n2b   = (const float*)d_in[16];
    const float* f1w   = (const float*)d_in[17];
    const float* f1b   = (const float*)d_in[18];
    const float* f2w   = (const float*)d_in[19];
    const float* f2b   = (const float*)d_in[20];
    const float* h1w   = (const float*)d_in[21];
    const float* h1b   = (const float*)d_in[22];
    const float* h2w   = (const float*)d_in[23];
    const float* h2b   = (const float*)d_in[24];
    const float* ow    = (const float*)d_in[25];
    const float* ob    = (const float*)d_in[26];

    const size_t BSD = (size_t)B_ * S_ * D_;
    float* A = (float*)d_ws;
    float* Q = A + BSD;
    float* K = Q + BSD;
    float* V = K + BSD;
    float* T = K;                              // post-LN1 (alias; K dead after attn)
    unsigned* W2 = (unsigned*)(V + BSD);       // split weights: 6 x L x 65536 uints
    const size_t WT = (size_t)L_ * 256 * 256;
    const size_t WM = (size_t)256 * 256;
    unsigned* P2 = W2 + 6 * WT;                // split proj: L x 256 x 32 uints
    int* slots = (int*)(P2 + (size_t)L_ * M_ * DH_);

    k_wconv<<<256, 256, 0, stream>>>(Wq,  W2 + 0 * WT);
    k_wconv<<<256, 256, 0, stream>>>(Wk,  W2 + 1 * WT);
    k_wconv<<<256, 256, 0, stream>>>(Wv,  W2 + 2 * WT);
    k_wconv<<<256, 256, 0, stream>>>(Wo,  W2 + 3 * WT);
    k_wconv<<<256, 256, 0, stream>>>(f1w, W2 + 4 * WT);
    k_wconv<<<256, 256, 0, stream>>>(f2w, W2 + 5 * WT);
    k_wconv<<<32, 256, 0, stream>>>(proj, P2);
    k_reset<<<1, 64, 0, stream>>>(slots);

    const int GB = B_ * S_ / 64;       // 512 blocks per GEMM
    const int DB = B_ * H_ * S_ / 64 * 2;  // 8192 blocks for k_dmax

    k_embed<<<B_ * S_ * D_ / 256, 256, 0, stream>>>(x, emb_w, emb_b, A);
    for (int l = 0; l < L_; l++) {
        k_gemm<0><<<GB, 256, 0, stream>>>(A, W2 + 0 * WT + l * WM, bq + l * D_, nullptr, nullptr, nullptr, Q);
        k_gemm<0><<<GB, 256, 0, stream>>>(A, W2 + 1 * WT + l * WM, bk + l * D_, nullptr, nullptr, nullptr, K);
        k_gemm<1><<<GB, 256, 0, stream>>>(A, W2 + 2 * WT + l * WM, bv + l * D_, nullptr, nullptr, mask, V);
        k_dmax<<<DB, 256, 0, stream>>>(K, P2 + (size_t)l * M_ * DH_, slots + l);
        k_attn<<<B_ * H_, 256, 0, stream>>>(Q, K, V, proj + (size_t)l * M_ * DH_, slots + l, A);
        k_gemm<2><<<GB, 256, 0, stream>>>(A, W2 + 3 * WT + l * WM, bo + l * D_, n1w + l * D_, n1b + l * D_, nullptr, T);
        k_gemm<3><<<GB, 256, 0, stream>>>(T, W2 + 4 * WT + l * WM, f1b + l * HID_, nullptr, nullptr, nullptr, Q);
        k_gemm<2><<<GB, 256, 0, stream>>>(Q, W2 + 5 * WT + l * WM, f2b + l * D_, n2w + l * D_, n2b + l * D_, nullptr, A);
    }
    k_head<<<B_, 256, 0, stream>>>(A, h1w, h1b, h2w, h2b, ow, ob, (float*)d_out);
}

// Round 7
// 2522.614 us; speedup vs baseline: 2.9489x; 1.3151x over previous
//
#include <hip/hip_runtime.h>
#include <math.h>

#define B_ 256
#define N_ 127
#define S_ 128
#define NDIM_ 3
#define D_ 256
#define H_ 8
#define DH_ 32
#define M_ 256
#define HID_ 256
#define L_ 4
#define LOG2E 1.44269504088896340736f

typedef __attribute__((ext_vector_type(8))) short short8;
typedef __attribute__((ext_vector_type(4))) float floatx4;

// ---------- bf16 split helpers ----------
__device__ __forceinline__ ushort bf16_rn(float x) {
    unsigned u = __float_as_uint(x);
    u = (u + 0x7fffu + ((u >> 16) & 1u)) >> 16;
    return (ushort)u;
}
// x -> {h,h} and {l,l} uints (A-pattern for 4-term split GEMM)
__device__ __forceinline__ void split2(float x, unsigned& hh, unsigned& ll) {
    const ushort h = bf16_rn(x);
    const float r = x - __uint_as_float(((unsigned)h) << 16);
    const ushort l = bf16_rn(r);
    hh = (unsigned)h * 0x10001u;
    ll = (unsigned)l * 0x10001u;
}
// x -> packed uint {h | l<<16}
__device__ __forceinline__ unsigned split_pack(float x) {
    const ushort h = bf16_rn(x);
    const float r = x - __uint_as_float(((unsigned)h) << 16);
    const ushort l = bf16_rn(r);
    return (unsigned)h | ((unsigned)l << 16);
}

// ---------- block reductions ----------
__device__ __forceinline__ float blk_sum(float v, float* sred) {
#pragma unroll
    for (int o = 32; o > 0; o >>= 1) v += __shfl_xor(v, o, 64);
    if ((threadIdx.x & 63) == 0) sred[threadIdx.x >> 6] = v;
    __syncthreads();
    v = sred[0] + sred[1] + sred[2] + sred[3];
    __syncthreads();
    return v;
}

// ---------- embedding ----------
__global__ void k_embed(const float* __restrict__ x, const float* __restrict__ ew,
                        const float* __restrict__ eb, float* __restrict__ h) {
    const int idx = blockIdx.x * 256 + threadIdx.x;
    const int d = idx & (D_ - 1);
    const int n = (idx >> 8) & (S_ - 1);
    const int b = idx >> 15;
    float val = 0.f;
    if (n > 0) {
        const float* xr = x + ((size_t)b * N_ + (n - 1)) * NDIM_;
        val = eb[d] + xr[0] * ew[d * 3 + 0] + xr[1] * ew[d * 3 + 1] + xr[2] * ew[d * 3 + 2];
    }
    h[idx] = val;
}

// ---------- weight pre-split (compact): fp32 -> uint [h|l<<16] ----------
__global__ void __launch_bounds__(256) k_wconv(const float* __restrict__ src, unsigned* __restrict__ dst) {
    const int idx = (blockIdx.x * 256 + threadIdx.x) * 4;
    const float4 w4 = *(const float4*)&src[idx];
    const float v[4] = {w4.x, w4.y, w4.z, w4.w};
    unsigned u[4];
#pragma unroll
    for (int i = 0; i < 4; i++) u[i] = split_pack(v[i]);
    *(uint4*)&dst[idx] = make_uint4(u[0], u[1], u[2], u[3]);
}

// ---------- MFMA bf16x2-split GEMM: C[64 x 256] per block, K2 = 1024 ----------
template<int EPI>
__global__ void __launch_bounds__(256) k_gemm(
    const float* __restrict__ A, const unsigned* __restrict__ W2,
    const float* __restrict__ bias, const float* __restrict__ g1,
    const float* __restrict__ g2, const int* __restrict__ mask,
    float* __restrict__ out)
{
    __shared__ ushort A2s[4 * 64 * 8];     // [c][row][8]
    __shared__ ushort W2s[4 * 256 * 8];    // [c][col][8]
    __shared__ float sredA[64][2], sredB[64][2];
    const int t = threadIdx.x;
    const int w = t >> 6, lane = t & 63;
    const int quad = lane >> 4, l16 = lane & 15;
    const int rowbase = 32 * (w >> 1), colbase = 128 * (w & 1);
    const int row0 = blockIdx.x * 64;

    floatx4 acc[2][8];
#pragma unroll
    for (int rt = 0; rt < 2; rt++)
#pragma unroll
        for (int ct = 0; ct < 8; ct++) acc[rt][ct] = (floatx4){0.f, 0.f, 0.f, 0.f};

    const int srow = t >> 2, skq = t & 3;
    const float* Arow = A + (size_t)(row0 + srow) * D_ + skq * 2;
    const unsigned* Wrow = W2 + (size_t)t * 256;

    for (int s = 0; s < 32; s++) {
        __syncthreads();
        {
            const float2 a2 = *(const float2*)(Arow + s * 8);
            unsigned hh0, ll0, hh1, ll1;
            split2(a2.x, hh0, ll0); split2(a2.y, hh1, ll1);
            *(uint4*)&A2s[skq * 512 + srow * 8] = make_uint4(hh0, ll0, hh1, ll1);
        }
        {
            const uint4* wp = (const uint4*)(Wrow + s * 8);
            const uint4 w0 = wp[0], w1 = wp[1];
            *(uint4*)&W2s[0 * 2048 + t * 8] = make_uint4(w0.x, w0.x, w0.y, w0.y);
            *(uint4*)&W2s[1 * 2048 + t * 8] = make_uint4(w0.z, w0.z, w0.w, w0.w);
            *(uint4*)&W2s[2 * 2048 + t * 8] = make_uint4(w1.x, w1.x, w1.y, w1.y);
            *(uint4*)&W2s[3 * 2048 + t * 8] = make_uint4(w1.z, w1.z, w1.w, w1.w);
        }
        __syncthreads();
        short8 af[2], bf[8];
#pragma unroll
        for (int rt = 0; rt < 2; rt++)
            af[rt] = *(const short8*)&A2s[quad * 512 + (rowbase + 16 * rt + l16) * 8];
#pragma unroll
        for (int ct = 0; ct < 8; ct++)
            bf[ct] = *(const short8*)&W2s[quad * 2048 + (colbase + 16 * ct + l16) * 8];
#pragma unroll
        for (int rt = 0; rt < 2; rt++)
#pragma unroll
            for (int ct = 0; ct < 8; ct++)
                acc[rt][ct] = __builtin_amdgcn_mfma_f32_16x16x32_bf16(af[rt], bf[ct], acc[rt][ct], 0, 0, 0);
    }

    int colv[8]; float bv[8];
#pragma unroll
    for (int ct = 0; ct < 8; ct++) { colv[ct] = colbase + 16 * ct + l16; bv[ct] = bias[colv[ct]]; }

    if (EPI <= 1) {
        const int b = row0 >> 7;
#pragma unroll
        for (int rt = 0; rt < 2; rt++)
#pragma unroll
        for (int i = 0; i < 4; i++) {
            const int rl = rowbase + 16 * rt + quad * 4 + i;
            const int n = (row0 + rl) & (S_ - 1);
            float keep = 1.f;
            if (EPI == 1) keep = (n == 0) ? 1.f : (mask[b * N_ + n - 1] ? 0.f : 1.f);
#pragma unroll
            for (int ct = 0; ct < 8; ct++) {
                float c = acc[rt][ct][i] + bv[ct];
                if (EPI == 1) c *= keep;
                const int col = colv[ct];
                out[(((size_t)b * H_ + (col >> 5)) * S_ + n) * DH_ + (col & 31)] = c;
            }
        }
    } else if (EPI == 2) {
        float gv[8], bbv[8];
#pragma unroll
        for (int ct = 0; ct < 8; ct++) { gv[ct] = g1[colv[ct]]; bbv[ct] = g2[colv[ct]]; }
#pragma unroll
        for (int rt = 0; rt < 2; rt++)
#pragma unroll
        for (int i = 0; i < 4; i++) {
            const int rl = rowbase + 16 * rt + quad * 4 + i;
            float s = 0.f, s2 = 0.f;
#pragma unroll
            for (int ct = 0; ct < 8; ct++) {
                const float c = acc[rt][ct][i] + bv[ct];
                s += c; s2 += c * c;
            }
#pragma unroll
            for (int o = 8; o > 0; o >>= 1) { s += __shfl_xor(s, o, 64); s2 += __shfl_xor(s2, o, 64); }
            if (l16 == 0) { sredA[rl][w & 1] = s; sredB[rl][w & 1] = s2; }
        }
        __syncthreads();
#pragma unroll
        for (int rt = 0; rt < 2; rt++)
#pragma unroll
        for (int i = 0; i < 4; i++) {
            const int rl = rowbase + 16 * rt + quad * 4 + i;
            const float s = sredA[rl][0] + sredA[rl][1];
            const float s2 = sredB[rl][0] + sredB[rl][1];
            const float mu = s * (1.f / D_);
            const float rs = rsqrtf(s2 * (1.f / D_) - mu * mu + 1e-5f);
#pragma unroll
            for (int ct = 0; ct < 8; ct++) {
                const float c = acc[rt][ct][i] + bv[ct];
                out[(size_t)(row0 + rl) * D_ + colv[ct]] = (c - mu) * rs * gv[ct] + bbv[ct];
            }
        }
    } else {
#pragma unroll
        for (int rt = 0; rt < 2; rt++)
#pragma unroll
        for (int i = 0; i < 4; i++) {
            const int rl = rowbase + 16 * rt + quad * 4 + i;
#pragma unroll
            for (int ct = 0; ct < 8; ct++) {
                const float c = acc[rt][ct][i] + bv[ct];
                out[(size_t)(row0 + rl) * D_ + colv[ct]] = (c >= 0.f) ? c : 0.2f * c;
            }
        }
    }
}

// ---------- reset kmax slots ----------
__global__ void k_reset(int* slots) {
    if (threadIdx.x < 4) {
        const int i = __float_as_int(-INFINITY);
        slots[threadIdx.x] = (i >= 0) ? i : (i ^ 0x7fffffff);
    }
}

// ---------- MFMA global k-max (unchanged, proven) ----------
__global__ void __launch_bounds__(256) k_dmax(
    const float* __restrict__ kg, const unsigned* __restrict__ P2, int* __restrict__ slot)
{
    __shared__ __align__(16) ushort A2s[64 * 136];
    __shared__ __align__(16) ushort Ps[128 * 136];
    __shared__ float sred[4];
    const int t = threadIdx.x;
    const size_t row0 = (size_t)(blockIdx.x >> 1) * 64;
    const int m0 = (blockIdx.x & 1) * 128;
    {
        const int row = t >> 2, kq = (t & 3) * 8;
        const float* src = kg + (row0 + row) * DH_ + kq;
        const float4 f0 = *(const float4*)src;
        const float4 f1 = *(const float4*)(src + 4);
        const float vv[8] = {f0.x, f0.y, f0.z, f0.w, f1.x, f1.y, f1.z, f1.w};
#pragma unroll
        for (int i = 0; i < 4; i++) {
            unsigned hh0, ll0, hh1, ll1;
            split2(vv[2 * i], hh0, ll0); split2(vv[2 * i + 1], hh1, ll1);
            *(uint4*)&A2s[row * 136 + ((t & 3) * 4 + i) * 8] = make_uint4(hh0, ll0, hh1, ll1);
        }
    }
    {
        const int col = t >> 1;
        const unsigned* src = P2 + (m0 + col) * DH_ + (t & 1) * 16;
#pragma unroll
        for (int i = 0; i < 8; i++) {
            const unsigned u0 = src[2 * i], u1 = src[2 * i + 1];
            *(uint4*)&Ps[col * 136 + ((t & 1) * 8 + i) * 8] = make_uint4(u0, u0, u1, u1);
        }
    }
    __syncthreads();
    const int w = t >> 6, lane = t & 63, quad = lane >> 4, l16 = lane & 15;
    floatx4 acc[4][2];
#pragma unroll
    for (int rt = 0; rt < 4; rt++)
#pragma unroll
        for (int ct = 0; ct < 2; ct++) acc[rt][ct] = (floatx4){0.f, 0.f, 0.f, 0.f};
#pragma unroll
    for (int kk = 0; kk < 4; kk++) {
        short8 af[4], bf[2];
#pragma unroll
        for (int rt = 0; rt < 4; rt++)
            af[rt] = *(const short8*)&A2s[(rt * 16 + l16) * 136 + (kk * 4 + quad) * 8];
#pragma unroll
        for (int ct = 0; ct < 2; ct++)
            bf[ct] = *(const short8*)&Ps[((w * 2 + ct) * 16 + l16) * 136 + (kk * 4 + quad) * 8];
#pragma unroll
        for (int rt = 0; rt < 4; rt++)
#pragma unroll
            for (int ct = 0; ct < 2; ct++)
                acc[rt][ct] = __builtin_amdgcn_mfma_f32_16x16x32_bf16(af[rt], bf[ct], acc[rt][ct], 0, 0, 0);
    }
    float mx = -INFINITY;
#pragma unroll
    for (int rt = 0; rt < 4; rt++)
#pragma unroll
        for (int ct = 0; ct < 2; ct++)
#pragma unroll
            for (int i = 0; i < 4; i++) mx = fmaxf(mx, acc[rt][ct][i]);
#pragma unroll
    for (int o = 32; o > 0; o >>= 1) mx = fmaxf(mx, __shfl_xor(mx, o, 64));
    if (lane == 0) sred[w] = mx;
    __syncthreads();
    if (t == 0) {
        const float m4 = fmaxf(fmaxf(sred[0], sred[1]), fmaxf(sred[2], sred[3]))
                       * 0.42044820762685725f;
        const int i = __float_as_int(m4);
        atomicMax(slot, (i >= 0) ? i : (i ^ 0x7fffffff));
    }
}

// ---------- per-q-row max of dd_q (k_dmax clone, direct store) ----------
__global__ void __launch_bounds__(256) k_qrowmax(
    const float* __restrict__ qg, const unsigned* __restrict__ P2, float* __restrict__ rowmax)
{
    __shared__ __align__(16) ushort A2s[64 * 136];
    __shared__ __align__(16) ushort Ps[128 * 136];
    __shared__ float sredR[4 * 64];
    const int t = threadIdx.x;
    const size_t row0 = (size_t)blockIdx.x * 64;
    {
        const int row = t >> 2, kq = (t & 3) * 8;
        const float* src = qg + (row0 + row) * DH_ + kq;
        const float4 f0 = *(const float4*)src;
        const float4 f1 = *(const float4*)(src + 4);
        const float vv[8] = {f0.x, f0.y, f0.z, f0.w, f1.x, f1.y, f1.z, f1.w};
#pragma unroll
        for (int i = 0; i < 4; i++) {
            unsigned hh0, ll0, hh1, ll1;
            split2(vv[2 * i], hh0, ll0); split2(vv[2 * i + 1], hh1, ll1);
            *(uint4*)&A2s[row * 136 + ((t & 3) * 4 + i) * 8] = make_uint4(hh0, ll0, hh1, ll1);
        }
    }
    const int w = t >> 6, lane = t & 63, quad = lane >> 4, l16 = lane & 15;
    float mxr[4][4];
#pragma unroll
    for (int rt = 0; rt < 4; rt++)
#pragma unroll
        for (int i = 0; i < 4; i++) mxr[rt][i] = -INFINITY;
    for (int mh = 0; mh < 2; mh++) {
        __syncthreads();
        {
            const int col = t >> 1;
            const unsigned* src = P2 + (mh * 128 + col) * DH_ + (t & 1) * 16;
#pragma unroll
            for (int i = 0; i < 8; i++) {
                const unsigned u0 = src[2 * i], u1 = src[2 * i + 1];
                *(uint4*)&Ps[col * 136 + ((t & 1) * 8 + i) * 8] = make_uint4(u0, u0, u1, u1);
            }
        }
        __syncthreads();
        floatx4 acc[4][2];
#pragma unroll
        for (int rt = 0; rt < 4; rt++)
#pragma unroll
            for (int ct = 0; ct < 2; ct++) acc[rt][ct] = (floatx4){0.f, 0.f, 0.f, 0.f};
#pragma unroll
        for (int kk = 0; kk < 4; kk++) {
            short8 af[4], bf[2];
#pragma unroll
            for (int rt = 0; rt < 4; rt++)
                af[rt] = *(const short8*)&A2s[(rt * 16 + l16) * 136 + (kk * 4 + quad) * 8];
#pragma unroll
            for (int ct = 0; ct < 2; ct++)
                bf[ct] = *(const short8*)&Ps[((w * 2 + ct) * 16 + l16) * 136 + (kk * 4 + quad) * 8];
#pragma unroll
            for (int rt = 0; rt < 4; rt++)
#pragma unroll
                for (int ct = 0; ct < 2; ct++)
                    acc[rt][ct] = __builtin_amdgcn_mfma_f32_16x16x32_bf16(af[rt], bf[ct], acc[rt][ct], 0, 0, 0);
        }
#pragma unroll
        for (int rt = 0; rt < 4; rt++)
#pragma unroll
            for (int i = 0; i < 4; i++)
                mxr[rt][i] = fmaxf(mxr[rt][i], fmaxf(acc[rt][0][i], acc[rt][1][i]));
    }
#pragma unroll
    for (int rt = 0; rt < 4; rt++)
#pragma unroll
    for (int i = 0; i < 4; i++) {
        float v = mxr[rt][i];
#pragma unroll
        for (int o = 8; o > 0; o >>= 1) v = fmaxf(v, __shfl_xor(v, o, 64));
        if (l16 == 0) sredR[w * 64 + rt * 16 + quad * 4 + i] = v;
    }
    __syncthreads();
    if (t < 64) {
        const float m = fmaxf(fmaxf(sredR[t], sredR[64 + t]), fmaxf(sredR[128 + t], sredR[192 + t]))
                      * 0.42044820762685725f;
        rowmax[row0 + t] = m;
    }
}

// ---------- full-MFMA performer attention, one block per (b,h) ----------
// dd_k/dd_q: 4-term split MFMA (exact-ish). kp/qp split{h,l}; v/ctx dup single-bf16.
// den in fp32 VALU. m processed in quarters of 64. 138 KB dynamic LDS, 1 block/CU.
__global__ void __launch_bounds__(256) k_attn2(
    const float* __restrict__ qg, const float* __restrict__ kg, const float* __restrict__ vg,
    const unsigned* __restrict__ P2, const int* __restrict__ slot,
    const float* __restrict__ rowmax, float* __restrict__ outp)
{
    extern __shared__ char smem[];
    ushort* sA   = (ushort*)(smem);            // [128][136]: K-split, then Q-split {h,h,l,l}
    ushort* sB   = (ushort*)(smem + 34816);    // [64][136]: P-quarter {h,l,h,l}
    ushort* sBig = (ushort*)(smem + 52224);    // kpT-q [64][264] split / qpA-q [128][136] split
    ushort* sV   = (ushort*)(smem + 87040);    // [32][264]: v dup {v,v}
    ushort* sCtx = (ushort*)(smem + 103936);   // [32][520]: ctx dup {c,c}, k-full
    float* sdk   = (float*)(smem + 137216);
    float* sdq   = (float*)(smem + 137728);
    float* smq   = (float*)(smem + 138240);
    float* sden  = (float*)(smem + 138752);
    float* sksum = (float*)(smem + 139264);
    float* sksP  = (float*)(smem + 140288);

    const int bh = blockIdx.x;
    const int b = bh >> 3, hh = bh & 7;
    const int t = threadIdx.x;
    const int w = t >> 6, lane = t & 63, quad = lane >> 4, l16 = lane & 15;
    const float* kb = kg + (size_t)bh * S_ * DH_;
    const float* qb = qg + (size_t)bh * S_ * DH_;
    const float* vb = vg + (size_t)bh * S_ * DH_;
    const float nrm = 0.42044820762685725f;
    const float diagc = 0.5f * nrm * nrm;
    const float ratio = 0.0625f;

    // ---- phase 0: stage K-split, v-dup; diag; rowmax preload
    {
        const int row = t >> 1, half = t & 1;
        const float* src = kb + row * DH_ + half * 16;
        float vv[16];
        *(float4*)&vv[0]  = *(const float4*)&src[0];
        *(float4*)&vv[4]  = *(const float4*)&src[4];
        *(float4*)&vv[8]  = *(const float4*)&src[8];
        *(float4*)&vv[12] = *(const float4*)&src[12];
#pragma unroll
        for (int p = 0; p < 8; p++) {
            unsigned hh0, ll0, hh1, ll1;
            split2(vv[2 * p], hh0, ll0); split2(vv[2 * p + 1], hh1, ll1);
            *(uint4*)&sA[row * 136 + half * 64 + p * 8] = make_uint4(hh0, ll0, hh1, ll1);
        }
    }
    {
        const int n = t >> 1, dh = (t & 1) * 16;
        const float* src = vb + n * DH_ + dh;
        float vv[16];
        *(float4*)&vv[0]  = *(const float4*)&src[0];
        *(float4*)&vv[4]  = *(const float4*)&src[4];
        *(float4*)&vv[8]  = *(const float4*)&src[8];
        *(float4*)&vv[12] = *(const float4*)&src[12];
        unsigned* dst = (unsigned*)sV;
#pragma unroll
        for (int j = 0; j < 16; j++)
            dst[(dh + j) * 132 + n] = (unsigned)bf16_rn(vv[j]) * 0x10001u;
    }
    if (t < 128) {
        float s = 0.f, s2 = 0.f;
#pragma unroll
        for (int d4 = 0; d4 < DH_ / 4; d4++) {
            const float4 kk = *(const float4*)&kb[t * DH_ + d4 * 4];
            s += kk.x * kk.x + kk.y * kk.y + kk.z * kk.z + kk.w * kk.w;
            const float4 qq = *(const float4*)&qb[t * DH_ + d4 * 4];
            s2 += qq.x * qq.x + qq.y * qq.y + qq.z * qq.z + qq.w * qq.w;
        }
        sdk[t] = s * diagc;
        sdq[t] = s2 * diagc;
        smq[t] = rowmax[(size_t)bh * S_ + t];
    }
    float kmaxv;
    { const int iv = *slot; kmaxv = __int_as_float((iv >= 0) ? iv : (iv ^ 0x7fffffff)); }
    __syncthreads();

    // ---- phase A/B: per m-quarter: dd_k -> kp(split) -> ksum, ctx -> ctxB
    for (int qd = 0; qd < 4; qd++) {
        {   // stage P-quarter
            const int col = t >> 2, chunk = t & 3;
            const unsigned* src = P2 + (size_t)(qd * 64 + col) * DH_ + chunk * 8;
#pragma unroll
            for (int p = 0; p < 4; p++) {
                const unsigned u0 = src[2 * p], u1 = src[2 * p + 1];
                *(uint4*)&sB[col * 136 + chunk * 32 + p * 8] = make_uint4(u0, u0, u1, u1);
            }
        }
        __syncthreads();
        floatx4 acc[2][4];
#pragma unroll
        for (int rtl = 0; rtl < 2; rtl++)
#pragma unroll
            for (int ct = 0; ct < 4; ct++) acc[rtl][ct] = (floatx4){0.f, 0.f, 0.f, 0.f};
#pragma unroll
        for (int ks = 0; ks < 4; ks++) {
            short8 af[2], bf[4];
#pragma unroll
            for (int rtl = 0; rtl < 2; rtl++)
                af[rtl] = *(const short8*)&sA[((w * 2 + rtl) * 16 + l16) * 136 + ks * 32 + quad * 8];
#pragma unroll
            for (int ct = 0; ct < 4; ct++)
                bf[ct] = *(const short8*)&sB[(ct * 16 + l16) * 136 + ks * 32 + quad * 8];
#pragma unroll
            for (int rtl = 0; rtl < 2; rtl++)
#pragma unroll
                for (int ct = 0; ct < 4; ct++)
                    acc[rtl][ct] = __builtin_amdgcn_mfma_f32_16x16x32_bf16(af[rtl], bf[ct], acc[rtl][ct], 0, 0, 0);
        }
        // kp + split write to kpT + ksum column partials
        float kcol[4] = {0.f, 0.f, 0.f, 0.f};
        unsigned* kpT = (unsigned*)sBig;
#pragma unroll
        for (int rtl = 0; rtl < 2; rtl++)
#pragma unroll
        for (int i = 0; i < 4; i++) {
            const int n = (w * 2 + rtl) * 16 + quad * 4 + i;
            const float dmk = sdk[n] + kmaxv;
#pragma unroll
            for (int ct = 0; ct < 4; ct++) {
                const float kp = ratio * (exp2f((acc[rtl][ct][i] * nrm - dmk) * LOG2E) + 1e-4f);
                kcol[ct] += kp;
                kpT[(ct * 16 + l16) * 132 + n] = split_pack(kp);
            }
        }
#pragma unroll
        for (int ct = 0; ct < 4; ct++) {
            kcol[ct] += __shfl_xor(kcol[ct], 16, 64);
            kcol[ct] += __shfl_xor(kcol[ct], 32, 64);
        }
        if (quad == 0) {
#pragma unroll
            for (int ct = 0; ct < 4; ct++) sksP[w * 64 + ct * 16 + l16] = kcol[ct];
        }
        __syncthreads();
        if (t < 64) sksum[qd * 64 + t] = sksP[t] + sksP[64 + t] + sksP[128 + t] + sksP[192 + t];
        // ctx-quarter MFMA: A = kpT-q (rows m_local), B = sV; K2 = 256
        floatx4 cacc[2];
        cacc[0] = (floatx4){0.f, 0.f, 0.f, 0.f};
        cacc[1] = (floatx4){0.f, 0.f, 0.f, 0.f};
#pragma unroll
        for (int ks = 0; ks < 8; ks++) {
            const short8 a = *(const short8*)&sBig[(w * 16 + l16) * 264 + ks * 32 + quad * 8];
            const short8 b0 = *(const short8*)&sV[(l16) * 264 + ks * 32 + quad * 8];
            const short8 b1 = *(const short8*)&sV[(16 + l16) * 264 + ks * 32 + quad * 8];
            cacc[0] = __builtin_amdgcn_mfma_f32_16x16x32_bf16(a, b0, cacc[0], 0, 0, 0);
            cacc[1] = __builtin_amdgcn_mfma_f32_16x16x32_bf16(a, b1, cacc[1], 0, 0, 0);
        }
        unsigned* ctxB = (unsigned*)sCtx;
#pragma unroll
        for (int ct2 = 0; ct2 < 2; ct2++)
#pragma unroll
        for (int i = 0; i < 4; i++) {
            const int ml = w * 16 + quad * 4 + i;
            const int d = ct2 * 16 + l16;
            ctxB[d * 260 + qd * 64 + ml] = (unsigned)bf16_rn(cacc[ct2][i]) * 0x10001u;
        }
        __syncthreads();
    }

    // ---- phase C prep: restage Q-split into sA
    {
        const int row = t >> 1, half = t & 1;
        const float* src = qb + row * DH_ + half * 16;
        float vv[16];
        *(float4*)&vv[0]  = *(const float4*)&src[0];
        *(float4*)&vv[4]  = *(const float4*)&src[4];
        *(float4*)&vv[8]  = *(const float4*)&src[8];
        *(float4*)&vv[12] = *(const float4*)&src[12];
#pragma unroll
        for (int p = 0; p < 8; p++) {
            unsigned hh0, ll0, hh1, ll1;
            split2(vv[2 * p], hh0, ll0); split2(vv[2 * p + 1], hh1, ll1);
            *(uint4*)&sA[row * 136 + half * 64 + p * 8] = make_uint4(hh0, ll0, hh1, ll1);
        }
    }

    // ---- phase C/D: per m-quarter: dd_q -> qp(split) -> den, o partial
    floatx4 oacc[2][2];
#pragma unroll
    for (int rtl = 0; rtl < 2; rtl++)
#pragma unroll
        for (int ct2 = 0; ct2 < 2; ct2++) oacc[rtl][ct2] = (floatx4){0.f, 0.f, 0.f, 0.f};
    for (int qd = 0; qd < 4; qd++) {
        {   // stage P-quarter
            const int col = t >> 2, chunk = t & 3;
            const unsigned* src = P2 + (size_t)(qd * 64 + col) * DH_ + chunk * 8;
#pragma unroll
            for (int p = 0; p < 4; p++) {
                const unsigned u0 = src[2 * p], u1 = src[2 * p + 1];
                *(uint4*)&sB[col * 136 + chunk * 32 + p * 8] = make_uint4(u0, u0, u1, u1);
            }
        }
        __syncthreads();
        float ks4[4];
#pragma unroll
        for (int ct = 0; ct < 4; ct++) ks4[ct] = sksum[qd * 64 + ct * 16 + l16];
        floatx4 acc[2][4];
#pragma unroll
        for (int rtl = 0; rtl < 2; rtl++)
#pragma unroll
            for (int ct = 0; ct < 4; ct++) acc[rtl][ct] = (floatx4){0.f, 0.f, 0.f, 0.f};
#pragma unroll
        for (int ks = 0; ks < 4; ks++) {
            short8 af[2], bf[4];
#pragma unroll
            for (int rtl = 0; rtl < 2; rtl++)
                af[rtl] = *(const short8*)&sA[((w * 2 + rtl) * 16 + l16) * 136 + ks * 32 + quad * 8];
#pragma unroll
            for (int ct = 0; ct < 4; ct++)
                bf[ct] = *(const short8*)&sB[(ct * 16 + l16) * 136 + ks * 32 + quad * 8];
#pragma unroll
            for (int rtl = 0; rtl < 2; rtl++)
#pragma unroll
                for (int ct = 0; ct < 4; ct++)
                    acc[rtl][ct] = __builtin_amdgcn_mfma_f32_16x16x32_bf16(af[rtl], bf[ct], acc[rtl][ct], 0, 0, 0);
        }
        unsigned* qpA = (unsigned*)sBig;
#pragma unroll
        for (int rtl = 0; rtl < 2; rtl++)
#pragma unroll
        for (int i = 0; i < 4; i++) {
            const int n = (w * 2 + rtl) * 16 + quad * 4 + i;
            const float dmq = sdq[n] + smq[n];
            float dp = 0.f;
#pragma unroll
            for (int ct = 0; ct < 4; ct++) {
                const float qp = ratio * (exp2f((acc[rtl][ct][i] * nrm - dmq) * LOG2E) + 1e-4f);
                dp += qp * ks4[ct];
                qpA[n * 68 + ct * 16 + l16] = split_pack(qp);
            }
#pragma unroll
            for (int o = 8; o > 0; o >>= 1) dp += __shfl_xor(dp, o, 64);
            if (l16 == 0) {
                if (qd == 0) sden[n] = dp; else sden[n] += dp;
            }
        }
        __syncthreads();
        // o partial: A = qpA (split), B = ctxB k-quarter (dup); K2 = 128
#pragma unroll
        for (int ks = 0; ks < 4; ks++) {
            short8 af[2], bf[2];
#pragma unroll
            for (int rtl = 0; rtl < 2; rtl++)
                af[rtl] = *(const short8*)&sBig[((w * 2 + rtl) * 16 + l16) * 136 + ks * 32 + quad * 8];
#pragma unroll
            for (int ct2 = 0; ct2 < 2; ct2++)
                bf[ct2] = *(const short8*)&sCtx[(ct2 * 16 + l16) * 520 + qd * 128 + ks * 32 + quad * 8];
#pragma unroll
            for (int rtl = 0; rtl < 2; rtl++)
#pragma unroll
                for (int ct2 = 0; ct2 < 2; ct2++)
                    oacc[rtl][ct2] = __builtin_amdgcn_mfma_f32_16x16x32_bf16(af[rtl], bf[ct2], oacc[rtl][ct2], 0, 0, 0);
        }
        __syncthreads();
    }

    // ---- epilogue: o / den
#pragma unroll
    for (int rtl = 0; rtl < 2; rtl++)
#pragma unroll
    for (int i = 0; i < 4; i++) {
        const int n = (w * 2 + rtl) * 16 + quad * 4 + i;
        const float inv = 1.0f / sden[n];
#pragma unroll
        for (int ct2 = 0; ct2 < 2; ct2++)
            outp[((size_t)b * S_ + n) * D_ + hh * DH_ + ct2 * 16 + l16] = oacc[rtl][ct2][i] * inv;
    }
}

// ---------- classification head ----------
__global__ void __launch_bounds__(256) k_head(
    const float* __restrict__ hfin, const float* __restrict__ h1w, const float* __restrict__ h1b,
    const float* __restrict__ h2w, const float* __restrict__ h2b,
    const float* __restrict__ ow, const float* __restrict__ ob, float* __restrict__ outp)
{
    __shared__ float c0[D_];
    __shared__ float c1[2 * HID_];
    __shared__ float sred[4];
    const int t = threadIdx.x;
    const int b = blockIdx.x;
    c0[t] = hfin[(size_t)b * S_ * D_ + t];
    __syncthreads();
#pragma unroll
    for (int half = 0; half < 2; half++) {
        const int j = half * 256 + t;
        float a = h1b[j];
        const float* w = h1w + (size_t)j * D_;
        for (int d = 0; d < D_; d += 4) {
            const float4 w4 = *(const float4*)&w[d];
            const float4 x4 = *(const float4*)&c0[d];
            a += x4.x * w4.x + x4.y * w4.y + x4.z * w4.z + x4.w * w4.w;
        }
        c1[j] = (a >= 0.f) ? a : 0.2f * a;
    }
    __syncthreads();
    float a2 = h2b[t];
    const float* w2 = h2w + (size_t)t * (2 * HID_);
    for (int j = 0; j < 2 * HID_; j += 4) {
        const float4 w4 = *(const float4*)&w2[j];
        const float4 x4 = *(const float4*)&c1[j];
        a2 += x4.x * w4.x + x4.y * w4.y + x4.z * w4.z + x4.w * w4.w;
    }
    const float c2 = (a2 >= 0.f) ? a2 : 0.2f * a2;
    const float s = blk_sum(c2 * ow[t], sred);
    if (t == 0) outp[b] = s + ob[0];
}

extern "C" void kernel_launch(void* const* d_in, const int* in_sizes, int n_in,
                              void* d_out, int out_size, void* d_ws, size_t ws_size,
                              hipStream_t stream)
{
    const float* x     = (const float*)d_in[0];
    const int*   mask  = (const int*)d_in[1];
    const float* emb_w = (const float*)d_in[2];
    const float* emb_b = (const float*)d_in[3];
    const float* Wq    = (const float*)d_in[4];
    const float* bq    = (const float*)d_in[5];
    const float* Wk    = (const float*)d_in[6];
    const float* bk    = (const float*)d_in[7];
    const float* Wv    = (const float*)d_in[8];
    const float* bv    = (const float*)d_in[9];
    const float* Wo    = (const float*)d_in[10];
    const float* bo    = (const float*)d_in[11];
    const float* proj  = (const float*)d_in[12];
    const float* n1w   = (const float*)d_in[13];
    const float* n1b   = (const float*)d_in[14];
    const float* n2w   = (const float*)d_in[15];
    const float* n2b   = (const float*)d_in[16];
    const float* f1w   = (const float*)d_in[17];
    const float* f1b   = (const float*)d_in[18];
    const float* f2w   = (const float*)d_in[19];
    const float* f2b   = (const float*)d_in[20];
    const float* h1w   = (const float*)d_in[21];
    const float* h1b   = (const float*)d_in[22];
    const float* h2w   = (const float*)d_in[23];
    const float* h2b   = (const float*)d_in[24];
    const float* ow    = (const float*)d_in[25];
    const float* ob    = (const float*)d_in[26];

    const size_t BSD = (size_t)B_ * S_ * D_;
    float* A = (float*)d_ws;
    float* Q = A + BSD;
    float* K = Q + BSD;
    float* V = K + BSD;
    float* T = K;                              // post-LN1 alias (K dead after attn)
    unsigned* W2 = (unsigned*)(V + BSD);
    const size_t WT = (size_t)L_ * 256 * 256;
    const size_t WM = (size_t)256 * 256;
    unsigned* P2 = W2 + 6 * WT;                // split proj: L x 256 x 32 uints
    int* slots = (int*)(P2 + (size_t)L_ * M_ * DH_);
    float* rowmax = (float*)(slots + 4);       // B*H*S floats

    k_wconv<<<256, 256, 0, stream>>>(Wq,  W2 + 0 * WT);
    k_wconv<<<256, 256, 0, stream>>>(Wk,  W2 + 1 * WT);
    k_wconv<<<256, 256, 0, stream>>>(Wv,  W2 + 2 * WT);
    k_wconv<<<256, 256, 0, stream>>>(Wo,  W2 + 3 * WT);
    k_wconv<<<256, 256, 0, stream>>>(f1w, W2 + 4 * WT);
    k_wconv<<<256, 256, 0, stream>>>(f2w, W2 + 5 * WT);
    k_wconv<<<32, 256, 0, stream>>>(proj, P2);
    k_reset<<<1, 64, 0, stream>>>(slots);

    const int GB = B_ * S_ / 64;               // 512 blocks per GEMM
    const int DB = B_ * H_ * S_ / 64 * 2;      // 8192 blocks for k_dmax
    const int RB = B_ * H_ * S_ / 64;          // 4096 blocks for k_qrowmax
    const size_t ATTN_LDS = 141312;            // 138 KB dynamic LDS

    k_embed<<<B_ * S_ * D_ / 256, 256, 0, stream>>>(x, emb_w, emb_b, A);
    for (int l = 0; l < L_; l++) {
        const unsigned* P2l = P2 + (size_t)l * M_ * DH_;
        k_gemm<0><<<GB, 256, 0, stream>>>(A, W2 + 0 * WT + l * WM, bq + l * D_, nullptr, nullptr, nullptr, Q);
        k_gemm<0><<<GB, 256, 0, stream>>>(A, W2 + 1 * WT + l * WM, bk + l * D_, nullptr, nullptr, nullptr, K);
        k_gemm<1><<<GB, 256, 0, stream>>>(A, W2 + 2 * WT + l * WM, bv + l * D_, nullptr, nullptr, mask, V);
        k_dmax<<<DB, 256, 0, stream>>>(K, P2l, slots + l);
        k_qrowmax<<<RB, 256, 0, stream>>>(Q, P2l, rowmax);
        k_attn2<<<B_ * H_, 256, ATTN_LDS, stream>>>(Q, K, V, P2l, slots + l, rowmax, A);
        k_gemm<2><<<GB, 256, 0, stream>>>(A, W2 + 3 * WT + l * WM, bo + l * D_, n1w + l * D_, n1b + l * D_, nullptr, T);
        k_gemm<3><<<GB, 256, 0, stream>>>(T, W2 + 4 * WT + l * WM, f1b + l * HID_, nullptr, nullptr, nullptr, Q);
        k_gemm<2><<<GB, 256, 0, stream>>>(Q, W2 + 5 * WT + l * WM, f2b + l * D_, n2w + l * D_, n2b + l * D_, nullptr, A);
    }
    k_head<<<B_, 256, 0, stream>>>(A, h1w, h1b, h2w, h2b, ow, ob, (float*)d_out);
}

// Round 8
// 2332.659 us; speedup vs baseline: 3.1890x; 1.0814x over previous
//
#include <hip/hip_runtime.h>
#include <math.h>

#define B_ 256
#define N_ 127
#define S_ 128
#define NDIM_ 3
#define D_ 256
#define H_ 8
#define DH_ 32
#define M_ 256
#define HID_ 256
#define L_ 4
#define LOG2E 1.44269504088896340736f

typedef __attribute__((ext_vector_type(8))) short short8;
typedef __attribute__((ext_vector_type(4))) float floatx4;

// ---------- bf16 split helpers ----------
__device__ __forceinline__ ushort bf16_rn(float x) {
    unsigned u = __float_as_uint(x);
    u = (u + 0x7fffu + ((u >> 16) & 1u)) >> 16;
    return (ushort)u;
}
__device__ __forceinline__ void split2(float x, unsigned& hh, unsigned& ll) {
    const ushort h = bf16_rn(x);
    const float r = x - __uint_as_float(((unsigned)h) << 16);
    const ushort l = bf16_rn(r);
    hh = (unsigned)h * 0x10001u;
    ll = (unsigned)l * 0x10001u;
}
__device__ __forceinline__ unsigned split_pack(float x) {
    const ushort h = bf16_rn(x);
    const float r = x - __uint_as_float(((unsigned)h) << 16);
    const ushort l = bf16_rn(r);
    return (unsigned)h | ((unsigned)l << 16);
}

// ---------- block reductions ----------
__device__ __forceinline__ float blk_sum(float v, float* sred) {
#pragma unroll
    for (int o = 32; o > 0; o >>= 1) v += __shfl_xor(v, o, 64);
    if ((threadIdx.x & 63) == 0) sred[threadIdx.x >> 6] = v;
    __syncthreads();
    v = sred[0] + sred[1] + sred[2] + sred[3];
    __syncthreads();
    return v;
}

// ---------- embedding ----------
__global__ void k_embed(const float* __restrict__ x, const float* __restrict__ ew,
                        const float* __restrict__ eb, float* __restrict__ h) {
    const int idx = blockIdx.x * 256 + threadIdx.x;
    const int d = idx & (D_ - 1);
    const int n = (idx >> 8) & (S_ - 1);
    const int b = idx >> 15;
    float val = 0.f;
    if (n > 0) {
        const float* xr = x + ((size_t)b * N_ + (n - 1)) * NDIM_;
        val = eb[d] + xr[0] * ew[d * 3 + 0] + xr[1] * ew[d * 3 + 1] + xr[2] * ew[d * 3 + 2];
    }
    h[idx] = val;
}

// ---------- weight pre-split (compact): fp32 -> uint [h|l<<16] ----------
__global__ void __launch_bounds__(256) k_wconv(const float* __restrict__ src, unsigned* __restrict__ dst) {
    const int idx = (blockIdx.x * 256 + threadIdx.x) * 4;
    const float4 w4 = *(const float4*)&src[idx];
    const float v[4] = {w4.x, w4.y, w4.z, w4.w};
    unsigned u[4];
#pragma unroll
    for (int i = 0; i < 4; i++) u[i] = split_pack(v[i]);
    *(uint4*)&dst[idx] = make_uint4(u[0], u[1], u[2], u[3]);
}

// ---------- MFMA bf16x2-split GEMM: C[64 x 256] per block, K2 = 1024 ----------
template<int EPI>
__global__ void __launch_bounds__(256) k_gemm(
    const float* __restrict__ A, const unsigned* __restrict__ W2,
    const float* __restrict__ bias, const float* __restrict__ g1,
    const float* __restrict__ g2, const int* __restrict__ mask,
    float* __restrict__ out)
{
    __shared__ ushort A2s[4 * 64 * 8];     // [c][row][8]
    __shared__ ushort W2s[4 * 256 * 8];    // [c][col][8]
    __shared__ float sredA[64][2], sredB[64][2];
    const int t = threadIdx.x;
    const int w = t >> 6, lane = t & 63;
    const int quad = lane >> 4, l16 = lane & 15;
    const int rowbase = 32 * (w >> 1), colbase = 128 * (w & 1);
    const int row0 = blockIdx.x * 64;

    floatx4 acc[2][8];
#pragma unroll
    for (int rt = 0; rt < 2; rt++)
#pragma unroll
        for (int ct = 0; ct < 8; ct++) acc[rt][ct] = (floatx4){0.f, 0.f, 0.f, 0.f};

    const int srow = t >> 2, skq = t & 3;
    const float* Arow = A + (size_t)(row0 + srow) * D_ + skq * 2;
    const unsigned* Wrow = W2 + (size_t)t * 256;

    for (int s = 0; s < 32; s++) {
        __syncthreads();
        {
            const float2 a2 = *(const float2*)(Arow + s * 8);
            unsigned hh0, ll0, hh1, ll1;
            split2(a2.x, hh0, ll0); split2(a2.y, hh1, ll1);
            *(uint4*)&A2s[skq * 512 + srow * 8] = make_uint4(hh0, ll0, hh1, ll1);
        }
        {
            const uint4* wp = (const uint4*)(Wrow + s * 8);
            const uint4 w0 = wp[0], w1 = wp[1];
            *(uint4*)&W2s[0 * 2048 + t * 8] = make_uint4(w0.x, w0.x, w0.y, w0.y);
            *(uint4*)&W2s[1 * 2048 + t * 8] = make_uint4(w0.z, w0.z, w0.w, w0.w);
            *(uint4*)&W2s[2 * 2048 + t * 8] = make_uint4(w1.x, w1.x, w1.y, w1.y);
            *(uint4*)&W2s[3 * 2048 + t * 8] = make_uint4(w1.z, w1.z, w1.w, w1.w);
        }
        __syncthreads();
        short8 af[2], bf[8];
#pragma unroll
        for (int rt = 0; rt < 2; rt++)
            af[rt] = *(const short8*)&A2s[quad * 512 + (rowbase + 16 * rt + l16) * 8];
#pragma unroll
        for (int ct = 0; ct < 8; ct++)
            bf[ct] = *(const short8*)&W2s[quad * 2048 + (colbase + 16 * ct + l16) * 8];
#pragma unroll
        for (int rt = 0; rt < 2; rt++)
#pragma unroll
            for (int ct = 0; ct < 8; ct++)
                acc[rt][ct] = __builtin_amdgcn_mfma_f32_16x16x32_bf16(af[rt], bf[ct], acc[rt][ct], 0, 0, 0);
    }

    int colv[8]; float bv[8];
#pragma unroll
    for (int ct = 0; ct < 8; ct++) { colv[ct] = colbase + 16 * ct + l16; bv[ct] = bias[colv[ct]]; }

    if (EPI <= 1) {
        const int b = row0 >> 7;
#pragma unroll
        for (int rt = 0; rt < 2; rt++)
#pragma unroll
        for (int i = 0; i < 4; i++) {
            const int rl = rowbase + 16 * rt + quad * 4 + i;
            const int n = (row0 + rl) & (S_ - 1);
            float keep = 1.f;
            if (EPI == 1) keep = (n == 0) ? 1.f : (mask[b * N_ + n - 1] ? 0.f : 1.f);
#pragma unroll
            for (int ct = 0; ct < 8; ct++) {
                float c = acc[rt][ct][i] + bv[ct];
                if (EPI == 1) c *= keep;
                const int col = colv[ct];
                out[(((size_t)b * H_ + (col >> 5)) * S_ + n) * DH_ + (col & 31)] = c;
            }
        }
    } else if (EPI == 2) {
        float gv[8], bbv[8];
#pragma unroll
        for (int ct = 0; ct < 8; ct++) { gv[ct] = g1[colv[ct]]; bbv[ct] = g2[colv[ct]]; }
#pragma unroll
        for (int rt = 0; rt < 2; rt++)
#pragma unroll
        for (int i = 0; i < 4; i++) {
            const int rl = rowbase + 16 * rt + quad * 4 + i;
            float s = 0.f, s2 = 0.f;
#pragma unroll
            for (int ct = 0; ct < 8; ct++) {
                const float c = acc[rt][ct][i] + bv[ct];
                s += c; s2 += c * c;
            }
#pragma unroll
            for (int o = 8; o > 0; o >>= 1) { s += __shfl_xor(s, o, 64); s2 += __shfl_xor(s2, o, 64); }
            if (l16 == 0) { sredA[rl][w & 1] = s; sredB[rl][w & 1] = s2; }
        }
        __syncthreads();
#pragma unroll
        for (int rt = 0; rt < 2; rt++)
#pragma unroll
        for (int i = 0; i < 4; i++) {
            const int rl = rowbase + 16 * rt + quad * 4 + i;
            const float s = sredA[rl][0] + sredA[rl][1];
            const float s2 = sredB[rl][0] + sredB[rl][1];
            const float mu = s * (1.f / D_);
            const float rs = rsqrtf(s2 * (1.f / D_) - mu * mu + 1e-5f);
#pragma unroll
            for (int ct = 0; ct < 8; ct++) {
                const float c = acc[rt][ct][i] + bv[ct];
                out[(size_t)(row0 + rl) * D_ + colv[ct]] = (c - mu) * rs * gv[ct] + bbv[ct];
            }
        }
    } else {
#pragma unroll
        for (int rt = 0; rt < 2; rt++)
#pragma unroll
        for (int i = 0; i < 4; i++) {
            const int rl = rowbase + 16 * rt + quad * 4 + i;
#pragma unroll
            for (int ct = 0; ct < 8; ct++) {
                const float c = acc[rt][ct][i] + bv[ct];
                out[(size_t)(row0 + rl) * D_ + colv[ct]] = (c >= 0.f) ? c : 0.2f * c;
            }
        }
    }
}

// ---------- reset kmax slots ----------
__global__ void k_reset(int* slots) {
    if (threadIdx.x < 4) {
        const int i = __float_as_int(-INFINITY);
        slots[threadIdx.x] = (i >= 0) ? i : (i ^ 0x7fffffff);
    }
}

// ---------- MFMA global k-max (proven) ----------
__global__ void __launch_bounds__(256) k_dmax(
    const float* __restrict__ kg, const unsigned* __restrict__ P2, int* __restrict__ slot)
{
    __shared__ __align__(16) ushort A2s[64 * 136];
    __shared__ __align__(16) ushort Ps[128 * 136];
    __shared__ float sred[4];
    const int t = threadIdx.x;
    const size_t row0 = (size_t)(blockIdx.x >> 1) * 64;
    const int m0 = (blockIdx.x & 1) * 128;
    {
        const int row = t >> 2, kq = (t & 3) * 8;
        const float* src = kg + (row0 + row) * DH_ + kq;
        const float4 f0 = *(const float4*)src;
        const float4 f1 = *(const float4*)(src + 4);
        const float vv[8] = {f0.x, f0.y, f0.z, f0.w, f1.x, f1.y, f1.z, f1.w};
#pragma unroll
        for (int i = 0; i < 4; i++) {
            unsigned hh0, ll0, hh1, ll1;
            split2(vv[2 * i], hh0, ll0); split2(vv[2 * i + 1], hh1, ll1);
            *(uint4*)&A2s[row * 136 + ((t & 3) * 4 + i) * 8] = make_uint4(hh0, ll0, hh1, ll1);
        }
    }
    {
        const int col = t >> 1;
        const unsigned* src = P2 + (m0 + col) * DH_ + (t & 1) * 16;
#pragma unroll
        for (int i = 0; i < 8; i++) {
            const unsigned u0 = src[2 * i], u1 = src[2 * i + 1];
            *(uint4*)&Ps[col * 136 + ((t & 1) * 8 + i) * 8] = make_uint4(u0, u0, u1, u1);
        }
    }
    __syncthreads();
    const int w = t >> 6, lane = t & 63, quad = lane >> 4, l16 = lane & 15;
    floatx4 acc[4][2];
#pragma unroll
    for (int rt = 0; rt < 4; rt++)
#pragma unroll
        for (int ct = 0; ct < 2; ct++) acc[rt][ct] = (floatx4){0.f, 0.f, 0.f, 0.f};
#pragma unroll
    for (int kk = 0; kk < 4; kk++) {
        short8 af[4], bf[2];
#pragma unroll
        for (int rt = 0; rt < 4; rt++)
            af[rt] = *(const short8*)&A2s[(rt * 16 + l16) * 136 + (kk * 4 + quad) * 8];
#pragma unroll
        for (int ct = 0; ct < 2; ct++)
            bf[ct] = *(const short8*)&Ps[((w * 2 + ct) * 16 + l16) * 136 + (kk * 4 + quad) * 8];
#pragma unroll
        for (int rt = 0; rt < 4; rt++)
#pragma unroll
            for (int ct = 0; ct < 2; ct++)
                acc[rt][ct] = __builtin_amdgcn_mfma_f32_16x16x32_bf16(af[rt], bf[ct], acc[rt][ct], 0, 0, 0);
    }
    float mx = -INFINITY;
#pragma unroll
    for (int rt = 0; rt < 4; rt++)
#pragma unroll
        for (int ct = 0; ct < 2; ct++)
#pragma unroll
            for (int i = 0; i < 4; i++) mx = fmaxf(mx, acc[rt][ct][i]);
#pragma unroll
    for (int o = 32; o > 0; o >>= 1) mx = fmaxf(mx, __shfl_xor(mx, o, 64));
    if (lane == 0) sred[w] = mx;
    __syncthreads();
    if (t == 0) {
        const float m4 = fmaxf(fmaxf(sred[0], sred[1]), fmaxf(sred[2], sred[3]))
                       * 0.42044820762685725f;
        const int i = __float_as_int(m4);
        atomicMax(slot, (i >= 0) ? i : (i ^ 0x7fffffff));
    }
}

// ---------- per-q-row max of dd_q ----------
__global__ void __launch_bounds__(256) k_qrowmax(
    const float* __restrict__ qg, const unsigned* __restrict__ P2, float* __restrict__ rowmax)
{
    __shared__ __align__(16) ushort A2s[64 * 136];
    __shared__ __align__(16) ushort Ps[128 * 136];
    __shared__ float sredR[4 * 64];
    const int t = threadIdx.x;
    const size_t row0 = (size_t)blockIdx.x * 64;
    {
        const int row = t >> 2, kq = (t & 3) * 8;
        const float* src = qg + (row0 + row) * DH_ + kq;
        const float4 f0 = *(const float4*)src;
        const float4 f1 = *(const float4*)(src + 4);
        const float vv[8] = {f0.x, f0.y, f0.z, f0.w, f1.x, f1.y, f1.z, f1.w};
#pragma unroll
        for (int i = 0; i < 4; i++) {
            unsigned hh0, ll0, hh1, ll1;
            split2(vv[2 * i], hh0, ll0); split2(vv[2 * i + 1], hh1, ll1);
            *(uint4*)&A2s[row * 136 + ((t & 3) * 4 + i) * 8] = make_uint4(hh0, ll0, hh1, ll1);
        }
    }
    const int w = t >> 6, lane = t & 63, quad = lane >> 4, l16 = lane & 15;
    float mxr[4][4];
#pragma unroll
    for (int rt = 0; rt < 4; rt++)
#pragma unroll
        for (int i = 0; i < 4; i++) mxr[rt][i] = -INFINITY;
    for (int mh = 0; mh < 2; mh++) {
        __syncthreads();
        {
            const int col = t >> 1;
            const unsigned* src = P2 + (mh * 128 + col) * DH_ + (t & 1) * 16;
#pragma unroll
            for (int i = 0; i < 8; i++) {
                const unsigned u0 = src[2 * i], u1 = src[2 * i + 1];
                *(uint4*)&Ps[col * 136 + ((t & 1) * 8 + i) * 8] = make_uint4(u0, u0, u1, u1);
            }
        }
        __syncthreads();
        floatx4 acc[4][2];
#pragma unroll
        for (int rt = 0; rt < 4; rt++)
#pragma unroll
            for (int ct = 0; ct < 2; ct++) acc[rt][ct] = (floatx4){0.f, 0.f, 0.f, 0.f};
#pragma unroll
        for (int kk = 0; kk < 4; kk++) {
            short8 af[4], bf[2];
#pragma unroll
            for (int rt = 0; rt < 4; rt++)
                af[rt] = *(const short8*)&A2s[(rt * 16 + l16) * 136 + (kk * 4 + quad) * 8];
#pragma unroll
            for (int ct = 0; ct < 2; ct++)
                bf[ct] = *(const short8*)&Ps[((w * 2 + ct) * 16 + l16) * 136 + (kk * 4 + quad) * 8];
#pragma unroll
            for (int rt = 0; rt < 4; rt++)
#pragma unroll
                for (int ct = 0; ct < 2; ct++)
                    acc[rt][ct] = __builtin_amdgcn_mfma_f32_16x16x32_bf16(af[rt], bf[ct], acc[rt][ct], 0, 0, 0);
        }
#pragma unroll
        for (int rt = 0; rt < 4; rt++)
#pragma unroll
            for (int i = 0; i < 4; i++)
                mxr[rt][i] = fmaxf(mxr[rt][i], fmaxf(acc[rt][0][i], acc[rt][1][i]));
    }
#pragma unroll
    for (int rt = 0; rt < 4; rt++)
#pragma unroll
    for (int i = 0; i < 4; i++) {
        float v = mxr[rt][i];
#pragma unroll
        for (int o = 8; o > 0; o >>= 1) v = fmaxf(v, __shfl_xor(v, o, 64));
        if (l16 == 0) sredR[w * 64 + rt * 16 + quad * 4 + i] = v;
    }
    __syncthreads();
    if (t < 64) {
        const float m = fmaxf(fmaxf(sredR[t], sredR[64 + t]), fmaxf(sredR[128 + t], sredR[192 + t]))
                      * 0.42044820762685725f;
        rowmax[row0 + t] = m;
    }
}

// ---------- full-MFMA performer attention, 512 threads (8 waves), 139 KB LDS ----------
// All LDS scatter-writes batched to 16B uint4 (conflict-free granule spread).
// dd_q operand-swapped (A=P, B=q -> D[m][n]) so qp writes batch along m.
__global__ void __launch_bounds__(512) k_attn2(
    const float* __restrict__ qg, const float* __restrict__ kg, const float* __restrict__ vg,
    const unsigned* __restrict__ P2, const int* __restrict__ slot,
    const float* __restrict__ rowmax, float* __restrict__ outp)
{
    extern __shared__ char smem[];
    ushort* sA   = (ushort*)(smem);            // [128][136]: K-split, then Q-split
    ushort* sB   = (ushort*)(smem + 34816);    // [64][136]: P-quarter {h,l,h,l}
    ushort* sBig = (ushort*)(smem + 52224);    // kpT [64][264] / qpA [128][136]
    ushort* sV   = (ushort*)(smem + 87040);    // [32][264]: v dup
    ushort* sCtx = (ushort*)(smem + 103936);   // [32][520]: ctx dup
    float* sdk   = (float*)(smem + 137216);
    float* sdq   = (float*)(smem + 137728);
    float* smq   = (float*)(smem + 138240);
    float* sden  = (float*)(smem + 138752);
    float* sksum = (float*)(smem + 139264);
    float* sksP  = (float*)(smem + 140288);    // [8][64]

    const int bh = blockIdx.x;
    const int b = bh >> 3, hh = bh & 7;
    const int t = threadIdx.x;
    const int w = t >> 6, lane = t & 63, quad = lane >> 4, l16 = lane & 15;
    const float* kb = kg + (size_t)bh * S_ * DH_;
    const float* qb = qg + (size_t)bh * S_ * DH_;
    const float* vb = vg + (size_t)bh * S_ * DH_;
    const float nrm = 0.42044820762685725f;
    const float diagc = 0.5f * nrm * nrm;
    const float ratio = 0.0625f;

    // ---- phase 0: K-split stage; v-dup stage; diag; rowmax
    {
        const int row = t >> 2, seg = t & 3;
        const float* src = kb + row * DH_ + seg * 8;
        float vv[8];
        *(float4*)&vv[0] = *(const float4*)&src[0];
        *(float4*)&vv[4] = *(const float4*)&src[4];
#pragma unroll
        for (int p = 0; p < 4; p++) {
            unsigned hh0, ll0, hh1, ll1;
            split2(vv[2 * p], hh0, ll0); split2(vv[2 * p + 1], hh1, ll1);
            *(uint4*)&sA[row * 136 + seg * 32 + p * 8] = make_uint4(hh0, ll0, hh1, ll1);
        }
    }
    {
        const int n = t & 127, d0 = (t >> 7) * 8;   // n = lane-consecutive -> 2-way LDS writes
        const float* src = vb + n * DH_ + d0;
        float vv[8];
        *(float4*)&vv[0] = *(const float4*)&src[0];
        *(float4*)&vv[4] = *(const float4*)&src[4];
        unsigned* dst = (unsigned*)sV;
#pragma unroll
        for (int j = 0; j < 8; j++)
            dst[(d0 + j) * 132 + n] = (unsigned)bf16_rn(vv[j]) * 0x10001u;
    }
    if (t < 128) {
        float s = 0.f, s2 = 0.f;
#pragma unroll
        for (int d4 = 0; d4 < DH_ / 4; d4++) {
            const float4 kk = *(const float4*)&kb[t * DH_ + d4 * 4];
            s += kk.x * kk.x + kk.y * kk.y + kk.z * kk.z + kk.w * kk.w;
            const float4 qq = *(const float4*)&qb[t * DH_ + d4 * 4];
            s2 += qq.x * qq.x + qq.y * qq.y + qq.z * qq.z + qq.w * qq.w;
        }
        sdk[t] = s * diagc;
        sdq[t] = s2 * diagc;
        smq[t] = rowmax[(size_t)bh * S_ + t];
    }
    float kmaxv;
    { const int iv = *slot; kmaxv = __int_as_float((iv >= 0) ? iv : (iv ^ 0x7fffffff)); }
    __syncthreads();

    // ---- phase A/B: per m-quarter: dd_k -> kp(split, batched) -> ksum, ctx -> ctxB
    for (int qd = 0; qd < 4; qd++) {
        {   // stage P-quarter: col = t>>3, ch = t&7 (4 uints each)
            const int col = t >> 3, ch = t & 7;
            const unsigned* src = P2 + (size_t)(qd * 64 + col) * DH_ + ch * 4;
            const unsigned u0 = src[0], u1 = src[1], u2 = src[2], u3 = src[3];
            *(uint4*)&sB[col * 136 + ch * 16]     = make_uint4(u0, u0, u1, u1);
            *(uint4*)&sB[col * 136 + ch * 16 + 8] = make_uint4(u2, u2, u3, u3);
        }
        __syncthreads();
        // dd_k: wave w -> n-tile w; 4 m-tiles
        floatx4 acc[4];
#pragma unroll
        for (int ct = 0; ct < 4; ct++) acc[ct] = (floatx4){0.f, 0.f, 0.f, 0.f};
#pragma unroll
        for (int ks = 0; ks < 4; ks++) {
            const short8 af = *(const short8*)&sA[(w * 16 + l16) * 136 + ks * 32 + quad * 8];
            short8 bf[4];
#pragma unroll
            for (int ct = 0; ct < 4; ct++)
                bf[ct] = *(const short8*)&sB[(ct * 16 + l16) * 136 + ks * 32 + quad * 8];
#pragma unroll
            for (int ct = 0; ct < 4; ct++)
                acc[ct] = __builtin_amdgcn_mfma_f32_16x16x32_bf16(af, bf[ct], acc[ct], 0, 0, 0);
        }
        // kp: thread n = w*16+quad*4+i, m = ct*16+l16; batched uint4 writes along n
        unsigned* kpT = (unsigned*)sBig;
        float kc[4];
#pragma unroll
        for (int ct = 0; ct < 4; ct++) {
            float kcl = 0.f;
            unsigned pk[4];
#pragma unroll
            for (int i = 0; i < 4; i++) {
                const int n = w * 16 + quad * 4 + i;
                const float kp = ratio * (exp2f((acc[ct][i] * nrm - sdk[n] - kmaxv) * LOG2E) + 1e-4f);
                kcl += kp;
                pk[i] = split_pack(kp);
            }
            *(uint4*)&kpT[(ct * 16 + l16) * 132 + w * 16 + quad * 4] = make_uint4(pk[0], pk[1], pk[2], pk[3]);
            kc[ct] = kcl;
        }
#pragma unroll
        for (int ct = 0; ct < 4; ct++) {
            kc[ct] += __shfl_xor(kc[ct], 16, 64);
            kc[ct] += __shfl_xor(kc[ct], 32, 64);
        }
        if (quad == 0) {
#pragma unroll
            for (int ct = 0; ct < 4; ct++) sksP[w * 64 + ct * 16 + l16] = kc[ct];
        }
        __syncthreads();
        if (t < 64) {
            float s = 0.f;
#pragma unroll
            for (int ww = 0; ww < 8; ww++) s += sksP[ww * 64 + t];
            sksum[qd * 64 + t] = s;
        }
        // ctx MFMA: wave w -> m-tile (w&3), d-tile (w>>2); K2 = 256 (n)
        floatx4 cacc = (floatx4){0.f, 0.f, 0.f, 0.f};
#pragma unroll
        for (int ks = 0; ks < 8; ks++) {
            const short8 a = *(const short8*)&sBig[((w & 3) * 16 + l16) * 264 + ks * 32 + quad * 8];
            const short8 bvv = *(const short8*)&sV[((w >> 2) * 16 + l16) * 264 + ks * 32 + quad * 8];
            cacc = __builtin_amdgcn_mfma_f32_16x16x32_bf16(a, bvv, cacc, 0, 0, 0);
        }
        {   // ctxB write: thread ml = (w&3)*16+quad*4+i, d = (w>>2)*16+l16; batched
            unsigned* ctxB = (unsigned*)sCtx;
            unsigned pk[4];
#pragma unroll
            for (int i = 0; i < 4; i++) pk[i] = (unsigned)bf16_rn(cacc[i]) * 0x10001u;
            *(uint4*)&ctxB[((w >> 2) * 16 + l16) * 260 + qd * 64 + (w & 3) * 16 + quad * 4] =
                make_uint4(pk[0], pk[1], pk[2], pk[3]);
        }
        __syncthreads();
    }

    // ---- phase C prep: restage Q-split into sA
    {
        const int row = t >> 2, seg = t & 3;
        const float* src = qb + row * DH_ + seg * 8;
        float vv[8];
        *(float4*)&vv[0] = *(const float4*)&src[0];
        *(float4*)&vv[4] = *(const float4*)&src[4];
#pragma unroll
        for (int p = 0; p < 4; p++) {
            unsigned hh0, ll0, hh1, ll1;
            split2(vv[2 * p], hh0, ll0); split2(vv[2 * p + 1], hh1, ll1);
            *(uint4*)&sA[row * 136 + seg * 32 + p * 8] = make_uint4(hh0, ll0, hh1, ll1);
        }
    }
    __syncthreads();

    // ---- phase C/D: per m-quarter: dd_q (swapped) -> qp(split, batched) -> den, o
    floatx4 oacc[2];
    oacc[0] = (floatx4){0.f, 0.f, 0.f, 0.f};
    oacc[1] = (floatx4){0.f, 0.f, 0.f, 0.f};
    for (int qd = 0; qd < 4; qd++) {
        {   // stage P-quarter
            const int col = t >> 3, ch = t & 7;
            const unsigned* src = P2 + (size_t)(qd * 64 + col) * DH_ + ch * 4;
            const unsigned u0 = src[0], u1 = src[1], u2 = src[2], u3 = src[3];
            *(uint4*)&sB[col * 136 + ch * 16]     = make_uint4(u0, u0, u1, u1);
            *(uint4*)&sB[col * 136 + ch * 16 + 8] = make_uint4(u2, u2, u3, u3);
        }
        __syncthreads();
        // dd_q swapped: A = P rows m (4 tiles), B = q rows n (tile w) -> D[m][n]
        floatx4 adq[4];
#pragma unroll
        for (int mt = 0; mt < 4; mt++) adq[mt] = (floatx4){0.f, 0.f, 0.f, 0.f};
#pragma unroll
        for (int ks = 0; ks < 4; ks++) {
            const short8 bf = *(const short8*)&sA[(w * 16 + l16) * 136 + ks * 32 + quad * 8];
            short8 af[4];
#pragma unroll
            for (int mt = 0; mt < 4; mt++)
                af[mt] = *(const short8*)&sB[(mt * 16 + l16) * 136 + ks * 32 + quad * 8];
#pragma unroll
            for (int mt = 0; mt < 4; mt++)
                adq[mt] = __builtin_amdgcn_mfma_f32_16x16x32_bf16(af[mt], bf, adq[mt], 0, 0, 0);
        }
        // qp: thread n = w*16 + l16 (fixed), m = mt*16 + quad*4 + i; batched along m
        const int nq = w * 16 + l16;
        const float dmq = sdq[nq] + smq[nq];
        unsigned* qpA = (unsigned*)sBig;
        float dp = 0.f;
#pragma unroll
        for (int mt = 0; mt < 4; mt++) {
            unsigned pk[4];
#pragma unroll
            for (int i = 0; i < 4; i++) {
                const float qp = ratio * (exp2f((adq[mt][i] * nrm - dmq) * LOG2E) + 1e-4f);
                dp += qp * sksum[qd * 64 + mt * 16 + quad * 4 + i];
                pk[i] = split_pack(qp);
            }
            *(uint4*)&qpA[nq * 68 + mt * 16 + quad * 4] = make_uint4(pk[0], pk[1], pk[2], pk[3]);
        }
        dp += __shfl_xor(dp, 16, 64);
        dp += __shfl_xor(dp, 32, 64);
        if (quad == 0) {
            if (qd == 0) sden[nq] = dp; else sden[nq] += dp;
        }
        __syncthreads();
        // o MFMA: wave w -> n-tile w, d-tiles 0..1; K2 = 128 (m-quarter)
#pragma unroll
        for (int ks = 0; ks < 4; ks++) {
            const short8 af = *(const short8*)&sBig[(w * 16 + l16) * 136 + ks * 32 + quad * 8];
            short8 bf[2];
#pragma unroll
            for (int dt = 0; dt < 2; dt++)
                bf[dt] = *(const short8*)&sCtx[(dt * 16 + l16) * 520 + qd * 128 + ks * 32 + quad * 8];
#pragma unroll
            for (int dt = 0; dt < 2; dt++)
                oacc[dt] = __builtin_amdgcn_mfma_f32_16x16x32_bf16(af, bf[dt], oacc[dt], 0, 0, 0);
        }
        __syncthreads();
    }

    // ---- epilogue: o / den; n = w*16 + quad*4 + i, d = dt*16 + l16
#pragma unroll
    for (int i = 0; i < 4; i++) {
        const int n = w * 16 + quad * 4 + i;
        const float inv = 1.0f / sden[n];
#pragma unroll
        for (int dt = 0; dt < 2; dt++)
            outp[((size_t)b * S_ + n) * D_ + hh * DH_ + dt * 16 + l16] = oacc[dt][i] * inv;
    }
}

// ---------- classification head ----------
__global__ void __launch_bounds__(256) k_head(
    const float* __restrict__ hfin, const float* __restrict__ h1w, const float* __restrict__ h1b,
    const float* __restrict__ h2w, const float* __restrict__ h2b,
    const float* __restrict__ ow, const float* __restrict__ ob, float* __restrict__ outp)
{
    __shared__ float c0[D_];
    __shared__ float c1[2 * HID_];
    __shared__ float sred[4];
    const int t = threadIdx.x;
    const int b = blockIdx.x;
    c0[t] = hfin[(size_t)b * S_ * D_ + t];
    __syncthreads();
#pragma unroll
    for (int half = 0; half < 2; half++) {
        const int j = half * 256 + t;
        float a = h1b[j];
        const float* w = h1w + (size_t)j * D_;
        for (int d = 0; d < D_; d += 4) {
            const float4 w4 = *(const float4*)&w[d];
            const float4 x4 = *(const float4*)&c0[d];
            a += x4.x * w4.x + x4.y * w4.y + x4.z * w4.z + x4.w * w4.w;
        }
        c1[j] = (a >= 0.f) ? a : 0.2f * a;
    }
    __syncthreads();
    float a2 = h2b[t];
    const float* w2 = h2w + (size_t)t * (2 * HID_);
    for (int j = 0; j < 2 * HID_; j += 4) {
        const float4 w4 = *(const float4*)&w2[j];
        const float4 x4 = *(const float4*)&c1[j];
        a2 += x4.x * w4.x + x4.y * w4.y + x4.z * w4.z + x4.w * w4.w;
    }
    const float c2 = (a2 >= 0.f) ? a2 : 0.2f * a2;
    const float s = blk_sum(c2 * ow[t], sred);
    if (t == 0) outp[b] = s + ob[0];
}

extern "C" void kernel_launch(void* const* d_in, const int* in_sizes, int n_in,
                              void* d_out, int out_size, void* d_ws, size_t ws_size,
                              hipStream_t stream)
{
    const float* x     = (const float*)d_in[0];
    const int*   mask  = (const int*)d_in[1];
    const float* emb_w = (const float*)d_in[2];
    const float* emb_b = (const float*)d_in[3];
    const float* Wq    = (const float*)d_in[4];
    const float* bq    = (const float*)d_in[5];
    const float* Wk    = (const float*)d_in[6];
    const float* bk    = (const float*)d_in[7];
    const float* Wv    = (const float*)d_in[8];
    const float* bv    = (const float*)d_in[9];
    const float* Wo    = (const float*)d_in[10];
    const float* bo    = (const float*)d_in[11];
    const float* proj  = (const float*)d_in[12];
    const float* n1w   = (const float*)d_in[13];
    const float* n1b   = (const float*)d_in[14];
    const float* n2w   = (const float*)d_in[15];
    const float* n2b   = (const float*)d_in[16];
    const float* f1w   = (const float*)d_in[17];
    const float* f1b   = (const float*)d_in[18];
    const float* f2w   = (const float*)d_in[19];
    const float* f2b   = (const float*)d_in[20];
    const float* h1w   = (const float*)d_in[21];
    const float* h1b   = (const float*)d_in[22];
    const float* h2w   = (const float*)d_in[23];
    const float* h2b   = (const float*)d_in[24];
    const float* ow    = (const float*)d_in[25];
    const float* ob    = (const float*)d_in[26];

    const size_t BSD = (size_t)B_ * S_ * D_;
    float* A = (float*)d_ws;
    float* Q = A + BSD;
    float* K = Q + BSD;
    float* V = K + BSD;
    float* T = K;                              // post-LN1 alias (K dead after attn)
    unsigned* W2 = (unsigned*)(V + BSD);
    const size_t WT = (size_t)L_ * 256 * 256;
    const size_t WM = (size_t)256 * 256;
    unsigned* P2 = W2 + 6 * WT;                // split proj: L x 256 x 32 uints
    int* slots = (int*)(P2 + (size_t)L_ * M_ * DH_);
    float* rowmax = (float*)(slots + 4);       // B*H*S floats

    k_wconv<<<256, 256, 0, stream>>>(Wq,  W2 + 0 * WT);
    k_wconv<<<256, 256, 0, stream>>>(Wk,  W2 + 1 * WT);
    k_wconv<<<256, 256, 0, stream>>>(Wv,  W2 + 2 * WT);
    k_wconv<<<256, 256, 0, stream>>>(Wo,  W2 + 3 * WT);
    k_wconv<<<256, 256, 0, stream>>>(f1w, W2 + 4 * WT);
    k_wconv<<<256, 256, 0, stream>>>(f2w, W2 + 5 * WT);
    k_wconv<<<32, 256, 0, stream>>>(proj, P2);
    k_reset<<<1, 64, 0, stream>>>(slots);

    const int GB = B_ * S_ / 64;               // 512 blocks per GEMM
    const int DB = B_ * H_ * S_ / 64 * 2;      // 8192 blocks for k_dmax
    const int RB = B_ * H_ * S_ / 64;          // 4096 blocks for k_qrowmax
    const size_t ATTN_LDS = 142336;            // 139 KB dynamic LDS

    k_embed<<<B_ * S_ * D_ / 256, 256, 0, stream>>>(x, emb_w, emb_b, A);
    for (int l = 0; l < L_; l++) {
        const unsigned* P2l = P2 + (size_t)l * M_ * DH_;
        k_gemm<0><<<GB, 256, 0, stream>>>(A, W2 + 0 * WT + l * WM, bq + l * D_, nullptr, nullptr, nullptr, Q);
        k_gemm<0><<<GB, 256, 0, stream>>>(A, W2 + 1 * WT + l * WM, bk + l * D_, nullptr, nullptr, nullptr, K);
        k_gemm<1><<<GB, 256, 0, stream>>>(A, W2 + 2 * WT + l * WM, bv + l * D_, nullptr, nullptr, mask, V);
        k_dmax<<<DB, 256, 0, stream>>>(K, P2l, slots + l);
        k_qrowmax<<<RB, 256, 0, stream>>>(Q, P2l, rowmax);
        k_attn2<<<B_ * H_, 512, ATTN_LDS, stream>>>(Q, K, V, P2l, slots + l, rowmax, A);
        k_gemm<2><<<GB, 256, 0, stream>>>(A, W2 + 3 * WT + l * WM, bo + l * D_, n1w + l * D_, n1b + l * D_, nullptr, T);
        k_gemm<3><<<GB, 256, 0, stream>>>(T, W2 + 4 * WT + l * WM, f1b + l * HID_, nullptr, nullptr, nullptr, Q);
        k_gemm<2><<<GB, 256, 0, stream>>>(Q, W2 + 5 * WT + l * WM, f2b + l * D_, n2w + l * D_, n2b + l * D_, nullptr, A);
    }
    k_head<<<B_, 256, 0, stream>>>(A, h1w, h1b, h2w, h2b, ow, ob, (float*)d_out);
}

// Round 9
// 2173.157 us; speedup vs baseline: 3.4231x; 1.0734x over previous
//
#include <hip/hip_runtime.h>
#include <math.h>

#define B_ 256
#define N_ 127
#define S_ 128
#define NDIM_ 3
#define D_ 256
#define H_ 8
#define DH_ 32
#define M_ 256
#define HID_ 256
#define L_ 4
#define LOG2E 1.44269504088896340736f

typedef __attribute__((ext_vector_type(8))) short short8;
typedef __attribute__((ext_vector_type(4))) float floatx4;

// ---------- bf16 split helpers ----------
__device__ __forceinline__ ushort bf16_rn(float x) {
    unsigned u = __float_as_uint(x);
    u = (u + 0x7fffu + ((u >> 16) & 1u)) >> 16;
    return (ushort)u;
}
__device__ __forceinline__ void split2(float x, unsigned& hh, unsigned& ll) {
    const ushort h = bf16_rn(x);
    const float r = x - __uint_as_float(((unsigned)h) << 16);
    const ushort l = bf16_rn(r);
    hh = (unsigned)h * 0x10001u;
    ll = (unsigned)l * 0x10001u;
}
__device__ __forceinline__ unsigned split_pack(float x) {
    const ushort h = bf16_rn(x);
    const float r = x - __uint_as_float(((unsigned)h) << 16);
    const ushort l = bf16_rn(r);
    return (unsigned)h | ((unsigned)l << 16);
}

// ---------- block reductions ----------
__device__ __forceinline__ float blk_sum(float v, float* sred) {
#pragma unroll
    for (int o = 32; o > 0; o >>= 1) v += __shfl_xor(v, o, 64);
    if ((threadIdx.x & 63) == 0) sred[threadIdx.x >> 6] = v;
    __syncthreads();
    v = sred[0] + sred[1] + sred[2] + sred[3];
    __syncthreads();
    return v;
}

// ---------- embedding ----------
__global__ void k_embed(const float* __restrict__ x, const float* __restrict__ ew,
                        const float* __restrict__ eb, float* __restrict__ h) {
    const int idx = blockIdx.x * 256 + threadIdx.x;
    const int d = idx & (D_ - 1);
    const int n = (idx >> 8) & (S_ - 1);
    const int b = idx >> 15;
    float val = 0.f;
    if (n > 0) {
        const float* xr = x + ((size_t)b * N_ + (n - 1)) * NDIM_;
        val = eb[d] + xr[0] * ew[d * 3 + 0] + xr[1] * ew[d * 3 + 1] + xr[2] * ew[d * 3 + 2];
    }
    h[idx] = val;
}

// ---------- weight pre-split (compact): fp32 -> uint [h|l<<16] ----------
__global__ void __launch_bounds__(256) k_wconv(const float* __restrict__ src, unsigned* __restrict__ dst) {
    const int idx = (blockIdx.x * 256 + threadIdx.x) * 4;
    const float4 w4 = *(const float4*)&src[idx];
    const float v[4] = {w4.x, w4.y, w4.z, w4.w};
    unsigned u[4];
#pragma unroll
    for (int i = 0; i < 4; i++) u[i] = split_pack(v[i]);
    *(uint4*)&dst[idx] = make_uint4(u[0], u[1], u[2], u[3]);
}

// ---------- MFMA bf16x2-split GEMM: C[64 x 256] per block, K2 = 1024 ----------
template<int EPI>
__global__ void __launch_bounds__(256) k_gemm(
    const float* __restrict__ A, const unsigned* __restrict__ W2,
    const float* __restrict__ bias, const float* __restrict__ g1,
    const float* __restrict__ g2, const int* __restrict__ mask,
    float* __restrict__ out)
{
    __shared__ ushort A2s[4 * 64 * 8];     // [c][row][8]
    __shared__ ushort W2s[4 * 256 * 8];    // [c][col][8]
    __shared__ float sredA[64][2], sredB[64][2];
    const int t = threadIdx.x;
    const int w = t >> 6, lane = t & 63;
    const int quad = lane >> 4, l16 = lane & 15;
    const int rowbase = 32 * (w >> 1), colbase = 128 * (w & 1);
    const int row0 = blockIdx.x * 64;

    floatx4 acc[2][8];
#pragma unroll
    for (int rt = 0; rt < 2; rt++)
#pragma unroll
        for (int ct = 0; ct < 8; ct++) acc[rt][ct] = (floatx4){0.f, 0.f, 0.f, 0.f};

    const int srow = t >> 2, skq = t & 3;
    const float* Arow = A + (size_t)(row0 + srow) * D_ + skq * 2;
    const unsigned* Wrow = W2 + (size_t)t * 256;

    for (int s = 0; s < 32; s++) {
        __syncthreads();
        {
            const float2 a2 = *(const float2*)(Arow + s * 8);
            unsigned hh0, ll0, hh1, ll1;
            split2(a2.x, hh0, ll0); split2(a2.y, hh1, ll1);
            *(uint4*)&A2s[skq * 512 + srow * 8] = make_uint4(hh0, ll0, hh1, ll1);
        }
        {
            const uint4* wp = (const uint4*)(Wrow + s * 8);
            const uint4 w0 = wp[0], w1 = wp[1];
            *(uint4*)&W2s[0 * 2048 + t * 8] = make_uint4(w0.x, w0.x, w0.y, w0.y);
            *(uint4*)&W2s[1 * 2048 + t * 8] = make_uint4(w0.z, w0.z, w0.w, w0.w);
            *(uint4*)&W2s[2 * 2048 + t * 8] = make_uint4(w1.x, w1.x, w1.y, w1.y);
            *(uint4*)&W2s[3 * 2048 + t * 8] = make_uint4(w1.z, w1.z, w1.w, w1.w);
        }
        __syncthreads();
        short8 af[2], bf[8];
#pragma unroll
        for (int rt = 0; rt < 2; rt++)
            af[rt] = *(const short8*)&A2s[quad * 512 + (rowbase + 16 * rt + l16) * 8];
#pragma unroll
        for (int ct = 0; ct < 8; ct++)
            bf[ct] = *(const short8*)&W2s[quad * 2048 + (colbase + 16 * ct + l16) * 8];
#pragma unroll
        for (int rt = 0; rt < 2; rt++)
#pragma unroll
            for (int ct = 0; ct < 8; ct++)
                acc[rt][ct] = __builtin_amdgcn_mfma_f32_16x16x32_bf16(af[rt], bf[ct], acc[rt][ct], 0, 0, 0);
    }

    int colv[8]; float bv[8];
#pragma unroll
    for (int ct = 0; ct < 8; ct++) { colv[ct] = colbase + 16 * ct + l16; bv[ct] = bias[colv[ct]]; }

    if (EPI <= 1) {
        const int b = row0 >> 7;
#pragma unroll
        for (int rt = 0; rt < 2; rt++)
#pragma unroll
        for (int i = 0; i < 4; i++) {
            const int rl = rowbase + 16 * rt + quad * 4 + i;
            const int n = (row0 + rl) & (S_ - 1);
            float keep = 1.f;
            if (EPI == 1) keep = (n == 0) ? 1.f : (mask[b * N_ + n - 1] ? 0.f : 1.f);
#pragma unroll
            for (int ct = 0; ct < 8; ct++) {
                float c = acc[rt][ct][i] + bv[ct];
                if (EPI == 1) c *= keep;
                const int col = colv[ct];
                out[(((size_t)b * H_ + (col >> 5)) * S_ + n) * DH_ + (col & 31)] = c;
            }
        }
    } else if (EPI == 2) {
        float gv[8], bbv[8];
#pragma unroll
        for (int ct = 0; ct < 8; ct++) { gv[ct] = g1[colv[ct]]; bbv[ct] = g2[colv[ct]]; }
#pragma unroll
        for (int rt = 0; rt < 2; rt++)
#pragma unroll
        for (int i = 0; i < 4; i++) {
            const int rl = rowbase + 16 * rt + quad * 4 + i;
            float s = 0.f, s2 = 0.f;
#pragma unroll
            for (int ct = 0; ct < 8; ct++) {
                const float c = acc[rt][ct][i] + bv[ct];
                s += c; s2 += c * c;
            }
#pragma unroll
            for (int o = 8; o > 0; o >>= 1) { s += __shfl_xor(s, o, 64); s2 += __shfl_xor(s2, o, 64); }
            if (l16 == 0) { sredA[rl][w & 1] = s; sredB[rl][w & 1] = s2; }
        }
        __syncthreads();
#pragma unroll
        for (int rt = 0; rt < 2; rt++)
#pragma unroll
        for (int i = 0; i < 4; i++) {
            const int rl = rowbase + 16 * rt + quad * 4 + i;
            const float s = sredA[rl][0] + sredA[rl][1];
            const float s2 = sredB[rl][0] + sredB[rl][1];
            const float mu = s * (1.f / D_);
            const float rs = rsqrtf(s2 * (1.f / D_) - mu * mu + 1e-5f);
#pragma unroll
            for (int ct = 0; ct < 8; ct++) {
                const float c = acc[rt][ct][i] + bv[ct];
                out[(size_t)(row0 + rl) * D_ + colv[ct]] = (c - mu) * rs * gv[ct] + bbv[ct];
            }
        }
    } else {
#pragma unroll
        for (int rt = 0; rt < 2; rt++)
#pragma unroll
        for (int i = 0; i < 4; i++) {
            const int rl = rowbase + 16 * rt + quad * 4 + i;
#pragma unroll
            for (int ct = 0; ct < 8; ct++) {
                const float c = acc[rt][ct][i] + bv[ct];
                out[(size_t)(row0 + rl) * D_ + colv[ct]] = (c >= 0.f) ? c : 0.2f * c;
            }
        }
    }
}

// ---------- reset kmax slots ----------
__global__ void k_reset(int* slots) {
    if (threadIdx.x < 4) {
        const int i = __float_as_int(-INFINITY);
        slots[threadIdx.x] = (i >= 0) ? i : (i ^ 0x7fffffff);
    }
}

// ---------- MFMA global k-max (proven) ----------
__global__ void __launch_bounds__(256) k_dmax(
    const float* __restrict__ kg, const unsigned* __restrict__ P2, int* __restrict__ slot)
{
    __shared__ __align__(16) ushort A2s[64 * 136];
    __shared__ __align__(16) ushort Ps[128 * 136];
    __shared__ float sred[4];
    const int t = threadIdx.x;
    const size_t row0 = (size_t)(blockIdx.x >> 1) * 64;
    const int m0 = (blockIdx.x & 1) * 128;
    {
        const int row = t >> 2, kq = (t & 3) * 8;
        const float* src = kg + (row0 + row) * DH_ + kq;
        const float4 f0 = *(const float4*)src;
        const float4 f1 = *(const float4*)(src + 4);
        const float vv[8] = {f0.x, f0.y, f0.z, f0.w, f1.x, f1.y, f1.z, f1.w};
#pragma unroll
        for (int i = 0; i < 4; i++) {
            unsigned hh0, ll0, hh1, ll1;
            split2(vv[2 * i], hh0, ll0); split2(vv[2 * i + 1], hh1, ll1);
            *(uint4*)&A2s[row * 136 + ((t & 3) * 4 + i) * 8] = make_uint4(hh0, ll0, hh1, ll1);
        }
    }
    {
        const int col = t >> 1;
        const unsigned* src = P2 + (m0 + col) * DH_ + (t & 1) * 16;
#pragma unroll
        for (int i = 0; i < 8; i++) {
            const unsigned u0 = src[2 * i], u1 = src[2 * i + 1];
            *(uint4*)&Ps[col * 136 + ((t & 1) * 8 + i) * 8] = make_uint4(u0, u0, u1, u1);
        }
    }
    __syncthreads();
    const int w = t >> 6, lane = t & 63, quad = lane >> 4, l16 = lane & 15;
    floatx4 acc[4][2];
#pragma unroll
    for (int rt = 0; rt < 4; rt++)
#pragma unroll
        for (int ct = 0; ct < 2; ct++) acc[rt][ct] = (floatx4){0.f, 0.f, 0.f, 0.f};
#pragma unroll
    for (int kk = 0; kk < 4; kk++) {
        short8 af[4], bf[2];
#pragma unroll
        for (int rt = 0; rt < 4; rt++)
            af[rt] = *(const short8*)&A2s[(rt * 16 + l16) * 136 + (kk * 4 + quad) * 8];
#pragma unroll
        for (int ct = 0; ct < 2; ct++)
            bf[ct] = *(const short8*)&Ps[((w * 2 + ct) * 16 + l16) * 136 + (kk * 4 + quad) * 8];
#pragma unroll
        for (int rt = 0; rt < 4; rt++)
#pragma unroll
            for (int ct = 0; ct < 2; ct++)
                acc[rt][ct] = __builtin_amdgcn_mfma_f32_16x16x32_bf16(af[rt], bf[ct], acc[rt][ct], 0, 0, 0);
    }
    float mx = -INFINITY;
#pragma unroll
    for (int rt = 0; rt < 4; rt++)
#pragma unroll
        for (int ct = 0; ct < 2; ct++)
#pragma unroll
            for (int i = 0; i < 4; i++) mx = fmaxf(mx, acc[rt][ct][i]);
#pragma unroll
    for (int o = 32; o > 0; o >>= 1) mx = fmaxf(mx, __shfl_xor(mx, o, 64));
    if (lane == 0) sred[w] = mx;
    __syncthreads();
    if (t == 0) {
        const float m4 = fmaxf(fmaxf(sred[0], sred[1]), fmaxf(sred[2], sred[3]))
                       * 0.42044820762685725f;
        const int i = __float_as_int(m4);
        atomicMax(slot, (i >= 0) ? i : (i ^ 0x7fffffff));
    }
}

// ---------- full-MFMA performer attention, 512 threads, 139 KB LDS ----------
// q-row max fused: pass 1 computes dd_q for all 4 m-quarters into registers,
// per-row max via per-thread max + 2 shfl_xor over quads; pass 2 exponentiates
// from registers -> qpA/den/o. k_qrowmax kernel eliminated.
__global__ void __launch_bounds__(512) k_attn2(
    const float* __restrict__ qg, const float* __restrict__ kg, const float* __restrict__ vg,
    const unsigned* __restrict__ P2, const int* __restrict__ slot,
    float* __restrict__ outp)
{
    extern __shared__ char smem[];
    ushort* sA   = (ushort*)(smem);            // [128][136]: K-split, then Q-split
    ushort* sB   = (ushort*)(smem + 34816);    // [64][136]: P-quarter {h,l,h,l}
    ushort* sBig = (ushort*)(smem + 52224);    // kpT [64][264] / qpA [128][136]
    ushort* sV   = (ushort*)(smem + 87040);    // [32][264]: v dup
    ushort* sCtx = (ushort*)(smem + 103936);   // [32][520]: ctx dup
    float* sdk   = (float*)(smem + 137216);
    float* sdq   = (float*)(smem + 137728);
    float* sden  = (float*)(smem + 138752);
    float* sksum = (float*)(smem + 139264);
    float* sksP  = (float*)(smem + 140288);    // [8][64]

    const int bh = blockIdx.x;
    const int b = bh >> 3, hh = bh & 7;
    const int t = threadIdx.x;
    const int w = t >> 6, lane = t & 63, quad = lane >> 4, l16 = lane & 15;
    const float* kb = kg + (size_t)bh * S_ * DH_;
    const float* qb = qg + (size_t)bh * S_ * DH_;
    const float* vb = vg + (size_t)bh * S_ * DH_;
    const float nrm = 0.42044820762685725f;
    const float diagc = 0.5f * nrm * nrm;
    const float ratio = 0.0625f;

    // ---- phase 0: K-split stage; v-dup stage; diag
    {
        const int row = t >> 2, seg = t & 3;
        const float* src = kb + row * DH_ + seg * 8;
        float vv[8];
        *(float4*)&vv[0] = *(const float4*)&src[0];
        *(float4*)&vv[4] = *(const float4*)&src[4];
#pragma unroll
        for (int p = 0; p < 4; p++) {
            unsigned hh0, ll0, hh1, ll1;
            split2(vv[2 * p], hh0, ll0); split2(vv[2 * p + 1], hh1, ll1);
            *(uint4*)&sA[row * 136 + seg * 32 + p * 8] = make_uint4(hh0, ll0, hh1, ll1);
        }
    }
    {
        const int n = t & 127, d0 = (t >> 7) * 8;
        const float* src = vb + n * DH_ + d0;
        float vv[8];
        *(float4*)&vv[0] = *(const float4*)&src[0];
        *(float4*)&vv[4] = *(const float4*)&src[4];
        unsigned* dst = (unsigned*)sV;
#pragma unroll
        for (int j = 0; j < 8; j++)
            dst[(d0 + j) * 132 + n] = (unsigned)bf16_rn(vv[j]) * 0x10001u;
    }
    if (t < 128) {
        float s = 0.f, s2 = 0.f;
#pragma unroll
        for (int d4 = 0; d4 < DH_ / 4; d4++) {
            const float4 kk = *(const float4*)&kb[t * DH_ + d4 * 4];
            s += kk.x * kk.x + kk.y * kk.y + kk.z * kk.z + kk.w * kk.w;
            const float4 qq = *(const float4*)&qb[t * DH_ + d4 * 4];
            s2 += qq.x * qq.x + qq.y * qq.y + qq.z * qq.z + qq.w * qq.w;
        }
        sdk[t] = s * diagc;
        sdq[t] = s2 * diagc;
    }
    float kmaxv;
    { const int iv = *slot; kmaxv = __int_as_float((iv >= 0) ? iv : (iv ^ 0x7fffffff)); }
    __syncthreads();

    // ---- phase A/B: per m-quarter: dd_k -> kp(split) -> ksum, ctx -> ctxB
    for (int qd = 0; qd < 4; qd++) {
        {   // stage P-quarter
            const int col = t >> 3, ch = t & 7;
            const unsigned* src = P2 + (size_t)(qd * 64 + col) * DH_ + ch * 4;
            const unsigned u0 = src[0], u1 = src[1], u2 = src[2], u3 = src[3];
            *(uint4*)&sB[col * 136 + ch * 16]     = make_uint4(u0, u0, u1, u1);
            *(uint4*)&sB[col * 136 + ch * 16 + 8] = make_uint4(u2, u2, u3, u3);
        }
        __syncthreads();
        // dd_k: wave w -> n-tile w; 4 m-tiles
        floatx4 acc[4];
#pragma unroll
        for (int ct = 0; ct < 4; ct++) acc[ct] = (floatx4){0.f, 0.f, 0.f, 0.f};
#pragma unroll
        for (int ks = 0; ks < 4; ks++) {
            const short8 af = *(const short8*)&sA[(w * 16 + l16) * 136 + ks * 32 + quad * 8];
            short8 bf[4];
#pragma unroll
            for (int ct = 0; ct < 4; ct++)
                bf[ct] = *(const short8*)&sB[(ct * 16 + l16) * 136 + ks * 32 + quad * 8];
#pragma unroll
            for (int ct = 0; ct < 4; ct++)
                acc[ct] = __builtin_amdgcn_mfma_f32_16x16x32_bf16(af, bf[ct], acc[ct], 0, 0, 0);
        }
        // kp: thread n = w*16+quad*4+i, m = ct*16+l16; batched uint4 writes
        unsigned* kpT = (unsigned*)sBig;
        float kc[4];
#pragma unroll
        for (int ct = 0; ct < 4; ct++) {
            float kcl = 0.f;
            unsigned pk[4];
#pragma unroll
            for (int i = 0; i < 4; i++) {
                const int n = w * 16 + quad * 4 + i;
                const float kp = ratio * (exp2f((acc[ct][i] * nrm - sdk[n] - kmaxv) * LOG2E) + 1e-4f);
                kcl += kp;
                pk[i] = split_pack(kp);
            }
            *(uint4*)&kpT[(ct * 16 + l16) * 132 + w * 16 + quad * 4] = make_uint4(pk[0], pk[1], pk[2], pk[3]);
            kc[ct] = kcl;
        }
#pragma unroll
        for (int ct = 0; ct < 4; ct++) {
            kc[ct] += __shfl_xor(kc[ct], 16, 64);
            kc[ct] += __shfl_xor(kc[ct], 32, 64);
        }
        if (quad == 0) {
#pragma unroll
            for (int ct = 0; ct < 4; ct++) sksP[w * 64 + ct * 16 + l16] = kc[ct];
        }
        __syncthreads();
        if (t < 64) {
            float s = 0.f;
#pragma unroll
            for (int ww = 0; ww < 8; ww++) s += sksP[ww * 64 + t];
            sksum[qd * 64 + t] = s;
        }
        // ctx MFMA: wave w -> m-tile (w&3), d-tile (w>>2); K2 = 256 (n)
        floatx4 cacc = (floatx4){0.f, 0.f, 0.f, 0.f};
#pragma unroll
        for (int ks = 0; ks < 8; ks++) {
            const short8 a = *(const short8*)&sBig[((w & 3) * 16 + l16) * 264 + ks * 32 + quad * 8];
            const short8 bvv = *(const short8*)&sV[((w >> 2) * 16 + l16) * 264 + ks * 32 + quad * 8];
            cacc = __builtin_amdgcn_mfma_f32_16x16x32_bf16(a, bvv, cacc, 0, 0, 0);
        }
        {
            unsigned* ctxB = (unsigned*)sCtx;
            unsigned pk[4];
#pragma unroll
            for (int i = 0; i < 4; i++) pk[i] = (unsigned)bf16_rn(cacc[i]) * 0x10001u;
            *(uint4*)&ctxB[((w >> 2) * 16 + l16) * 260 + qd * 64 + (w & 3) * 16 + quad * 4] =
                make_uint4(pk[0], pk[1], pk[2], pk[3]);
        }
        __syncthreads();
    }

    // ---- phase C prep: restage Q-split into sA
    {
        const int row = t >> 2, seg = t & 3;
        const float* src = qb + row * DH_ + seg * 8;
        float vv[8];
        *(float4*)&vv[0] = *(const float4*)&src[0];
        *(float4*)&vv[4] = *(const float4*)&src[4];
#pragma unroll
        for (int p = 0; p < 4; p++) {
            unsigned hh0, ll0, hh1, ll1;
            split2(vv[2 * p], hh0, ll0); split2(vv[2 * p + 1], hh1, ll1);
            *(uint4*)&sA[row * 136 + seg * 32 + p * 8] = make_uint4(hh0, ll0, hh1, ll1);
        }
    }

    // ---- phase C pass 1: dd_q (swapped: A=P rows m, B=q rows n) into registers
    floatx4 adq[4][4];
#pragma unroll
    for (int qd = 0; qd < 4; qd++) {
        {   // stage P-quarter
            const int col = t >> 3, ch = t & 7;
            const unsigned* src = P2 + (size_t)(qd * 64 + col) * DH_ + ch * 4;
            const unsigned u0 = src[0], u1 = src[1], u2 = src[2], u3 = src[3];
            *(uint4*)&sB[col * 136 + ch * 16]     = make_uint4(u0, u0, u1, u1);
            *(uint4*)&sB[col * 136 + ch * 16 + 8] = make_uint4(u2, u2, u3, u3);
        }
        __syncthreads();
#pragma unroll
        for (int mt = 0; mt < 4; mt++) adq[qd][mt] = (floatx4){0.f, 0.f, 0.f, 0.f};
#pragma unroll
        for (int ks = 0; ks < 4; ks++) {
            const short8 bf = *(const short8*)&sA[(w * 16 + l16) * 136 + ks * 32 + quad * 8];
            short8 af[4];
#pragma unroll
            for (int mt = 0; mt < 4; mt++)
                af[mt] = *(const short8*)&sB[(mt * 16 + l16) * 136 + ks * 32 + quad * 8];
#pragma unroll
            for (int mt = 0; mt < 4; mt++)
                adq[qd][mt] = __builtin_amdgcn_mfma_f32_16x16x32_bf16(af[mt], bf, adq[qd][mt], 0, 0, 0);
        }
        __syncthreads();   // before next stage overwrites sB
    }

    // ---- fused q-row max: thread n = w*16 + l16; max over its 64 m + quad-reduce
    const int nq = w * 16 + l16;
    float mxn = -INFINITY;
#pragma unroll
    for (int qd = 0; qd < 4; qd++)
#pragma unroll
        for (int mt = 0; mt < 4; mt++)
#pragma unroll
            for (int i = 0; i < 4; i++) mxn = fmaxf(mxn, adq[qd][mt][i]);
    mxn = fmaxf(mxn, __shfl_xor(mxn, 16, 64));
    mxn = fmaxf(mxn, __shfl_xor(mxn, 32, 64));
    const float dmq = sdq[nq] + mxn * nrm;

    // ---- phase C pass 2: qp from registers -> qpA, den, o
    floatx4 oacc[2];
    oacc[0] = (floatx4){0.f, 0.f, 0.f, 0.f};
    oacc[1] = (floatx4){0.f, 0.f, 0.f, 0.f};
    float dp = 0.f;
#pragma unroll
    for (int qd = 0; qd < 4; qd++) {
        unsigned* qpA = (unsigned*)sBig;
#pragma unroll
        for (int mt = 0; mt < 4; mt++) {
            unsigned pk[4];
#pragma unroll
            for (int i = 0; i < 4; i++) {
                const float qp = ratio * (exp2f((adq[qd][mt][i] * nrm - dmq) * LOG2E) + 1e-4f);
                dp += qp * sksum[qd * 64 + mt * 16 + quad * 4 + i];
                pk[i] = split_pack(qp);
            }
            *(uint4*)&qpA[nq * 68 + mt * 16 + quad * 4] = make_uint4(pk[0], pk[1], pk[2], pk[3]);
        }
        __syncthreads();
        // o MFMA: wave w -> n-tile w, d-tiles 0..1; K2 = 128 (m-quarter)
#pragma unroll
        for (int ks = 0; ks < 4; ks++) {
            const short8 af = *(const short8*)&sBig[(w * 16 + l16) * 136 + ks * 32 + quad * 8];
            short8 bf[2];
#pragma unroll
            for (int dt = 0; dt < 2; dt++)
                bf[dt] = *(const short8*)&sCtx[(dt * 16 + l16) * 520 + qd * 128 + ks * 32 + quad * 8];
#pragma unroll
            for (int dt = 0; dt < 2; dt++)
                oacc[dt] = __builtin_amdgcn_mfma_f32_16x16x32_bf16(af, bf[dt], oacc[dt], 0, 0, 0);
        }
        __syncthreads();
    }
    dp += __shfl_xor(dp, 16, 64);
    dp += __shfl_xor(dp, 32, 64);
    if (quad == 0) sden[nq] = dp;
    __syncthreads();

    // ---- epilogue: o / den; n = w*16 + quad*4 + i, d = dt*16 + l16
#pragma unroll
    for (int i = 0; i < 4; i++) {
        const int n = w * 16 + quad * 4 + i;
        const float inv = 1.0f / sden[n];
#pragma unroll
        for (int dt = 0; dt < 2; dt++)
            outp[((size_t)b * S_ + n) * D_ + hh * DH_ + dt * 16 + l16] = oacc[dt][i] * inv;
    }
}

// ---------- classification head ----------
__global__ void __launch_bounds__(256) k_head(
    const float* __restrict__ hfin, const float* __restrict__ h1w, const float* __restrict__ h1b,
    const float* __restrict__ h2w, const float* __restrict__ h2b,
    const float* __restrict__ ow, const float* __restrict__ ob, float* __restrict__ outp)
{
    __shared__ float c0[D_];
    __shared__ float c1[2 * HID_];
    __shared__ float sred[4];
    const int t = threadIdx.x;
    const int b = blockIdx.x;
    c0[t] = hfin[(size_t)b * S_ * D_ + t];
    __syncthreads();
#pragma unroll
    for (int half = 0; half < 2; half++) {
        const int j = half * 256 + t;
        float a = h1b[j];
        const float* w = h1w + (size_t)j * D_;
        for (int d = 0; d < D_; d += 4) {
            const float4 w4 = *(const float4*)&w[d];
            const float4 x4 = *(const float4*)&c0[d];
            a += x4.x * w4.x + x4.y * w4.y + x4.z * w4.z + x4.w * w4.w;
        }
        c1[j] = (a >= 0.f) ? a : 0.2f * a;
    }
    __syncthreads();
    float a2 = h2b[t];
    const float* w2 = h2w + (size_t)t * (2 * HID_);
    for (int j = 0; j < 2 * HID_; j += 4) {
        const float4 w4 = *(const float4*)&w2[j];
        const float4 x4 = *(const float4*)&c1[j];
        a2 += x4.x * w4.x + x4.y * w4.y + x4.z * w4.z + x4.w * w4.w;
    }
    const float c2 = (a2 >= 0.f) ? a2 : 0.2f * a2;
    const float s = blk_sum(c2 * ow[t], sred);
    if (t == 0) outp[b] = s + ob[0];
}

extern "C" void kernel_launch(void* const* d_in, const int* in_sizes, int n_in,
                              void* d_out, int out_size, void* d_ws, size_t ws_size,
                              hipStream_t stream)
{
    const float* x     = (const float*)d_in[0];
    const int*   mask  = (const int*)d_in[1];
    const float* emb_w = (const float*)d_in[2];
    const float* emb_b = (const float*)d_in[3];
    const float* Wq    = (const float*)d_in[4];
    const float* bq    = (const float*)d_in[5];
    const float* Wk    = (const float*)d_in[6];
    const float* bk    = (const float*)d_in[7];
    const float* Wv    = (const float*)d_in[8];
    const float* bv    = (const float*)d_in[9];
    const float* Wo    = (const float*)d_in[10];
    const float* bo    = (const float*)d_in[11];
    const float* proj  = (const float*)d_in[12];
    const float* n1w   = (const float*)d_in[13];
    const float* n1b   = (const float*)d_in[14];
    const float* n2w   = (const float*)d_in[15];
    const float* n2b   = (const float*)d_in[16];
    const float* f1w   = (const float*)d_in[17];
    const float* f1b   = (const float*)d_in[18];
    const float* f2w   = (const float*)d_in[19];
    const float* f2b   = (const float*)d_in[20];
    const float* h1w   = (const float*)d_in[21];
    const float* h1b   = (const float*)d_in[22];
    const float* h2w   = (const float*)d_in[23];
    const float* h2b   = (const float*)d_in[24];
    const float* ow    = (const float*)d_in[25];
    const float* ob    = (const float*)d_in[26];

    const size_t BSD = (size_t)B_ * S_ * D_;
    float* A = (float*)d_ws;
    float* Q = A + BSD;
    float* K = Q + BSD;
    float* V = K + BSD;
    float* T = K;                              // post-LN1 alias (K dead after attn)
    unsigned* W2 = (unsigned*)(V + BSD);
    const size_t WT = (size_t)L_ * 256 * 256;
    const size_t WM = (size_t)256 * 256;
    unsigned* P2 = W2 + 6 * WT;                // split proj: L x 256 x 32 uints
    int* slots = (int*)(P2 + (size_t)L_ * M_ * DH_);

    k_wconv<<<256, 256, 0, stream>>>(Wq,  W2 + 0 * WT);
    k_wconv<<<256, 256, 0, stream>>>(Wk,  W2 + 1 * WT);
    k_wconv<<<256, 256, 0, stream>>>(Wv,  W2 + 2 * WT);
    k_wconv<<<256, 256, 0, stream>>>(Wo,  W2 + 3 * WT);
    k_wconv<<<256, 256, 0, stream>>>(f1w, W2 + 4 * WT);
    k_wconv<<<256, 256, 0, stream>>>(f2w, W2 + 5 * WT);
    k_wconv<<<32, 256, 0, stream>>>(proj, P2);
    k_reset<<<1, 64, 0, stream>>>(slots);

    const int GB = B_ * S_ / 64;               // 512 blocks per GEMM
    const int DB = B_ * H_ * S_ / 64 * 2;      // 8192 blocks for k_dmax
    const size_t ATTN_LDS = 142336;            // 139 KB dynamic LDS

    k_embed<<<B_ * S_ * D_ / 256, 256, 0, stream>>>(x, emb_w, emb_b, A);
    for (int l = 0; l < L_; l++) {
        const unsigned* P2l = P2 + (size_t)l * M_ * DH_;
        k_gemm<0><<<GB, 256, 0, stream>>>(A, W2 + 0 * WT + l * WM, bq + l * D_, nullptr, nullptr, nullptr, Q);
        k_gemm<0><<<GB, 256, 0, stream>>>(A, W2 + 1 * WT + l * WM, bk + l * D_, nullptr, nullptr, nullptr, K);
        k_gemm<1><<<GB, 256, 0, stream>>>(A, W2 + 2 * WT + l * WM, bv + l * D_, nullptr, nullptr, mask, V);
        k_dmax<<<DB, 256, 0, stream>>>(K, P2l, slots + l);
        k_attn2<<<B_ * H_, 512, ATTN_LDS, stream>>>(Q, K, V, P2l, slots + l, A);
        k_gemm<2><<<GB, 256, 0, stream>>>(A, W2 + 3 * WT + l * WM, bo + l * D_, n1w + l * D_, n1b + l * D_, nullptr, T);
        k_gemm<3><<<GB, 256, 0, stream>>>(T, W2 + 4 * WT + l * WM, f1b + l * HID_, nullptr, nullptr, nullptr, Q);
        k_gemm<2><<<GB, 256, 0, stream>>>(Q, W2 + 5 * WT + l * WM, f2b + l * D_, n2w + l * D_, n2b + l * D_, nullptr, A);
    }
    k_head<<<B_, 256, 0, stream>>>(A, h1w, h1b, h2w, h2b, ow, ob, (float*)d_out);
}

// Round 10
// 2133.775 us; speedup vs baseline: 3.4863x; 1.0185x over previous
//
#include <hip/hip_runtime.h>
#include <math.h>

#define B_ 256
#define N_ 127
#define S_ 128
#define NDIM_ 3
#define D_ 256
#define H_ 8
#define DH_ 32
#define M_ 256
#define HID_ 256
#define L_ 4
#define LOG2E 1.44269504088896340736f

typedef __attribute__((ext_vector_type(8))) short short8;
typedef __attribute__((ext_vector_type(4))) float floatx4;

// ---------- bf16 split helpers ----------
__device__ __forceinline__ ushort bf16_rn(float x) {
    unsigned u = __float_as_uint(x);
    u = (u + 0x7fffu + ((u >> 16) & 1u)) >> 16;
    return (ushort)u;
}
__device__ __forceinline__ void split2(float x, unsigned& hh, unsigned& ll) {
    const ushort h = bf16_rn(x);
    const float r = x - __uint_as_float(((unsigned)h) << 16);
    const ushort l = bf16_rn(r);
    hh = (unsigned)h * 0x10001u;
    ll = (unsigned)l * 0x10001u;
}
__device__ __forceinline__ unsigned split_pack(float x) {
    const ushort h = bf16_rn(x);
    const float r = x - __uint_as_float(((unsigned)h) << 16);
    const ushort l = bf16_rn(r);
    return (unsigned)h | ((unsigned)l << 16);
}

// ---------- block reductions ----------
__device__ __forceinline__ float blk_sum(float v, float* sred) {
#pragma unroll
    for (int o = 32; o > 0; o >>= 1) v += __shfl_xor(v, o, 64);
    if ((threadIdx.x & 63) == 0) sred[threadIdx.x >> 6] = v;
    __syncthreads();
    v = sred[0] + sred[1] + sred[2] + sred[3];
    __syncthreads();
    return v;
}

// ---------- embedding ----------
__global__ void k_embed(const float* __restrict__ x, const float* __restrict__ ew,
                        const float* __restrict__ eb, float* __restrict__ h) {
    const int idx = blockIdx.x * 256 + threadIdx.x;
    const int d = idx & (D_ - 1);
    const int n = (idx >> 8) & (S_ - 1);
    const int b = idx >> 15;
    float val = 0.f;
    if (n > 0) {
        const float* xr = x + ((size_t)b * N_ + (n - 1)) * NDIM_;
        val = eb[d] + xr[0] * ew[d * 3 + 0] + xr[1] * ew[d * 3 + 1] + xr[2] * ew[d * 3 + 2];
    }
    h[idx] = val;
}

// ---------- weight pre-split (compact): fp32 -> uint [h|l<<16] ----------
__global__ void __launch_bounds__(256) k_wconv(const float* __restrict__ src, unsigned* __restrict__ dst) {
    const int idx = (blockIdx.x * 256 + threadIdx.x) * 4;
    const float4 w4 = *(const float4*)&src[idx];
    const float v[4] = {w4.x, w4.y, w4.z, w4.w};
    unsigned u[4];
#pragma unroll
    for (int i = 0; i < 4; i++) u[i] = split_pack(v[i]);
    *(uint4*)&dst[idx] = make_uint4(u[0], u[1], u[2], u[3]);
}

// ---------- MFMA bf16x2-split GEMM: C[64 x 256] per block, K2 = 1024 ----------
template<int EPI>
__global__ void __launch_bounds__(256) k_gemm(
    const float* __restrict__ A, const unsigned* __restrict__ W2,
    const float* __restrict__ bias, const float* __restrict__ g1,
    const float* __restrict__ g2, const int* __restrict__ mask,
    float* __restrict__ out)
{
    __shared__ ushort A2s[4 * 64 * 8];     // [c][row][8]
    __shared__ ushort W2s[4 * 256 * 8];    // [c][col][8]
    __shared__ float sredA[64][2], sredB[64][2];
    const int t = threadIdx.x;
    const int w = t >> 6, lane = t & 63;
    const int quad = lane >> 4, l16 = lane & 15;
    const int rowbase = 32 * (w >> 1), colbase = 128 * (w & 1);
    const int row0 = blockIdx.x * 64;

    floatx4 acc[2][8];
#pragma unroll
    for (int rt = 0; rt < 2; rt++)
#pragma unroll
        for (int ct = 0; ct < 8; ct++) acc[rt][ct] = (floatx4){0.f, 0.f, 0.f, 0.f};

    const int srow = t >> 2, skq = t & 3;
    const float* Arow = A + (size_t)(row0 + srow) * D_ + skq * 2;
    const unsigned* Wrow = W2 + (size_t)t * 256;

    for (int s = 0; s < 32; s++) {
        __syncthreads();
        {
            const float2 a2 = *(const float2*)(Arow + s * 8);
            unsigned hh0, ll0, hh1, ll1;
            split2(a2.x, hh0, ll0); split2(a2.y, hh1, ll1);
            *(uint4*)&A2s[skq * 512 + srow * 8] = make_uint4(hh0, ll0, hh1, ll1);
        }
        {
            const uint4* wp = (const uint4*)(Wrow + s * 8);
            const uint4 w0 = wp[0], w1 = wp[1];
            *(uint4*)&W2s[0 * 2048 + t * 8] = make_uint4(w0.x, w0.x, w0.y, w0.y);
            *(uint4*)&W2s[1 * 2048 + t * 8] = make_uint4(w0.z, w0.z, w0.w, w0.w);
            *(uint4*)&W2s[2 * 2048 + t * 8] = make_uint4(w1.x, w1.x, w1.y, w1.y);
            *(uint4*)&W2s[3 * 2048 + t * 8] = make_uint4(w1.z, w1.z, w1.w, w1.w);
        }
        __syncthreads();
        short8 af[2], bf[8];
#pragma unroll
        for (int rt = 0; rt < 2; rt++)
            af[rt] = *(const short8*)&A2s[quad * 512 + (rowbase + 16 * rt + l16) * 8];
#pragma unroll
        for (int ct = 0; ct < 8; ct++)
            bf[ct] = *(const short8*)&W2s[quad * 2048 + (colbase + 16 * ct + l16) * 8];
#pragma unroll
        for (int rt = 0; rt < 2; rt++)
#pragma unroll
            for (int ct = 0; ct < 8; ct++)
                acc[rt][ct] = __builtin_amdgcn_mfma_f32_16x16x32_bf16(af[rt], bf[ct], acc[rt][ct], 0, 0, 0);
    }

    int colv[8]; float bv[8];
#pragma unroll
    for (int ct = 0; ct < 8; ct++) { colv[ct] = colbase + 16 * ct + l16; bv[ct] = bias[colv[ct]]; }

    if (EPI <= 1) {
        const int b = row0 >> 7;
#pragma unroll
        for (int rt = 0; rt < 2; rt++)
#pragma unroll
        for (int i = 0; i < 4; i++) {
            const int rl = rowbase + 16 * rt + quad * 4 + i;
            const int n = (row0 + rl) & (S_ - 1);
            float keep = 1.f;
            if (EPI == 1) keep = (n == 0) ? 1.f : (mask[b * N_ + n - 1] ? 0.f : 1.f);
#pragma unroll
            for (int ct = 0; ct < 8; ct++) {
                float c = acc[rt][ct][i] + bv[ct];
                if (EPI == 1) c *= keep;
                const int col = colv[ct];
                out[(((size_t)b * H_ + (col >> 5)) * S_ + n) * DH_ + (col & 31)] = c;
            }
        }
    } else if (EPI == 2) {
        float gv[8], bbv[8];
#pragma unroll
        for (int ct = 0; ct < 8; ct++) { gv[ct] = g1[colv[ct]]; bbv[ct] = g2[colv[ct]]; }
#pragma unroll
        for (int rt = 0; rt < 2; rt++)
#pragma unroll
        for (int i = 0; i < 4; i++) {
            const int rl = rowbase + 16 * rt + quad * 4 + i;
            float s = 0.f, s2 = 0.f;
#pragma unroll
            for (int ct = 0; ct < 8; ct++) {
                const float c = acc[rt][ct][i] + bv[ct];
                s += c; s2 += c * c;
            }
#pragma unroll
            for (int o = 8; o > 0; o >>= 1) { s += __shfl_xor(s, o, 64); s2 += __shfl_xor(s2, o, 64); }
            if (l16 == 0) { sredA[rl][w & 1] = s; sredB[rl][w & 1] = s2; }
        }
        __syncthreads();
#pragma unroll
        for (int rt = 0; rt < 2; rt++)
#pragma unroll
        for (int i = 0; i < 4; i++) {
            const int rl = rowbase + 16 * rt + quad * 4 + i;
            const float s = sredA[rl][0] + sredA[rl][1];
            const float s2 = sredB[rl][0] + sredB[rl][1];
            const float mu = s * (1.f / D_);
            const float rs = rsqrtf(s2 * (1.f / D_) - mu * mu + 1e-5f);
#pragma unroll
            for (int ct = 0; ct < 8; ct++) {
                const float c = acc[rt][ct][i] + bv[ct];
                out[(size_t)(row0 + rl) * D_ + colv[ct]] = (c - mu) * rs * gv[ct] + bbv[ct];
            }
        }
    } else {
#pragma unroll
        for (int rt = 0; rt < 2; rt++)
#pragma unroll
        for (int i = 0; i < 4; i++) {
            const int rl = rowbase + 16 * rt + quad * 4 + i;
#pragma unroll
            for (int ct = 0; ct < 8; ct++) {
                const float c = acc[rt][ct][i] + bv[ct];
                out[(size_t)(row0 + rl) * D_ + colv[ct]] = (c >= 0.f) ? c : 0.2f * c;
            }
        }
    }
}

// ---------- reset kmax slots ----------
__global__ void k_reset(int* slots) {
    if (threadIdx.x < 4) {
        const int i = __float_as_int(-INFINITY);
        slots[threadIdx.x] = (i >= 0) ? i : (i ^ 0x7fffffff);
    }
}

// ---------- MFMA global k-max (proven) ----------
__global__ void __launch_bounds__(256) k_dmax(
    const float* __restrict__ kg, const unsigned* __restrict__ P2, int* __restrict__ slot)
{
    __shared__ __align__(16) ushort A2s[64 * 136];
    __shared__ __align__(16) ushort Ps[128 * 136];
    __shared__ float sred[4];
    const int t = threadIdx.x;
    const size_t row0 = (size_t)(blockIdx.x >> 1) * 64;
    const int m0 = (blockIdx.x & 1) * 128;
    {
        const int row = t >> 2, kq = (t & 3) * 8;
        const float* src = kg + (row0 + row) * DH_ + kq;
        const float4 f0 = *(const float4*)src;
        const float4 f1 = *(const float4*)(src + 4);
        const float vv[8] = {f0.x, f0.y, f0.z, f0.w, f1.x, f1.y, f1.z, f1.w};
#pragma unroll
        for (int i = 0; i < 4; i++) {
            unsigned hh0, ll0, hh1, ll1;
            split2(vv[2 * i], hh0, ll0); split2(vv[2 * i + 1], hh1, ll1);
            *(uint4*)&A2s[row * 136 + ((t & 3) * 4 + i) * 8] = make_uint4(hh0, ll0, hh1, ll1);
        }
    }
    {
        const int col = t >> 1;
        const unsigned* src = P2 + (m0 + col) * DH_ + (t & 1) * 16;
#pragma unroll
        for (int i = 0; i < 8; i++) {
            const unsigned u0 = src[2 * i], u1 = src[2 * i + 1];
            *(uint4*)&Ps[col * 136 + ((t & 1) * 8 + i) * 8] = make_uint4(u0, u0, u1, u1);
        }
    }
    __syncthreads();
    const int w = t >> 6, lane = t & 63, quad = lane >> 4, l16 = lane & 15;
    floatx4 acc[4][2];
#pragma unroll
    for (int rt = 0; rt < 4; rt++)
#pragma unroll
        for (int ct = 0; ct < 2; ct++) acc[rt][ct] = (floatx4){0.f, 0.f, 0.f, 0.f};
#pragma unroll
    for (int kk = 0; kk < 4; kk++) {
        short8 af[4], bf[2];
#pragma unroll
        for (int rt = 0; rt < 4; rt++)
            af[rt] = *(const short8*)&A2s[(rt * 16 + l16) * 136 + (kk * 4 + quad) * 8];
#pragma unroll
        for (int ct = 0; ct < 2; ct++)
            bf[ct] = *(const short8*)&Ps[((w * 2 + ct) * 16 + l16) * 136 + (kk * 4 + quad) * 8];
#pragma unroll
        for (int rt = 0; rt < 4; rt++)
#pragma unroll
            for (int ct = 0; ct < 2; ct++)
                acc[rt][ct] = __builtin_amdgcn_mfma_f32_16x16x32_bf16(af[rt], bf[ct], acc[rt][ct], 0, 0, 0);
    }
    float mx = -INFINITY;
#pragma unroll
    for (int rt = 0; rt < 4; rt++)
#pragma unroll
        for (int ct = 0; ct < 2; ct++)
#pragma unroll
            for (int i = 0; i < 4; i++) mx = fmaxf(mx, acc[rt][ct][i]);
#pragma unroll
    for (int o = 32; o > 0; o >>= 1) mx = fmaxf(mx, __shfl_xor(mx, o, 64));
    if (lane == 0) sred[w] = mx;
    __syncthreads();
    if (t == 0) {
        const float m4 = fmaxf(fmaxf(sred[0], sred[1]), fmaxf(sred[2], sred[3]))
                       * 0.42044820762685725f;
        const int i = __float_as_int(m4);
        atomicMax(slot, (i >= 0) ? i : (i ^ 0x7fffffff));
    }
}

// ---------- full-MFMA performer attention, 1024 threads (16 waves), 140 KB LDS ----------
// 1 block/CU (LDS-bound) but 4 waves/SIMD. Wave w: n-tile wg = w&7, m-half wh = w>>3.
__global__ void __launch_bounds__(1024) k_attn2(
    const float* __restrict__ qg, const float* __restrict__ kg, const float* __restrict__ vg,
    const unsigned* __restrict__ P2, const int* __restrict__ slot,
    float* __restrict__ outp)
{
    extern __shared__ char smem[];
    ushort* sA    = (ushort*)(smem);            // [128][136]: K-split, then Q-split
    ushort* sB    = (ushort*)(smem + 34816);    // [64][136]: P-quarter {h,l,h,l}
    ushort* sBig  = (ushort*)(smem + 52224);    // kpT [64][264] / qpA [128][136]
    ushort* sV    = (ushort*)(smem + 87040);    // [32][264]: v dup
    ushort* sCtx  = (ushort*)(smem + 103936);   // [32][520]: ctx dup
    float* sdk    = (float*)(smem + 137216);    // [128]
    float* sdq    = (float*)(smem + 137728);    // [128]
    float* smaxP  = (float*)(smem + 138240);    // [2][128] rowmax partials
    float* sdenP  = (float*)(smem + 139264);    // [2][128] den partials
    float* sksum  = (float*)(smem + 140288);    // [256]
    float* sksP   = (float*)(smem + 141312);    // [16][32] ksum partials

    const int bh = blockIdx.x;
    const int b = bh >> 3, hh = bh & 7;
    const int t = threadIdx.x;
    const int w = t >> 6, lane = t & 63, quad = lane >> 4, l16 = lane & 15;
    const int wg = w & 7, wh = w >> 3;
    const float* kb = kg + (size_t)bh * S_ * DH_;
    const float* qb = qg + (size_t)bh * S_ * DH_;
    const float* vb = vg + (size_t)bh * S_ * DH_;
    const float nrm = 0.42044820762685725f;
    const float diagc = 0.5f * nrm * nrm;
    const float ratio = 0.0625f;

    // ---- phase 0: waves 0-7 stage K-split (+diag on t<128); waves 8-15 stage v-dup
    if (t < 512) {
        const int row = t >> 2, seg = t & 3;
        const float* src = kb + row * DH_ + seg * 8;
        float vv[8];
        *(float4*)&vv[0] = *(const float4*)&src[0];
        *(float4*)&vv[4] = *(const float4*)&src[4];
#pragma unroll
        for (int p = 0; p < 4; p++) {
            unsigned hh0, ll0, hh1, ll1;
            split2(vv[2 * p], hh0, ll0); split2(vv[2 * p + 1], hh1, ll1);
            *(uint4*)&sA[row * 136 + seg * 32 + p * 8] = make_uint4(hh0, ll0, hh1, ll1);
        }
    } else {
        const int tt2 = t - 512;
        const int n = tt2 & 127, d0 = (tt2 >> 7) * 8;
        const float* src = vb + n * DH_ + d0;
        float vv[8];
        *(float4*)&vv[0] = *(const float4*)&src[0];
        *(float4*)&vv[4] = *(const float4*)&src[4];
        unsigned* dst = (unsigned*)sV;
#pragma unroll
        for (int j = 0; j < 8; j++)
            dst[(d0 + j) * 132 + n] = (unsigned)bf16_rn(vv[j]) * 0x10001u;
    }
    if (t < 128) {
        float s = 0.f, s2 = 0.f;
#pragma unroll
        for (int d4 = 0; d4 < DH_ / 4; d4++) {
            const float4 kk = *(const float4*)&kb[t * DH_ + d4 * 4];
            s += kk.x * kk.x + kk.y * kk.y + kk.z * kk.z + kk.w * kk.w;
            const float4 qq = *(const float4*)&qb[t * DH_ + d4 * 4];
            s2 += qq.x * qq.x + qq.y * qq.y + qq.z * qq.z + qq.w * qq.w;
        }
        sdk[t] = s * diagc;
        sdq[t] = s2 * diagc;
    }
    float kmaxv;
    { const int iv = *slot; kmaxv = __int_as_float((iv >= 0) ? iv : (iv ^ 0x7fffffff)); }
    __syncthreads();

    // ---- phase A/B: per m-quarter: dd_k -> kp(split) -> ksum, ctx -> ctxB
    for (int qd = 0; qd < 4; qd++) {
        {   // stage P-quarter: 1024 threads, 2 originals each
            const int col = t >> 4, ch2 = t & 15;
            const unsigned* src = P2 + (size_t)(qd * 64 + col) * DH_ + ch2 * 2;
            const unsigned u0 = src[0], u1 = src[1];
            *(uint4*)&sB[col * 136 + ch2 * 8] = make_uint4(u0, u0, u1, u1);
        }
        __syncthreads();
        // dd_k: n-tile wg, m-tiles 2wh+{0,1}
        floatx4 acc[2];
        acc[0] = (floatx4){0.f, 0.f, 0.f, 0.f};
        acc[1] = (floatx4){0.f, 0.f, 0.f, 0.f};
#pragma unroll
        for (int ks = 0; ks < 4; ks++) {
            const short8 af = *(const short8*)&sA[(wg * 16 + l16) * 136 + ks * 32 + quad * 8];
            short8 bf[2];
#pragma unroll
            for (int ctl = 0; ctl < 2; ctl++)
                bf[ctl] = *(const short8*)&sB[((2 * wh + ctl) * 16 + l16) * 136 + ks * 32 + quad * 8];
#pragma unroll
            for (int ctl = 0; ctl < 2; ctl++)
                acc[ctl] = __builtin_amdgcn_mfma_f32_16x16x32_bf16(af, bf[ctl], acc[ctl], 0, 0, 0);
        }
        // kp: thread n = wg*16+quad*4+i, m = (2wh+ctl)*16+l16; batched uint4 along n
        unsigned* kpT = (unsigned*)sBig;
        float kc[2];
#pragma unroll
        for (int ctl = 0; ctl < 2; ctl++) {
            float kcl = 0.f;
            unsigned pk[4];
#pragma unroll
            for (int i = 0; i < 4; i++) {
                const int n = wg * 16 + quad * 4 + i;
                const float kp = ratio * (exp2f((acc[ctl][i] * nrm - sdk[n] - kmaxv) * LOG2E) + 1e-4f);
                kcl += kp;
                pk[i] = split_pack(kp);
            }
            *(uint4*)&kpT[((2 * wh + ctl) * 16 + l16) * 132 + wg * 16 + quad * 4] =
                make_uint4(pk[0], pk[1], pk[2], pk[3]);
            kc[ctl] = kcl;
        }
#pragma unroll
        for (int ctl = 0; ctl < 2; ctl++) {
            kc[ctl] += __shfl_xor(kc[ctl], 16, 64);
            kc[ctl] += __shfl_xor(kc[ctl], 32, 64);
        }
        if (quad == 0) {
            sksP[w * 32 + l16] = kc[0];
            sksP[w * 32 + 16 + l16] = kc[1];
        }
        __syncthreads();
        if (t < 64) {   // mloc = t: wh_sel = t>>5, m31 = t&31
            float s = 0.f;
#pragma unroll
            for (int wg2 = 0; wg2 < 8; wg2++)
                s += sksP[((t >> 5) * 8 + wg2) * 32 + (t & 31)];
            sksum[qd * 64 + t] = s;
        }
        // ctx MFMA on waves 0-7: m-tile mt = w&3, d-tile dt = w>>2; K2 = 256 (n)
        if (w < 8) {
            const int mt = w & 3, dt = w >> 2;
            floatx4 cacc = (floatx4){0.f, 0.f, 0.f, 0.f};
#pragma unroll
            for (int ks = 0; ks < 8; ks++) {
                const short8 a = *(const short8*)&sBig[(mt * 16 + l16) * 264 + ks * 32 + quad * 8];
                const short8 bvv = *(const short8*)&sV[(dt * 16 + l16) * 264 + ks * 32 + quad * 8];
                cacc = __builtin_amdgcn_mfma_f32_16x16x32_bf16(a, bvv, cacc, 0, 0, 0);
            }
            unsigned* ctxB = (unsigned*)sCtx;
            unsigned pk[4];
#pragma unroll
            for (int i = 0; i < 4; i++) pk[i] = (unsigned)bf16_rn(cacc[i]) * 0x10001u;
            *(uint4*)&ctxB[(dt * 16 + l16) * 260 + qd * 64 + mt * 16 + quad * 4] =
                make_uint4(pk[0], pk[1], pk[2], pk[3]);
        }
        __syncthreads();
    }

    // ---- phase C prep: restage Q-split into sA
    if (t < 512) {
        const int row = t >> 2, seg = t & 3;
        const float* src = qb + row * DH_ + seg * 8;
        float vv[8];
        *(float4*)&vv[0] = *(const float4*)&src[0];
        *(float4*)&vv[4] = *(const float4*)&src[4];
#pragma unroll
        for (int p = 0; p < 4; p++) {
            unsigned hh0, ll0, hh1, ll1;
            split2(vv[2 * p], hh0, ll0); split2(vv[2 * p + 1], hh1, ll1);
            *(uint4*)&sA[row * 136 + seg * 32 + p * 8] = make_uint4(hh0, ll0, hh1, ll1);
        }
    }

    // ---- phase C pass 1: dd_q (swapped: A=P rows m, B=q rows n) into registers
    floatx4 adq[4][2];
#pragma unroll
    for (int qd = 0; qd < 4; qd++) {
        {   // stage P-quarter
            const int col = t >> 4, ch2 = t & 15;
            const unsigned* src = P2 + (size_t)(qd * 64 + col) * DH_ + ch2 * 2;
            const unsigned u0 = src[0], u1 = src[1];
            *(uint4*)&sB[col * 136 + ch2 * 8] = make_uint4(u0, u0, u1, u1);
        }
        __syncthreads();
        adq[qd][0] = (floatx4){0.f, 0.f, 0.f, 0.f};
        adq[qd][1] = (floatx4){0.f, 0.f, 0.f, 0.f};
#pragma unroll
        for (int ks = 0; ks < 4; ks++) {
            const short8 bf = *(const short8*)&sA[(wg * 16 + l16) * 136 + ks * 32 + quad * 8];
            short8 af[2];
#pragma unroll
            for (int mtl = 0; mtl < 2; mtl++)
                af[mtl] = *(const short8*)&sB[((2 * wh + mtl) * 16 + l16) * 136 + ks * 32 + quad * 8];
#pragma unroll
            for (int mtl = 0; mtl < 2; mtl++)
                adq[qd][mtl] = __builtin_amdgcn_mfma_f32_16x16x32_bf16(af[mtl], bf, adq[qd][mtl], 0, 0, 0);
        }
        __syncthreads();   // before next stage overwrites sB
    }

    // ---- fused q-row max: thread n = wg*16 + l16; its m-half max, then cross-wave
    const int nq = wg * 16 + l16;
    {
        float mxn = -INFINITY;
#pragma unroll
        for (int qd = 0; qd < 4; qd++)
#pragma unroll
            for (int mtl = 0; mtl < 2; mtl++)
#pragma unroll
                for (int i = 0; i < 4; i++) mxn = fmaxf(mxn, adq[qd][mtl][i]);
        mxn = fmaxf(mxn, __shfl_xor(mxn, 16, 64));
        mxn = fmaxf(mxn, __shfl_xor(mxn, 32, 64));
        if (quad == 0) smaxP[wh * 128 + nq] = mxn;
    }
    __syncthreads();
    const float dmq = sdq[nq] + fmaxf(smaxP[nq], smaxP[128 + nq]) * nrm;

    // ---- phase C pass 2: qp from registers -> qpA, den partial, o
    floatx4 oacc = (floatx4){0.f, 0.f, 0.f, 0.f};
    float dp = 0.f;
#pragma unroll
    for (int qd = 0; qd < 4; qd++) {
        unsigned* qpA = (unsigned*)sBig;
#pragma unroll
        for (int mtl = 0; mtl < 2; mtl++) {
            unsigned pk[4];
#pragma unroll
            for (int i = 0; i < 4; i++) {
                const float qp = ratio * (exp2f((adq[qd][mtl][i] * nrm - dmq) * LOG2E) + 1e-4f);
                dp += qp * sksum[qd * 64 + (2 * wh + mtl) * 16 + quad * 4 + i];
                pk[i] = split_pack(qp);
            }
            *(uint4*)&qpA[nq * 68 + (2 * wh + mtl) * 16 + quad * 4] = make_uint4(pk[0], pk[1], pk[2], pk[3]);
        }
        __syncthreads();
        // o MFMA: wave -> n-tile wg, d-half wh; K2 = 128 (m-quarter)
#pragma unroll
        for (int ks = 0; ks < 4; ks++) {
            const short8 af = *(const short8*)&sBig[(wg * 16 + l16) * 136 + ks * 32 + quad * 8];
            const short8 bf = *(const short8*)&sCtx[(wh * 16 + l16) * 520 + qd * 128 + ks * 32 + quad * 8];
            oacc = __builtin_amdgcn_mfma_f32_16x16x32_bf16(af, bf, oacc, 0, 0, 0);
        }
        __syncthreads();
    }
    dp += __shfl_xor(dp, 16, 64);
    dp += __shfl_xor(dp, 32, 64);
    if (quad == 0) sdenP[wh * 128 + nq] = dp;
    __syncthreads();

    // ---- epilogue: o / den; n = wg*16 + quad*4 + i, d = wh*16 + l16
#pragma unroll
    for (int i = 0; i < 4; i++) {
        const int n = wg * 16 + quad * 4 + i;
        const float inv = 1.0f / (sdenP[n] + sdenP[128 + n]);
        outp[((size_t)b * S_ + n) * D_ + hh * DH_ + wh * 16 + l16] = oacc[i] * inv;
    }
}

// ---------- classification head ----------
__global__ void __launch_bounds__(256) k_head(
    const float* __restrict__ hfin, const float* __restrict__ h1w, const float* __restrict__ h1b,
    const float* __restrict__ h2w, const float* __restrict__ h2b,
    const float* __restrict__ ow, const float* __restrict__ ob, float* __restrict__ outp)
{
    __shared__ float c0[D_];
    __shared__ float c1[2 * HID_];
    __shared__ float sred[4];
    const int t = threadIdx.x;
    const int b = blockIdx.x;
    c0[t] = hfin[(size_t)b * S_ * D_ + t];
    __syncthreads();
#pragma unroll
    for (int half = 0; half < 2; half++) {
        const int j = half * 256 + t;
        float a = h1b[j];
        const float* w = h1w + (size_t)j * D_;
        for (int d = 0; d < D_; d += 4) {
            const float4 w4 = *(const float4*)&w[d];
            const float4 x4 = *(const float4*)&c0[d];
            a += x4.x * w4.x + x4.y * w4.y + x4.z * w4.z + x4.w * w4.w;
        }
        c1[j] = (a >= 0.f) ? a : 0.2f * a;
    }
    __syncthreads();
    float a2 = h2b[t];
    const float* w2 = h2w + (size_t)t * (2 * HID_);
    for (int j = 0; j < 2 * HID_; j += 4) {
        const float4 w4 = *(const float4*)&w2[j];
        const float4 x4 = *(const float4*)&c1[j];
        a2 += x4.x * w4.x + x4.y * w4.y + x4.z * w4.z + x4.w * w4.w;
    }
    const float c2 = (a2 >= 0.f) ? a2 : 0.2f * a2;
    const float s = blk_sum(c2 * ow[t], sred);
    if (t == 0) outp[b] = s + ob[0];
}

extern "C" void kernel_launch(void* const* d_in, const int* in_sizes, int n_in,
                              void* d_out, int out_size, void* d_ws, size_t ws_size,
                              hipStream_t stream)
{
    const float* x     = (const float*)d_in[0];
    const int*   mask  = (const int*)d_in[1];
    const float* emb_w = (const float*)d_in[2];
    const float* emb_b = (const float*)d_in[3];
    const float* Wq    = (const float*)d_in[4];
    const float* bq    = (const float*)d_in[5];
    const float* Wk    = (const float*)d_in[6];
    const float* bk    = (const float*)d_in[7];
    const float* Wv    = (const float*)d_in[8];
    const float* bv    = (const float*)d_in[9];
    const float* Wo    = (const float*)d_in[10];
    const float* bo    = (const float*)d_in[11];
    const float* proj  = (const float*)d_in[12];
    const float* n1w   = (const float*)d_in[13];
    const float* n1b   = (const float*)d_in[14];
    const float* n2w   = (const float*)d_in[15];
    const float* n2b   = (const float*)d_in[16];
    const float* f1w   = (const float*)d_in[17];
    const float* f1b   = (const float*)d_in[18];
    const float* f2w   = (const float*)d_in[19];
    const float* f2b   = (const float*)d_in[20];
    const float* h1w   = (const float*)d_in[21];
    const float* h1b   = (const float*)d_in[22];
    const float* h2w   = (const float*)d_in[23];
    const float* h2b   = (const float*)d_in[24];
    const float* ow    = (const float*)d_in[25];
    const float* ob    = (const float*)d_in[26];

    const size_t BSD = (size_t)B_ * S_ * D_;
    float* A = (float*)d_ws;
    float* Q = A + BSD;
    float* K = Q + BSD;
    float* V = K + BSD;
    float* T = K;                              // post-LN1 alias (K dead after attn)
    unsigned* W2 = (unsigned*)(V + BSD);
    const size_t WT = (size_t)L_ * 256 * 256;
    const size_t WM = (size_t)256 * 256;
    unsigned* P2 = W2 + 6 * WT;                // split proj: L x 256 x 32 uints
    int* slots = (int*)(P2 + (size_t)L_ * M_ * DH_);

    k_wconv<<<256, 256, 0, stream>>>(Wq,  W2 + 0 * WT);
    k_wconv<<<256, 256, 0, stream>>>(Wk,  W2 + 1 * WT);
    k_wconv<<<256, 256, 0, stream>>>(Wv,  W2 + 2 * WT);
    k_wconv<<<256, 256, 0, stream>>>(Wo,  W2 + 3 * WT);
    k_wconv<<<256, 256, 0, stream>>>(f1w, W2 + 4 * WT);
    k_wconv<<<256, 256, 0, stream>>>(f2w, W2 + 5 * WT);
    k_wconv<<<32, 256, 0, stream>>>(proj, P2);
    k_reset<<<1, 64, 0, stream>>>(slots);

    const int GB = B_ * S_ / 64;               // 512 blocks per GEMM
    const int DB = B_ * H_ * S_ / 64 * 2;      // 8192 blocks for k_dmax
    const size_t ATTN_LDS = 143360;            // 140 KB dynamic LDS

    k_embed<<<B_ * S_ * D_ / 256, 256, 0, stream>>>(x, emb_w, emb_b, A);
    for (int l = 0; l < L_; l++) {
        const unsigned* P2l = P2 + (size_t)l * M_ * DH_;
        k_gemm<0><<<GB, 256, 0, stream>>>(A, W2 + 0 * WT + l * WM, bq + l * D_, nullptr, nullptr, nullptr, Q);
        k_gemm<0><<<GB, 256, 0, stream>>>(A, W2 + 1 * WT + l * WM, bk + l * D_, nullptr, nullptr, nullptr, K);
        k_gemm<1><<<GB, 256, 0, stream>>>(A, W2 + 2 * WT + l * WM, bv + l * D_, nullptr, nullptr, mask, V);
        k_dmax<<<DB, 256, 0, stream>>>(K, P2l, slots + l);
        k_attn2<<<B_ * H_, 1024, ATTN_LDS, stream>>>(Q, K, V, P2l, slots + l, A);
        k_gemm<2><<<GB, 256, 0, stream>>>(A, W2 + 3 * WT + l * WM, bo + l * D_, n1w + l * D_, n1b + l * D_, nullptr, T);
        k_gemm<3><<<GB, 256, 0, stream>>>(T, W2 + 4 * WT + l * WM, f1b + l * HID_, nullptr, nullptr, nullptr, Q);
        k_gemm<2><<<GB, 256, 0, stream>>>(Q, W2 + 5 * WT + l * WM, f2b + l * D_, n2w + l * D_, n2b + l * D_, nullptr, A);
    }
    k_head<<<B_, 256, 0, stream>>>(A, h1w, h1b, h2w, h2b, ow, ob, (float*)d_out);
}